// Round 16
// baseline (1448.196 us; speedup 1.0000x reference)
//
#include <hip/hip_runtime.h>
#include <hip/hip_bf16.h>
#include <math.h>

typedef __attribute__((ext_vector_type(8))) short short8;
typedef __attribute__((ext_vector_type(4))) float f32x4;

__device__ __forceinline__ unsigned short f2bf(float f){
  union { __hip_bfloat16 h; unsigned short u; } cv;
  cv.h = __float2bfloat16(f);
  return cv.u;
}

__device__ __forceinline__ float bf2f(unsigned short u){
  union { unsigned int i; float f; } v;
  v.i = ((unsigned int)u) << 16;
  return v.f;
}

// gelu via sigmoid: 0.5v(1+tanh(u)) == v*sigmoid(2u), exp2-folded constants
__device__ __forceinline__ float gelu_f(float v){
  float v2 = v * v;
  float nw = v * fmaf(-0.10294364f, v2, -2.3022090f);  // -2u*log2(e)
  float e  = __builtin_amdgcn_exp2f(nw);
  return v * __builtin_amdgcn_rcpf(1.f + e);
}

__device__ __forceinline__ void gload_lds16(const unsigned short* g, unsigned short* l){
  __builtin_amdgcn_global_load_lds(
      (const __attribute__((address_space(1))) void*)g,
      (__attribute__((address_space(3))) void*)l, 16, 0, 0);
}

// ---------------- all four weight transposes in one launch -------------------
__global__ __launch_bounds__(256) void wconv4(
    const float* __restrict__ qkv_w, const float* __restrict__ proj_w,
    const float* __restrict__ fc1_w, const float* __restrict__ fc2_w,
    unsigned short* __restrict__ wq, unsigned short* __restrict__ wp,
    unsigned short* __restrict__ w1, unsigned short* __restrict__ w2){
  int idx = blockIdx.x * 256 + threadIdx.x;
  if (idx < 196608){                       // qkv: K=256 N=768
    int k = idx / 768, n = idx % 768;
    wq[n*256 + k] = f2bf(qkv_w[idx]);
  } else if (idx < 262144){                // proj: K=256 N=256
    int l = idx - 196608;
    int k = l >> 8, n = l & 255;
    wp[n*256 + k] = f2bf(proj_w[l]);
  } else if (idx < 524288){                // fc1: K=256 N=1024
    int l = idx - 262144;
    int k = l >> 10, n = l & 1023;
    w1[n*256 + k] = f2bf(fc1_w[l]);
  } else {                                 // fc2: K=1024 N=256
    int l = idx - 524288;
    int k = l >> 8, n = l & 255;
    w2[n*1024 + k] = f2bf(fc2_w[l]);
  }
}

// ---------------- LayerNorm: x f32 [M][256] -> out bf16 [M][256] -------------
__global__ __launch_bounds__(256) void ln_kernel(
    const float* __restrict__ x, const float* __restrict__ g,
    const float* __restrict__ b, unsigned short* __restrict__ out){
  const int lane = threadIdx.x & 63;
  const int wv = threadIdx.x >> 6;
  const long row = (long)blockIdx.x * 4 + wv;
  const float4 xv = ((const float4*)(x + row * 256))[lane];
  float s  = xv.x + xv.y + xv.z + xv.w;
  float s2 = xv.x*xv.x + xv.y*xv.y + xv.z*xv.z + xv.w*xv.w;
  #pragma unroll
  for (int m = 1; m < 64; m <<= 1){
    s  += __shfl_xor(s,  m);
    s2 += __shfl_xor(s2, m);
  }
  float mu = s * (1.f/256.f);
  float rs = rsqrtf(s2 * (1.f/256.f) - mu*mu + 1e-5f);
  float4 gv = ((const float4*)g)[lane];
  float4 bv = ((const float4*)b)[lane];
  ushort4 o;
  o.x = f2bf((xv.x - mu)*rs*gv.x + bv.x);
  o.y = f2bf((xv.y - mu)*rs*gv.y + bv.y);
  o.z = f2bf((xv.z - mu)*rs*gv.z + bv.z);
  o.w = f2bf((xv.w - mu)*rs*gv.w + bv.w);
  ((ushort4*)(out + row * 256))[lane] = o;
}

// ---------------- GEMM: A[M][K] bf16 @ Wt[N][K] bf16 -> out [M][N] -----------
// 512 threads / 8 waves (2x4 wave grid), 128x128 tile, BK=64, XOR-swizzled LDS,
// XCD-band grid swizzle. SWAPPED MFMA: row = ..+l15, cols = ..+4*l4+{0..3}
// MODE 0: out bf16 = acc + bias             (direct uint2 stores)
// MODE 1: out bf16 = gelu(acc + bias)       (direct uint2 stores)
// MODE 2: out f32  = acc + bias + res(bf16) (float4 direct stores)
template<int MODE>
__global__ __launch_bounds__(512, 8) void gemm_bt(
    const unsigned short* __restrict__ A,
    const unsigned short* __restrict__ Bt,
    const float* __restrict__ bias,
    const unsigned short* __restrict__ res,
    void* __restrict__ out,
    int N, int K, int nbx){
  __shared__ unsigned short S[2*128*64];
  unsigned short* As = S;
  unsigned short* Bs = S + 128*64;
  const int tid  = threadIdx.x;
  const int lane = tid & 63;
  const int wave = tid >> 6;
  const int wm = wave >> 1, wn = wave & 1;   // 4 x 2 wave grid: 32-row x 64-col

  const int nby  = gridDim.x / nbx;
  const int bid  = blockIdx.x;
  const int xcd  = bid & 7;
  const int local = bid >> 3;
  const int lrow = local / nbx;
  const int rowb = xcd * (nby >> 3) + lrow;
  const int colb = local - lrow * nbx;
  const long row0 = (long)rowb * 128;
  const int  col0 = colb * 128;
  const int l15 = lane & 15, l4 = lane >> 4;

  f32x4 acc[2][4];
  #pragma unroll
  for (int i = 0; i < 2; ++i)
    #pragma unroll
    for (int j = 0; j < 4; ++j)
      acc[i][j] = (f32x4){0.f, 0.f, 0.f, 0.f};

  const int nk = K >> 6;
  for (int kt = 0; kt < nk; ++kt){
    #pragma unroll
    for (int it = 0; it < 2; ++it){
      int ch = it*512 + tid;
      int r = ch >> 3, cc = ch & 7;
      int srcc = ((cc ^ (r & 7)) << 3);
      gload_lds16(A  + (row0 + r) * K + kt*64 + srcc, &As[ch*8]);
      gload_lds16(Bt + (long)(col0 + r) * K + kt*64 + srcc, &Bs[ch*8]);
    }
    __syncthreads();
    #pragma unroll
    for (int ks = 0; ks < 2; ++ks){
      short8 af[2], bfr[4];
      #pragma unroll
      for (int mi = 0; mi < 2; ++mi){
        int ar = wm*32 + mi*16 + l15;
        af[mi] = *(const short8*)&As[ar*64 + (((ks*4 + l4) ^ (ar & 7)) << 3)];
      }
      #pragma unroll
      for (int ni = 0; ni < 4; ++ni){
        int br = wn*64 + ni*16 + l15;
        bfr[ni] = *(const short8*)&Bs[br*64 + (((ks*4 + l4) ^ (br & 7)) << 3)];
      }
      #pragma unroll
      for (int mi = 0; mi < 2; ++mi)
        #pragma unroll
        for (int ni = 0; ni < 4; ++ni)
          acc[mi][ni] = __builtin_amdgcn_mfma_f32_16x16x32_bf16(bfr[ni], af[mi], acc[mi][ni], 0, 0, 0);
    }
    __syncthreads();
  }

  if (MODE == 2){
    float* outf = (float*)out;
    #pragma unroll
    for (int mi = 0; mi < 2; ++mi){
      long row = row0 + wm*32 + mi*16 + l15;
      #pragma unroll
      for (int ni = 0; ni < 4; ++ni){
        int colg = col0 + wn*64 + ni*16 + 4*l4;
        float4 bv = *(const float4*)&bias[colg];
        long idx = row * N + colg;
        ushort4 rv = *(const ushort4*)&res[idx];
        float4 o;
        o.x = acc[mi][ni][0] + bv.x + bf2f(rv.x);
        o.y = acc[mi][ni][1] + bv.y + bf2f(rv.y);
        o.z = acc[mi][ni][2] + bv.z + bf2f(rv.z);
        o.w = acc[mi][ni][3] + bv.w + bf2f(rv.w);
        *(float4*)&outf[idx] = o;
      }
    }
  } else {
    unsigned short* outp = (unsigned short*)out;
    #pragma unroll
    for (int mi = 0; mi < 2; ++mi){
      long row = row0 + wm*32 + mi*16 + l15;
      #pragma unroll
      for (int ni = 0; ni < 4; ++ni){
        int colg = col0 + wn*64 + ni*16 + 4*l4;
        float4 bv = *(const float4*)&bias[colg];
        float v0 = acc[mi][ni][0] + bv.x;
        float v1 = acc[mi][ni][1] + bv.y;
        float v2 = acc[mi][ni][2] + bv.z;
        float v3 = acc[mi][ni][3] + bv.w;
        if (MODE == 1){ v0 = gelu_f(v0); v1 = gelu_f(v1); v2 = gelu_f(v2); v3 = gelu_f(v3); }
        uint2 dv;
        dv.x = ((unsigned int)f2bf(v1) << 16) | f2bf(v0);
        dv.y = ((unsigned int)f2bf(v3) << 16) | f2bf(v2);
        *(uint2*)&outp[row * N + colg] = dv;
      }
    }
  }
}

// ---------------- Window attention: one WAVE = one (window, head) ------------
// Swapped QK^T and PV: packed uint2 P writes (16) and ao writes (8).
__global__ __launch_bounds__(64, 3) void attn_kernel(
    const unsigned short* __restrict__ qkv,
    const float* __restrict__ bt,
    unsigned short* __restrict__ ao){
  __shared__ unsigned short P[64*64];
  const int lane = threadIdx.x;
  const int wb = blockIdx.x;
  const int w = wb >> 3, h = wb & 7;
  const int bidx = w >> 10, rem = w & 1023;
  const int wy = rem >> 5, wx = rem & 31;
  const long tok0 = (long)bidx * 65536 + (long)wy * 2048 + wx * 8;
  const int l15 = lane & 15, l4 = lane >> 4;

  short8 qf[4], kf[4];
  #pragma unroll
  for (int t = 0; t < 4; ++t){
    int n = t*16 + l15;
    long tok = tok0 + (n >> 3) * 256 + (n & 7);
    qf[t] = *(const short8*)(qkv + tok*768 +       h*32 + 8*l4);
    kf[t] = *(const short8*)(qkv + tok*768 + 256 + h*32 + 8*l4);
  }
  // swapped: s[mi][ni]: lane holds q = mi*16+l15, k = ni*16+4*l4+{0..3}
  f32x4 s[4][4];
  #pragma unroll
  for (int i = 0; i < 4; ++i)
    #pragma unroll
    for (int j = 0; j < 4; ++j)
      s[i][j] = (f32x4){0.f, 0.f, 0.f, 0.f};
  #pragma unroll
  for (int mi = 0; mi < 4; ++mi)
    #pragma unroll
    for (int ni = 0; ni < 4; ++ni)
      s[mi][ni] = __builtin_amdgcn_mfma_f32_16x16x32_bf16(kf[ni], qf[mi], s[mi][ni], 0, 0, 0);

  const float scale = 0.17677669529663687f; // 1/sqrt(32)
  #pragma unroll
  for (int mi = 0; mi < 4; ++mi){
    int q = mi*16 + l15;
    int ny = q >> 3, nx = q & 7;
    #pragma unroll
    for (int ni = 0; ni < 4; ++ni){
      #pragma unroll
      for (int j = 0; j < 4; ++j){
        int k = ni*16 + 4*l4 + j;
        int db = (ny - (k >> 3) + 7) * 15 + (nx - (k & 7) + 7);
        s[mi][ni][j] = s[mi][ni][j] * scale + bt[db*8 + h];
      }
    }
    float mx = -1e30f;
    #pragma unroll
    for (int ni = 0; ni < 4; ++ni)
      #pragma unroll
      for (int j = 0; j < 4; ++j)
        mx = fmaxf(mx, s[mi][ni][j]);
    mx = fmaxf(mx, __shfl_xor(mx, 16));
    mx = fmaxf(mx, __shfl_xor(mx, 32));
    float sm = 0.f;
    #pragma unroll
    for (int ni = 0; ni < 4; ++ni)
      #pragma unroll
      for (int j = 0; j < 4; ++j){
        float p = __expf(s[mi][ni][j] - mx);
        s[mi][ni][j] = p;
        sm += p;
      }
    sm += __shfl_xor(sm, 16);
    sm += __shfl_xor(sm, 32);
    float inv = __builtin_amdgcn_rcpf(sm);
    #pragma unroll
    for (int ni = 0; ni < 4; ++ni){
      uint2 dv;
      dv.x = ((unsigned int)f2bf(s[mi][ni][1]*inv) << 16) | f2bf(s[mi][ni][0]*inv);
      dv.y = ((unsigned int)f2bf(s[mi][ni][3]*inv) << 16) | f2bf(s[mi][ni][2]*inv);
      int g = ni*2 + (l4 >> 1);
      *(uint2*)&P[q*64 + ((g ^ (q & 7)) << 3) + 4*(l4 & 1)] = dv;
    }
  }
  // single wave: no barrier needed (compiler orders via lgkmcnt)

  // PV swapped: o[mi][ni]: lane holds token = mi*16+l15, d = ni*16+4*l4+{0..3}
  f32x4 o[4][2];
  #pragma unroll
  for (int i = 0; i < 4; ++i)
    #pragma unroll
    for (int j = 0; j < 2; ++j)
      o[i][j] = (f32x4){0.f, 0.f, 0.f, 0.f};
  #pragma unroll
  for (int kt = 0; kt < 2; ++kt){
    short8 vf[2];
    #pragma unroll
    for (int ni = 0; ni < 2; ++ni){
      union { unsigned short u[8]; short8 v; } tmp;
      #pragma unroll
      for (int i = 0; i < 8; ++i){
        int kk = kt*32 + 8*l4 + i;
        long tok = tok0 + (kk >> 3) * 256 + (kk & 7);
        tmp.u[i] = qkv[tok*768 + 512 + h*32 + ni*16 + l15];
      }
      vf[ni] = tmp.v;
    }
    #pragma unroll
    for (int mi = 0; mi < 4; ++mi){
      int r = mi*16 + l15;
      short8 pf = *(const short8*)&P[r*64 + (((kt*4 + l4) ^ (r & 7)) << 3)];
      #pragma unroll
      for (int ni = 0; ni < 2; ++ni)
        o[mi][ni] = __builtin_amdgcn_mfma_f32_16x16x32_bf16(vf[ni], pf, o[mi][ni], 0, 0, 0);
    }
  }
  #pragma unroll
  for (int mi = 0; mi < 4; ++mi){
    int t = mi*16 + l15;
    long tok = tok0 + (t >> 3) * 256 + (t & 7);
    #pragma unroll
    for (int ni = 0; ni < 2; ++ni){
      uint2 dv;
      dv.x = ((unsigned int)f2bf(o[mi][ni][1]) << 16) | f2bf(o[mi][ni][0]);
      dv.y = ((unsigned int)f2bf(o[mi][ni][3]) << 16) | f2bf(o[mi][ni][2]);
      *(uint2*)&ao[tok*256 + h*32 + ni*16 + 4*l4] = dv;
    }
  }
}

// ---------------- proj + residual + LN2 fused (R13 version) ------------------
__global__ __launch_bounds__(512, 4) void proj_ln2(
    const unsigned short* __restrict__ A,
    const unsigned short* __restrict__ Bt,
    const float* __restrict__ bias,
    const float* __restrict__ res,
    const float* __restrict__ g2,
    const float* __restrict__ b2,
    unsigned short* __restrict__ hout,
    unsigned short* __restrict__ hn){
  __shared__ unsigned short As[128*64];
  __shared__ unsigned short Bs[256*64];
  __shared__ float redsum[4][128];
  __shared__ float redsq[4][128];
  __shared__ float mu_s[128];
  __shared__ float rs_s[128];
  const int tid = threadIdx.x, lane = tid & 63, wave = tid >> 6;
  const int l15 = lane & 15, l4 = lane >> 4;
  const int wm = wave >> 2, wn = wave & 3;
  const long row0 = (long)blockIdx.x * 128;

  f32x4 acc[4][4];
  #pragma unroll
  for (int i = 0; i < 4; ++i)
    #pragma unroll
    for (int j = 0; j < 4; ++j)
      acc[i][j] = (f32x4){0.f, 0.f, 0.f, 0.f};

  for (int kt = 0; kt < 4; ++kt){
    #pragma unroll
    for (int it = 0; it < 2; ++it){
      int ch = it*512 + tid;
      int r = ch >> 3, cc = ch & 7;
      gload_lds16(A + (row0 + r)*256 + kt*64 + ((cc ^ (r & 7))*8), &As[ch*8]);
    }
    #pragma unroll
    for (int it = 0; it < 4; ++it){
      int ch = it*512 + tid;
      int r = ch >> 3, cc = ch & 7;
      gload_lds16(Bt + r*256 + kt*64 + ((cc ^ (r & 7))*8), &Bs[ch*8]);
    }
    __syncthreads();
    #pragma unroll
    for (int ks = 0; ks < 2; ++ks){
      short8 af[4], bf[4];
      #pragma unroll
      for (int mi = 0; mi < 4; ++mi){
        int ar = wm*64 + mi*16 + l15;
        af[mi] = *(const short8*)&As[ar*64 + (((ks*4 + l4) ^ (ar & 7))*8)];
      }
      #pragma unroll
      for (int ni = 0; ni < 4; ++ni){
        int br = wn*64 + ni*16 + l15;
        bf[ni] = *(const short8*)&Bs[br*64 + (((ks*4 + l4) ^ (br & 7))*8)];
      }
      #pragma unroll
      for (int mi = 0; mi < 4; ++mi)
        #pragma unroll
        for (int ni = 0; ni < 4; ++ni)
          acc[mi][ni] = __builtin_amdgcn_mfma_f32_16x16x32_bf16(af[mi], bf[ni], acc[mi][ni], 0, 0, 0);
    }
    __syncthreads();
  }

  float bcol[4];
  #pragma unroll
  for (int ni = 0; ni < 4; ++ni) bcol[ni] = bias[wn*64 + ni*16 + l15];
  f32x4 psum[4], psq[4];
  #pragma unroll
  for (int mi = 0; mi < 4; ++mi){
    psum[mi] = (f32x4){0.f,0.f,0.f,0.f};
    psq[mi]  = (f32x4){0.f,0.f,0.f,0.f};
    #pragma unroll
    for (int ni = 0; ni < 4; ++ni){
      int col = wn*64 + ni*16 + l15;
      #pragma unroll
      for (int j = 0; j < 4; ++j){
        long row = row0 + wm*64 + mi*16 + 4*l4 + j;
        long idx = row * 256 + col;
        float v = acc[mi][ni][j] + bcol[ni] + res[idx];
        hout[idx] = f2bf(v);
        acc[mi][ni][j] = v;
        psum[mi][j] += v;
        psq[mi][j]  += v * v;
      }
    }
  }
  #pragma unroll
  for (int mi = 0; mi < 4; ++mi){
    #pragma unroll
    for (int j = 0; j < 4; ++j){
      float s = psum[mi][j], q = psq[mi][j];
      #pragma unroll
      for (int m = 1; m < 16; m <<= 1){
        s += __shfl_xor(s, m);
        q += __shfl_xor(q, m);
      }
      if (l15 == 0){
        int rl = wm*64 + mi*16 + 4*l4 + j;
        redsum[wn][rl] = s;
        redsq[wn][rl]  = q;
      }
    }
  }
  __syncthreads();
  if (tid < 128){
    float s = redsum[0][tid] + redsum[1][tid] + redsum[2][tid] + redsum[3][tid];
    float q = redsq[0][tid]  + redsq[1][tid]  + redsq[2][tid]  + redsq[3][tid];
    float mu = s * (1.f/256.f);
    mu_s[tid] = mu;
    rs_s[tid] = rsqrtf(q * (1.f/256.f) - mu*mu + 1e-5f);
  }
  __syncthreads();
  float gcol[4], b2col[4];
  #pragma unroll
  for (int ni = 0; ni < 4; ++ni){
    gcol[ni]  = g2[wn*64 + ni*16 + l15];
    b2col[ni] = b2[wn*64 + ni*16 + l15];
  }
  #pragma unroll
  for (int mi = 0; mi < 4; ++mi){
    #pragma unroll
    for (int j = 0; j < 4; ++j){
      int rl = wm*64 + mi*16 + 4*l4 + j;
      float mu = mu_s[rl], rs = rs_s[rl];
      long row = row0 + rl;
      #pragma unroll
      for (int ni = 0; ni < 4; ++ni){
        int col = wn*64 + ni*16 + l15;
        hn[row*256 + col] = f2bf((acc[mi][ni][j] - mu)*rs*gcol[ni] + b2col[ni]);
      }
    }
  }
}

extern "C" void kernel_launch(void* const* d_in, const int* in_sizes, int n_in,
                              void* d_out, int out_size, void* d_ws, size_t ws_size,
                              hipStream_t stream){
  const float* x      = (const float*)d_in[0];
  const float* ln1_g  = (const float*)d_in[1];
  const float* ln1_b  = (const float*)d_in[2];
  const float* qkv_w  = (const float*)d_in[3];
  const float* qkv_b  = (const float*)d_in[4];
  const float* proj_w = (const float*)d_in[5];
  const float* proj_b = (const float*)d_in[6];
  const float* btab   = (const float*)d_in[7];
  const float* ln2_g  = (const float*)d_in[8];
  const float* ln2_b  = (const float*)d_in[9];
  const float* fc1_w  = (const float*)d_in[10];
  const float* fc1_b  = (const float*)d_in[11];
  const float* fc2_w  = (const float*)d_in[12];
  const float* fc2_b  = (const float*)d_in[13];

  const long M = (long)in_sizes[0] / 256;  // 262144 tokens

  char* ws = (char*)d_ws;
  unsigned short* xn  = (unsigned short*)(ws);
  unsigned short* ao  = xn;
  unsigned short* act = xn;
  unsigned short* qkv = (unsigned short*)(ws + 134217728);
  unsigned short* hn  = (unsigned short*)(ws + 536870912);
  unsigned short* wq  = (unsigned short*)(ws + 671088640);
  unsigned short* wp  = wq + 256*768;
  unsigned short* w1  = wp + 256*256;
  unsigned short* w2  = w1 + 256*1024;
  unsigned short* hh  = (unsigned short*)(ws + (712ull << 20));
  float* outf = (float*)d_out;

  // all 4 weight transposes in one launch (786432 elems)
  wconv4<<<3072, 256, 0, stream>>>(qkv_w, proj_w, fc1_w, fc2_w, wq, wp, w1, w2);

  // LN1
  ln_kernel<<<M/4, 256, 0, stream>>>(x, ln1_g, ln1_b, xn);
  // QKV (swizzled): nbx=6
  gemm_bt<0><<<6 * (M/128), 512, 0, stream>>>(xn, wq, qkv_b, nullptr, qkv, 768, 256, 6);
  // window attention: one wave per (window, head)
  attn_kernel<<<(M/64) * 8, 64, 0, stream>>>(qkv, btab, ao);
  // proj + residual + LN2  (h bf16 -> hh, hn bf16)
  proj_ln2<<<M/128, 512, 0, stream>>>(ao, wp, proj_b, x, ln2_g, ln2_b, hh, hn);
  // FC1 + GELU (swizzled): nbx=8
  gemm_bt<1><<<8 * (M/128), 512, 0, stream>>>(hn, w1, fc1_b, nullptr, act, 1024, 256, 8);
  // FC2 + residual(h bf16) -> out f32 (swizzled): nbx=2
  gemm_bt<2><<<2 * (M/128), 512, 0, stream>>>(act, w2, fc2_b, hh, outf, 256, 1024, 2);
}

// Round 17
// 1253.471 us; speedup vs baseline: 1.1553x; 1.1553x over previous
//
#include <hip/hip_runtime.h>
#include <hip/hip_bf16.h>
#include <math.h>

typedef __attribute__((ext_vector_type(8))) short short8;
typedef __attribute__((ext_vector_type(4))) float f32x4;

__device__ __forceinline__ unsigned short f2bf(float f){
  union { __hip_bfloat16 h; unsigned short u; } cv;
  cv.h = __float2bfloat16(f);
  return cv.u;
}

__device__ __forceinline__ float bf2f(unsigned short u){
  union { unsigned int i; float f; } v;
  v.i = ((unsigned int)u) << 16;
  return v.f;
}

// gelu via sigmoid: 0.5v(1+tanh(u)) == v*sigmoid(2u), exp2-folded constants
__device__ __forceinline__ float gelu_f(float v){
  float v2 = v * v;
  float nw = v * fmaf(-0.10294364f, v2, -2.3022090f);  // -2u*log2(e)
  float e  = __builtin_amdgcn_exp2f(nw);
  return v * __builtin_amdgcn_rcpf(1.f + e);
}

__device__ __forceinline__ void gload_lds16(const unsigned short* g, unsigned short* l){
  __builtin_amdgcn_global_load_lds(
      (const __attribute__((address_space(1))) void*)g,
      (__attribute__((address_space(3))) void*)l, 16, 0, 0);
}

// ---------------- all four weight transposes in one launch -------------------
__global__ __launch_bounds__(256) void wconv4(
    const float* __restrict__ qkv_w, const float* __restrict__ proj_w,
    const float* __restrict__ fc1_w, const float* __restrict__ fc2_w,
    unsigned short* __restrict__ wq, unsigned short* __restrict__ wp,
    unsigned short* __restrict__ w1, unsigned short* __restrict__ w2){
  int idx = blockIdx.x * 256 + threadIdx.x;
  if (idx < 196608){                       // qkv: K=256 N=768
    int k = idx / 768, n = idx % 768;
    wq[n*256 + k] = f2bf(qkv_w[idx]);
  } else if (idx < 262144){                // proj: K=256 N=256
    int l = idx - 196608;
    int k = l >> 8, n = l & 255;
    wp[n*256 + k] = f2bf(proj_w[l]);
  } else if (idx < 524288){                // fc1: K=256 N=1024
    int l = idx - 262144;
    int k = l >> 10, n = l & 1023;
    w1[n*256 + k] = f2bf(fc1_w[l]);
  } else {                                 // fc2: K=1024 N=256
    int l = idx - 524288;
    int k = l >> 8, n = l & 255;
    w2[n*1024 + k] = f2bf(fc2_w[l]);
  }
}

// ---------------- LayerNorm: x f32 [M][256] -> out bf16 [M][256] -------------
__global__ __launch_bounds__(256) void ln_kernel(
    const float* __restrict__ x, const float* __restrict__ g,
    const float* __restrict__ b, unsigned short* __restrict__ out){
  const int lane = threadIdx.x & 63;
  const int wv = threadIdx.x >> 6;
  const long row = (long)blockIdx.x * 4 + wv;
  const float4 xv = ((const float4*)(x + row * 256))[lane];
  float s  = xv.x + xv.y + xv.z + xv.w;
  float s2 = xv.x*xv.x + xv.y*xv.y + xv.z*xv.z + xv.w*xv.w;
  #pragma unroll
  for (int m = 1; m < 64; m <<= 1){
    s  += __shfl_xor(s,  m);
    s2 += __shfl_xor(s2, m);
  }
  float mu = s * (1.f/256.f);
  float rs = rsqrtf(s2 * (1.f/256.f) - mu*mu + 1e-5f);
  float4 gv = ((const float4*)g)[lane];
  float4 bv = ((const float4*)b)[lane];
  ushort4 o;
  o.x = f2bf((xv.x - mu)*rs*gv.x + bv.x);
  o.y = f2bf((xv.y - mu)*rs*gv.y + bv.y);
  o.z = f2bf((xv.z - mu)*rs*gv.z + bv.z);
  o.w = f2bf((xv.w - mu)*rs*gv.w + bv.w);
  ((ushort4*)(out + row * 256))[lane] = o;
}

// ---------------- GEMM: A[M][K] bf16 @ Wt[N][K] bf16 -> out [M][N] -----------
// 256 threads / 4 waves, 128x128 tile, BK=64, XOR-swizzled LDS, XCD banding.
// SWAPPED MFMA: per lane row = ..+l15, cols = ..+4*l4+{0..3}
// MODE 0: out bf16 = acc + bias             (direct uint2 stores)
// MODE 1: out bf16 = gelu(acc + bias)       (direct uint2 stores)
// MODE 2: out f32  = acc + bias + res(bf16) (float4 direct stores)
template<int MODE>
__global__ __launch_bounds__(256, 4) void gemm_bt(
    const unsigned short* __restrict__ A,
    const unsigned short* __restrict__ Bt,
    const float* __restrict__ bias,
    const unsigned short* __restrict__ res,
    void* __restrict__ out,
    int N, int K, int nbx){
  __shared__ unsigned short S[2*128*64];
  unsigned short* As = S;
  unsigned short* Bs = S + 128*64;
  const int tid  = threadIdx.x;
  const int lane = tid & 63;
  const int wave = tid >> 6;
  const int wm = wave >> 1, wn = wave & 1;

  const int nby  = gridDim.x / nbx;
  const int bid  = blockIdx.x;
  const int xcd  = bid & 7;
  const int local = bid >> 3;
  const int lrow = local / nbx;
  const int rowb = xcd * (nby >> 3) + lrow;
  const int colb = local - lrow * nbx;
  const long row0 = (long)rowb * 128;
  const int  col0 = colb * 128;
  const int l15 = lane & 15, l4 = lane >> 4;

  f32x4 acc[4][4];
  #pragma unroll
  for (int i = 0; i < 4; ++i)
    #pragma unroll
    for (int j = 0; j < 4; ++j)
      acc[i][j] = (f32x4){0.f, 0.f, 0.f, 0.f};

  const int nk = K >> 6;
  for (int kt = 0; kt < nk; ++kt){
    #pragma unroll
    for (int it = 0; it < 4; ++it){
      int ch = it*256 + tid;
      int r = ch >> 3, cc = ch & 7;
      int srcc = ((cc ^ (r & 7)) << 3);
      gload_lds16(A  + (row0 + r) * K + kt*64 + srcc, &As[ch*8]);
      gload_lds16(Bt + (long)(col0 + r) * K + kt*64 + srcc, &Bs[ch*8]);
    }
    __syncthreads();
    #pragma unroll
    for (int ks = 0; ks < 2; ++ks){
      short8 af[4], bfr[4];
      #pragma unroll
      for (int mi = 0; mi < 4; ++mi){
        int ar = wm*64 + mi*16 + l15;
        af[mi] = *(const short8*)&As[ar*64 + (((ks*4 + l4) ^ (ar & 7)) << 3)];
      }
      #pragma unroll
      for (int ni = 0; ni < 4; ++ni){
        int br = wn*64 + ni*16 + l15;
        bfr[ni] = *(const short8*)&Bs[br*64 + (((ks*4 + l4) ^ (br & 7)) << 3)];
      }
      #pragma unroll
      for (int mi = 0; mi < 4; ++mi)
        #pragma unroll
        for (int ni = 0; ni < 4; ++ni)
          acc[mi][ni] = __builtin_amdgcn_mfma_f32_16x16x32_bf16(bfr[ni], af[mi], acc[mi][ni], 0, 0, 0);
    }
    __syncthreads();
  }

  if (MODE == 2){
    float* outf = (float*)out;
    #pragma unroll
    for (int mi = 0; mi < 4; ++mi){
      long row = row0 + wm*64 + mi*16 + l15;
      #pragma unroll
      for (int ni = 0; ni < 4; ++ni){
        int colg = col0 + wn*64 + ni*16 + 4*l4;
        float4 bv = *(const float4*)&bias[colg];
        long idx = row * N + colg;
        ushort4 rv = *(const ushort4*)&res[idx];
        float4 o;
        o.x = acc[mi][ni][0] + bv.x + bf2f(rv.x);
        o.y = acc[mi][ni][1] + bv.y + bf2f(rv.y);
        o.z = acc[mi][ni][2] + bv.z + bf2f(rv.z);
        o.w = acc[mi][ni][3] + bv.w + bf2f(rv.w);
        *(float4*)&outf[idx] = o;
      }
    }
  } else {
    unsigned short* outp = (unsigned short*)out;
    #pragma unroll
    for (int mi = 0; mi < 4; ++mi){
      long row = row0 + wm*64 + mi*16 + l15;
      #pragma unroll
      for (int ni = 0; ni < 4; ++ni){
        int colg = col0 + wn*64 + ni*16 + 4*l4;
        float4 bv = *(const float4*)&bias[colg];
        float v0 = acc[mi][ni][0] + bv.x;
        float v1 = acc[mi][ni][1] + bv.y;
        float v2 = acc[mi][ni][2] + bv.z;
        float v3 = acc[mi][ni][3] + bv.w;
        if (MODE == 1){ v0 = gelu_f(v0); v1 = gelu_f(v1); v2 = gelu_f(v2); v3 = gelu_f(v3); }
        uint2 dv;
        dv.x = ((unsigned int)f2bf(v1) << 16) | f2bf(v0);
        dv.y = ((unsigned int)f2bf(v3) << 16) | f2bf(v2);
        *(uint2*)&outp[row * N + colg] = dv;
      }
    }
  }
}

// ---------------- Window attention: one WAVE = one (window, head) ------------
// Swapped QK^T and PV: packed uint2 P writes (16) and ao writes (8).
__global__ __launch_bounds__(64, 3) void attn_kernel(
    const unsigned short* __restrict__ qkv,
    const float* __restrict__ bt,
    unsigned short* __restrict__ ao){
  __shared__ unsigned short P[64*64];
  const int lane = threadIdx.x;
  const int wb = blockIdx.x;
  const int w = wb >> 3, h = wb & 7;
  const int bidx = w >> 10, rem = w & 1023;
  const int wy = rem >> 5, wx = rem & 31;
  const long tok0 = (long)bidx * 65536 + (long)wy * 2048 + wx * 8;
  const int l15 = lane & 15, l4 = lane >> 4;

  short8 qf[4], kf[4];
  #pragma unroll
  for (int t = 0; t < 4; ++t){
    int n = t*16 + l15;
    long tok = tok0 + (n >> 3) * 256 + (n & 7);
    qf[t] = *(const short8*)(qkv + tok*768 +       h*32 + 8*l4);
    kf[t] = *(const short8*)(qkv + tok*768 + 256 + h*32 + 8*l4);
  }
  // swapped: s[mi][ni]: lane holds q = mi*16+l15, k = ni*16+4*l4+{0..3}
  f32x4 s[4][4];
  #pragma unroll
  for (int i = 0; i < 4; ++i)
    #pragma unroll
    for (int j = 0; j < 4; ++j)
      s[i][j] = (f32x4){0.f, 0.f, 0.f, 0.f};
  #pragma unroll
  for (int mi = 0; mi < 4; ++mi)
    #pragma unroll
    for (int ni = 0; ni < 4; ++ni)
      s[mi][ni] = __builtin_amdgcn_mfma_f32_16x16x32_bf16(kf[ni], qf[mi], s[mi][ni], 0, 0, 0);

  const float scale = 0.17677669529663687f; // 1/sqrt(32)
  #pragma unroll
  for (int mi = 0; mi < 4; ++mi){
    int q = mi*16 + l15;
    int ny = q >> 3, nx = q & 7;
    #pragma unroll
    for (int ni = 0; ni < 4; ++ni){
      #pragma unroll
      for (int j = 0; j < 4; ++j){
        int k = ni*16 + 4*l4 + j;
        int db = (ny - (k >> 3) + 7) * 15 + (nx - (k & 7) + 7);
        s[mi][ni][j] = s[mi][ni][j] * scale + bt[db*8 + h];
      }
    }
    float mx = -1e30f;
    #pragma unroll
    for (int ni = 0; ni < 4; ++ni)
      #pragma unroll
      for (int j = 0; j < 4; ++j)
        mx = fmaxf(mx, s[mi][ni][j]);
    mx = fmaxf(mx, __shfl_xor(mx, 16));
    mx = fmaxf(mx, __shfl_xor(mx, 32));
    float sm = 0.f;
    #pragma unroll
    for (int ni = 0; ni < 4; ++ni)
      #pragma unroll
      for (int j = 0; j < 4; ++j){
        float p = __expf(s[mi][ni][j] - mx);
        s[mi][ni][j] = p;
        sm += p;
      }
    sm += __shfl_xor(sm, 16);
    sm += __shfl_xor(sm, 32);
    float inv = __builtin_amdgcn_rcpf(sm);
    #pragma unroll
    for (int ni = 0; ni < 4; ++ni){
      uint2 dv;
      dv.x = ((unsigned int)f2bf(s[mi][ni][1]*inv) << 16) | f2bf(s[mi][ni][0]*inv);
      dv.y = ((unsigned int)f2bf(s[mi][ni][3]*inv) << 16) | f2bf(s[mi][ni][2]*inv);
      int g = ni*2 + (l4 >> 1);
      *(uint2*)&P[q*64 + ((g ^ (q & 7)) << 3) + 4*(l4 & 1)] = dv;
    }
  }
  // single wave: no barrier needed (compiler orders via lgkmcnt)

  // PV swapped: o[mi][ni]: lane holds token = mi*16+l15, d = ni*16+4*l4+{0..3}
  f32x4 o[4][2];
  #pragma unroll
  for (int i = 0; i < 4; ++i)
    #pragma unroll
    for (int j = 0; j < 2; ++j)
      o[i][j] = (f32x4){0.f, 0.f, 0.f, 0.f};
  #pragma unroll
  for (int kt = 0; kt < 2; ++kt){
    short8 vf[2];
    #pragma unroll
    for (int ni = 0; ni < 2; ++ni){
      union { unsigned short u[8]; short8 v; } tmp;
      #pragma unroll
      for (int i = 0; i < 8; ++i){
        int kk = kt*32 + 8*l4 + i;
        long tok = tok0 + (kk >> 3) * 256 + (kk & 7);
        tmp.u[i] = qkv[tok*768 + 512 + h*32 + ni*16 + l15];
      }
      vf[ni] = tmp.v;
    }
    #pragma unroll
    for (int mi = 0; mi < 4; ++mi){
      int r = mi*16 + l15;
      short8 pf = *(const short8*)&P[r*64 + (((kt*4 + l4) ^ (r & 7)) << 3)];
      #pragma unroll
      for (int ni = 0; ni < 2; ++ni)
        o[mi][ni] = __builtin_amdgcn_mfma_f32_16x16x32_bf16(vf[ni], pf, o[mi][ni], 0, 0, 0);
    }
  }
  #pragma unroll
  for (int mi = 0; mi < 4; ++mi){
    int t = mi*16 + l15;
    long tok = tok0 + (t >> 3) * 256 + (t & 7);
    #pragma unroll
    for (int ni = 0; ni < 2; ++ni){
      uint2 dv;
      dv.x = ((unsigned int)f2bf(o[mi][ni][1]) << 16) | f2bf(o[mi][ni][0]);
      dv.y = ((unsigned int)f2bf(o[mi][ni][3]) << 16) | f2bf(o[mi][ni][2]);
      *(uint2*)&ao[tok*256 + h*32 + ni*16 + 4*l4] = dv;
    }
  }
}

// ---------------- proj + residual + LN2 fused (R13 version) ------------------
__global__ __launch_bounds__(512, 4) void proj_ln2(
    const unsigned short* __restrict__ A,
    const unsigned short* __restrict__ Bt,
    const float* __restrict__ bias,
    const float* __restrict__ res,
    const float* __restrict__ g2,
    const float* __restrict__ b2,
    unsigned short* __restrict__ hout,
    unsigned short* __restrict__ hn){
  __shared__ unsigned short As[128*64];
  __shared__ unsigned short Bs[256*64];
  __shared__ float redsum[4][128];
  __shared__ float redsq[4][128];
  __shared__ float mu_s[128];
  __shared__ float rs_s[128];
  const int tid = threadIdx.x, lane = tid & 63, wave = tid >> 6;
  const int l15 = lane & 15, l4 = lane >> 4;
  const int wm = wave >> 2, wn = wave & 3;
  const long row0 = (long)blockIdx.x * 128;

  f32x4 acc[4][4];
  #pragma unroll
  for (int i = 0; i < 4; ++i)
    #pragma unroll
    for (int j = 0; j < 4; ++j)
      acc[i][j] = (f32x4){0.f, 0.f, 0.f, 0.f};

  for (int kt = 0; kt < 4; ++kt){
    #pragma unroll
    for (int it = 0; it < 2; ++it){
      int ch = it*512 + tid;
      int r = ch >> 3, cc = ch & 7;
      gload_lds16(A + (row0 + r)*256 + kt*64 + ((cc ^ (r & 7))*8), &As[ch*8]);
    }
    #pragma unroll
    for (int it = 0; it < 4; ++it){
      int ch = it*512 + tid;
      int r = ch >> 3, cc = ch & 7;
      gload_lds16(Bt + r*256 + kt*64 + ((cc ^ (r & 7))*8), &Bs[ch*8]);
    }
    __syncthreads();
    #pragma unroll
    for (int ks = 0; ks < 2; ++ks){
      short8 af[4], bf[4];
      #pragma unroll
      for (int mi = 0; mi < 4; ++mi){
        int ar = wm*64 + mi*16 + l15;
        af[mi] = *(const short8*)&As[ar*64 + (((ks*4 + l4) ^ (ar & 7))*8)];
      }
      #pragma unroll
      for (int ni = 0; ni < 4; ++ni){
        int br = wn*64 + ni*16 + l15;
        bf[ni] = *(const short8*)&Bs[br*64 + (((ks*4 + l4) ^ (br & 7))*8)];
      }
      #pragma unroll
      for (int mi = 0; mi < 4; ++mi)
        #pragma unroll
        for (int ni = 0; ni < 4; ++ni)
          acc[mi][ni] = __builtin_amdgcn_mfma_f32_16x16x32_bf16(af[mi], bf[ni], acc[mi][ni], 0, 0, 0);
    }
    __syncthreads();
  }

  float bcol[4];
  #pragma unroll
  for (int ni = 0; ni < 4; ++ni) bcol[ni] = bias[wn*64 + ni*16 + l15];
  f32x4 psum[4], psq[4];
  #pragma unroll
  for (int mi = 0; mi < 4; ++mi){
    psum[mi] = (f32x4){0.f,0.f,0.f,0.f};
    psq[mi]  = (f32x4){0.f,0.f,0.f,0.f};
    #pragma unroll
    for (int ni = 0; ni < 4; ++ni){
      int col = wn*64 + ni*16 + l15;
      #pragma unroll
      for (int j = 0; j < 4; ++j){
        long row = row0 + wm*64 + mi*16 + 4*l4 + j;
        long idx = row * 256 + col;
        float v = acc[mi][ni][j] + bcol[ni] + res[idx];
        hout[idx] = f2bf(v);
        acc[mi][ni][j] = v;
        psum[mi][j] += v;
        psq[mi][j]  += v * v;
      }
    }
  }
  #pragma unroll
  for (int mi = 0; mi < 4; ++mi){
    #pragma unroll
    for (int j = 0; j < 4; ++j){
      float s = psum[mi][j], q = psq[mi][j];
      #pragma unroll
      for (int m = 1; m < 16; m <<= 1){
        s += __shfl_xor(s, m);
        q += __shfl_xor(q, m);
      }
      if (l15 == 0){
        int rl = wm*64 + mi*16 + 4*l4 + j;
        redsum[wn][rl] = s;
        redsq[wn][rl]  = q;
      }
    }
  }
  __syncthreads();
  if (tid < 128){
    float s = redsum[0][tid] + redsum[1][tid] + redsum[2][tid] + redsum[3][tid];
    float q = redsq[0][tid]  + redsq[1][tid]  + redsq[2][tid]  + redsq[3][tid];
    float mu = s * (1.f/256.f);
    mu_s[tid] = mu;
    rs_s[tid] = rsqrtf(q * (1.f/256.f) - mu*mu + 1e-5f);
  }
  __syncthreads();
  float gcol[4], b2col[4];
  #pragma unroll
  for (int ni = 0; ni < 4; ++ni){
    gcol[ni]  = g2[wn*64 + ni*16 + l15];
    b2col[ni] = b2[wn*64 + ni*16 + l15];
  }
  #pragma unroll
  for (int mi = 0; mi < 4; ++mi){
    #pragma unroll
    for (int j = 0; j < 4; ++j){
      int rl = wm*64 + mi*16 + 4*l4 + j;
      float mu = mu_s[rl], rs = rs_s[rl];
      long row = row0 + rl;
      #pragma unroll
      for (int ni = 0; ni < 4; ++ni){
        int col = wn*64 + ni*16 + l15;
        hn[row*256 + col] = f2bf((acc[mi][ni][j] - mu)*rs*gcol[ni] + b2col[ni]);
      }
    }
  }
}

extern "C" void kernel_launch(void* const* d_in, const int* in_sizes, int n_in,
                              void* d_out, int out_size, void* d_ws, size_t ws_size,
                              hipStream_t stream){
  const float* x      = (const float*)d_in[0];
  const float* ln1_g  = (const float*)d_in[1];
  const float* ln1_b  = (const float*)d_in[2];
  const float* qkv_w  = (const float*)d_in[3];
  const float* qkv_b  = (const float*)d_in[4];
  const float* proj_w = (const float*)d_in[5];
  const float* proj_b = (const float*)d_in[6];
  const float* btab   = (const float*)d_in[7];
  const float* ln2_g  = (const float*)d_in[8];
  const float* ln2_b  = (const float*)d_in[9];
  const float* fc1_w  = (const float*)d_in[10];
  const float* fc1_b  = (const float*)d_in[11];
  const float* fc2_w  = (const float*)d_in[12];
  const float* fc2_b  = (const float*)d_in[13];

  const long M = (long)in_sizes[0] / 256;  // 262144 tokens

  char* ws = (char*)d_ws;
  unsigned short* xn  = (unsigned short*)(ws);
  unsigned short* ao  = xn;
  unsigned short* act = xn;
  unsigned short* qkv = (unsigned short*)(ws + 134217728);
  unsigned short* hn  = (unsigned short*)(ws + 536870912);
  unsigned short* wq  = (unsigned short*)(ws + 671088640);
  unsigned short* wp  = wq + 256*768;
  unsigned short* w1  = wp + 256*256;
  unsigned short* w2  = w1 + 256*1024;
  unsigned short* hh  = (unsigned short*)(ws + (712ull << 20));
  float* outf = (float*)d_out;

  // all 4 weight transposes in one launch (786432 elems)
  wconv4<<<3072, 256, 0, stream>>>(qkv_w, proj_w, fc1_w, fc2_w, wq, wp, w1, w2);

  // LN1
  ln_kernel<<<M/4, 256, 0, stream>>>(x, ln1_g, ln1_b, xn);
  // QKV (swizzled): nbx=6
  gemm_bt<0><<<6 * (M/128), 256, 0, stream>>>(xn, wq, qkv_b, nullptr, qkv, 768, 256, 6);
  // window attention: one wave per (window, head)
  attn_kernel<<<(M/64) * 8, 64, 0, stream>>>(qkv, btab, ao);
  // proj + residual + LN2  (h bf16 -> hh, hn bf16)
  proj_ln2<<<M/128, 512, 0, stream>>>(ao, wp, proj_b, x, ln2_g, ln2_b, hh, hn);
  // FC1 + GELU (swizzled): nbx=8
  gemm_bt<1><<<8 * (M/128), 256, 0, stream>>>(hn, w1, fc1_b, nullptr, act, 1024, 256, 8);
  // FC2 + residual(h bf16) -> out f32 (swizzled): nbx=2
  gemm_bt<2><<<2 * (M/128), 256, 0, stream>>>(act, w2, fc2_b, hh, outf, 256, 1024, 2);
}

// Round 18
// 1167.351 us; speedup vs baseline: 1.2406x; 1.0738x over previous
//
#include <hip/hip_runtime.h>
#include <hip/hip_bf16.h>
#include <math.h>

typedef __attribute__((ext_vector_type(8))) short short8;
typedef __attribute__((ext_vector_type(4))) float f32x4;

__device__ __forceinline__ unsigned short f2bf(float f){
  union { __hip_bfloat16 h; unsigned short u; } cv;
  cv.h = __float2bfloat16(f);
  return cv.u;
}

__device__ __forceinline__ float bf2f(unsigned short u){
  union { unsigned int i; float f; } v;
  v.i = ((unsigned int)u) << 16;
  return v.f;
}

// gelu via sigmoid: 0.5v(1+tanh(u)) == v*sigmoid(2u), exp2-folded constants
__device__ __forceinline__ float gelu_f(float v){
  float v2 = v * v;
  float nw = v * fmaf(-0.10294364f, v2, -2.3022090f);  // -2u*log2(e)
  float e  = __builtin_amdgcn_exp2f(nw);
  return v * __builtin_amdgcn_rcpf(1.f + e);
}

__device__ __forceinline__ void gload_lds16(const void* g, void* l){
  __builtin_amdgcn_global_load_lds(
      (const __attribute__((address_space(1))) void*)g,
      (__attribute__((address_space(3))) void*)l, 16, 0, 0);
}

// ---------------- all four weight transposes in one launch -------------------
// wq/wp/w1 bf16; w2 fp8 e4m3 pre-scaled by 64 (values ~0.02 -> ~1.3 normal range)
__global__ __launch_bounds__(256) void wconv4(
    const float* __restrict__ qkv_w, const float* __restrict__ proj_w,
    const float* __restrict__ fc1_w, const float* __restrict__ fc2_w,
    unsigned short* __restrict__ wq, unsigned short* __restrict__ wp,
    unsigned short* __restrict__ w1, unsigned char* __restrict__ w2){
  int idx = blockIdx.x * 256 + threadIdx.x;
  if (idx < 196608){                       // qkv: K=256 N=768
    int k = idx / 768, n = idx % 768;
    wq[n*256 + k] = f2bf(qkv_w[idx]);
  } else if (idx < 262144){                // proj: K=256 N=256
    int l = idx - 196608;
    int k = l >> 8, n = l & 255;
    wp[n*256 + k] = f2bf(proj_w[l]);
  } else if (idx < 524288){                // fc1: K=256 N=1024
    int l = idx - 262144;
    int k = l >> 10, n = l & 1023;
    w1[n*256 + k] = f2bf(fc1_w[l]);
  } else {                                 // fc2: K=1024 N=256 -> fp8 * 64
    int l = idx - 524288;
    int k = l >> 8, n = l & 255;
    float v = fc2_w[l] * 64.f;
    w2[n*1024 + k] = (unsigned char)(__builtin_amdgcn_cvt_pk_fp8_f32(v, v, 0, 0) & 0xff);
  }
}

// ---------------- LayerNorm: x f32 [M][256] -> out bf16 [M][256] -------------
__global__ __launch_bounds__(256) void ln_kernel(
    const float* __restrict__ x, const float* __restrict__ g,
    const float* __restrict__ b, unsigned short* __restrict__ out){
  const int lane = threadIdx.x & 63;
  const int wv = threadIdx.x >> 6;
  const long row = (long)blockIdx.x * 4 + wv;
  const float4 xv = ((const float4*)(x + row * 256))[lane];
  float s  = xv.x + xv.y + xv.z + xv.w;
  float s2 = xv.x*xv.x + xv.y*xv.y + xv.z*xv.z + xv.w*xv.w;
  #pragma unroll
  for (int m = 1; m < 64; m <<= 1){
    s  += __shfl_xor(s,  m);
    s2 += __shfl_xor(s2, m);
  }
  float mu = s * (1.f/256.f);
  float rs = rsqrtf(s2 * (1.f/256.f) - mu*mu + 1e-5f);
  float4 gv = ((const float4*)g)[lane];
  float4 bv = ((const float4*)b)[lane];
  ushort4 o;
  o.x = f2bf((xv.x - mu)*rs*gv.x + bv.x);
  o.y = f2bf((xv.y - mu)*rs*gv.y + bv.y);
  o.z = f2bf((xv.z - mu)*rs*gv.z + bv.z);
  o.w = f2bf((xv.w - mu)*rs*gv.w + bv.w);
  ((ushort4*)(out + row * 256))[lane] = o;
}

// ---------------- bf16 GEMM: A[M][K] @ Wt[N][K] -> out [M][N] ----------------
// 256 threads / 4 waves, 128x128 tile, BK=64, XOR-swizzled LDS, XCD banding.
// SWAPPED MFMA: per lane row = ..+l15, cols = ..+4*l4+{0..3}
// MODE 0: out bf16 = acc + bias                 (direct uint2 stores)
// MODE 1: out fp8  = cvt_fp8(8*gelu(acc+bias))  (direct uint stores)
template<int MODE>
__global__ __launch_bounds__(256, 4) void gemm_bt(
    const unsigned short* __restrict__ A,
    const unsigned short* __restrict__ Bt,
    const float* __restrict__ bias,
    void* __restrict__ out,
    int N, int K, int nbx){
  __shared__ unsigned short S[2*128*64];
  unsigned short* As = S;
  unsigned short* Bs = S + 128*64;
  const int tid  = threadIdx.x;
  const int lane = tid & 63;
  const int wave = tid >> 6;
  const int wm = wave >> 1, wn = wave & 1;

  const int nby  = gridDim.x / nbx;
  const int bid  = blockIdx.x;
  const int xcd  = bid & 7;
  const int local = bid >> 3;
  const int lrow = local / nbx;
  const int rowb = xcd * (nby >> 3) + lrow;
  const int colb = local - lrow * nbx;
  const long row0 = (long)rowb * 128;
  const int  col0 = colb * 128;
  const int l15 = lane & 15, l4 = lane >> 4;

  f32x4 acc[4][4];
  #pragma unroll
  for (int i = 0; i < 4; ++i)
    #pragma unroll
    for (int j = 0; j < 4; ++j)
      acc[i][j] = (f32x4){0.f, 0.f, 0.f, 0.f};

  const int nk = K >> 6;
  for (int kt = 0; kt < nk; ++kt){
    #pragma unroll
    for (int it = 0; it < 4; ++it){
      int ch = it*256 + tid;
      int r = ch >> 3, cc = ch & 7;
      int srcc = ((cc ^ (r & 7)) << 3);
      gload_lds16(A  + (row0 + r) * K + kt*64 + srcc, &As[ch*8]);
      gload_lds16(Bt + (long)(col0 + r) * K + kt*64 + srcc, &Bs[ch*8]);
    }
    __syncthreads();
    #pragma unroll
    for (int ks = 0; ks < 2; ++ks){
      short8 af[4], bfr[4];
      #pragma unroll
      for (int mi = 0; mi < 4; ++mi){
        int ar = wm*64 + mi*16 + l15;
        af[mi] = *(const short8*)&As[ar*64 + (((ks*4 + l4) ^ (ar & 7)) << 3)];
      }
      #pragma unroll
      for (int ni = 0; ni < 4; ++ni){
        int br = wn*64 + ni*16 + l15;
        bfr[ni] = *(const short8*)&Bs[br*64 + (((ks*4 + l4) ^ (br & 7)) << 3)];
      }
      #pragma unroll
      for (int mi = 0; mi < 4; ++mi)
        #pragma unroll
        for (int ni = 0; ni < 4; ++ni)
          acc[mi][ni] = __builtin_amdgcn_mfma_f32_16x16x32_bf16(bfr[ni], af[mi], acc[mi][ni], 0, 0, 0);
    }
    __syncthreads();
  }

  if (MODE == 0){
    unsigned short* outp = (unsigned short*)out;
    #pragma unroll
    for (int mi = 0; mi < 4; ++mi){
      long row = row0 + wm*64 + mi*16 + l15;
      #pragma unroll
      for (int ni = 0; ni < 4; ++ni){
        int colg = col0 + wn*64 + ni*16 + 4*l4;
        float4 bv = *(const float4*)&bias[colg];
        uint2 dv;
        dv.x = ((unsigned int)f2bf(acc[mi][ni][1] + bv.y) << 16) | f2bf(acc[mi][ni][0] + bv.x);
        dv.y = ((unsigned int)f2bf(acc[mi][ni][3] + bv.w) << 16) | f2bf(acc[mi][ni][2] + bv.z);
        *(uint2*)&outp[row * N + colg] = dv;
      }
    }
  } else {
    // act fp8 output, scaled by 8
    unsigned char* outp = (unsigned char*)out;
    #pragma unroll
    for (int mi = 0; mi < 4; ++mi){
      long row = row0 + wm*64 + mi*16 + l15;
      #pragma unroll
      for (int ni = 0; ni < 4; ++ni){
        int colg = col0 + wn*64 + ni*16 + 4*l4;
        float4 bv = *(const float4*)&bias[colg];
        float v0 = 8.f * gelu_f(acc[mi][ni][0] + bv.x);
        float v1 = 8.f * gelu_f(acc[mi][ni][1] + bv.y);
        float v2 = 8.f * gelu_f(acc[mi][ni][2] + bv.z);
        float v3 = 8.f * gelu_f(acc[mi][ni][3] + bv.w);
        int p = __builtin_amdgcn_cvt_pk_fp8_f32(v0, v1, 0, 0);
        p = __builtin_amdgcn_cvt_pk_fp8_f32(v2, v3, p, 1);
        *(unsigned int*)&outp[row * N + colg] = (unsigned int)p;
      }
    }
  }
}

// ---------------- fp8 GEMM (fc2): act fp8 [M][1024] @ w2 fp8 [256][1024] -----
// out f32 = acc/512 + bias + res(bf16). BK=128 fp8 bytes, same swizzle/banding.
__global__ __launch_bounds__(256, 4) void gemm_fp8(
    const unsigned char* __restrict__ A,
    const unsigned char* __restrict__ Bt,
    const float* __restrict__ bias,
    const unsigned short* __restrict__ res,
    float* __restrict__ out,
    int N, int K, int nbx){
  __shared__ unsigned char S[2*128*128];   // As | Bs, 16KB each
  unsigned char* As = S;
  unsigned char* Bs = S + 128*128;
  const int tid  = threadIdx.x;
  const int lane = tid & 63;
  const int wave = tid >> 6;
  const int wm = wave >> 1, wn = wave & 1;

  const int nby  = gridDim.x / nbx;
  const int bid  = blockIdx.x;
  const int xcd  = bid & 7;
  const int local = bid >> 3;
  const int lrow = local / nbx;
  const int rowb = xcd * (nby >> 3) + lrow;
  const int colb = local - lrow * nbx;
  const long row0 = (long)rowb * 128;
  const int  col0 = colb * 128;
  const int l15 = lane & 15, l4 = lane >> 4;

  f32x4 acc[4][4];
  #pragma unroll
  for (int i = 0; i < 4; ++i)
    #pragma unroll
    for (int j = 0; j < 4; ++j)
      acc[i][j] = (f32x4){0.f, 0.f, 0.f, 0.f};

  const int nk = K >> 7;                   // BK = 128 fp8 elements
  for (int kt = 0; kt < nk; ++kt){
    #pragma unroll
    for (int it = 0; it < 4; ++it){
      int ch = it*256 + tid;               // 1024 granules of 16B per tile
      int r = ch >> 3, cc = ch & 7;
      int srcc = ((cc ^ (r & 7)) << 4);
      gload_lds16(A  + (row0 + r) * K + kt*128 + srcc, &As[ch*16]);
      gload_lds16(Bt + (long)(col0 + r) * K + kt*128 + srcc, &Bs[ch*16]);
    }
    __syncthreads();
    #pragma unroll
    for (int ks = 0; ks < 4; ++ks){        // K=32 fp8 per MFMA
      long af[4], bfr[4];
      #pragma unroll
      for (int mi = 0; mi < 4; ++mi){
        int ar = wm*64 + mi*16 + l15;
        af[mi] = *(const long*)&As[ar*128 + (((2*ks + (l4 >> 1)) ^ (ar & 7)) << 4) + 8*(l4 & 1)];
      }
      #pragma unroll
      for (int ni = 0; ni < 4; ++ni){
        int br = wn*64 + ni*16 + l15;
        bfr[ni] = *(const long*)&Bs[br*128 + (((2*ks + (l4 >> 1)) ^ (br & 7)) << 4) + 8*(l4 & 1)];
      }
      #pragma unroll
      for (int mi = 0; mi < 4; ++mi)
        #pragma unroll
        for (int ni = 0; ni < 4; ++ni)
          acc[mi][ni] = __builtin_amdgcn_mfma_f32_16x16x32_fp8_fp8(bfr[ni], af[mi], acc[mi][ni], 0, 0, 0);
    }
    __syncthreads();
  }

  const float sc = 1.f / 512.f;            // undo act*8 and w2*64
  #pragma unroll
  for (int mi = 0; mi < 4; ++mi){
    long row = row0 + wm*64 + mi*16 + l15;
    #pragma unroll
    for (int ni = 0; ni < 4; ++ni){
      int colg = col0 + wn*64 + ni*16 + 4*l4;
      float4 bv = *(const float4*)&bias[colg];
      long idx = row * N + colg;
      ushort4 rv = *(const ushort4*)&res[idx];
      float4 o;
      o.x = acc[mi][ni][0]*sc + bv.x + bf2f(rv.x);
      o.y = acc[mi][ni][1]*sc + bv.y + bf2f(rv.y);
      o.z = acc[mi][ni][2]*sc + bv.z + bf2f(rv.z);
      o.w = acc[mi][ni][3]*sc + bv.w + bf2f(rv.w);
      *(float4*)&out[idx] = o;
    }
  }
}

// ---------------- Window attention: one WAVE = one (window, head) ------------
__global__ __launch_bounds__(64, 3) void attn_kernel(
    const unsigned short* __restrict__ qkv,
    const float* __restrict__ bt,
    unsigned short* __restrict__ ao){
  __shared__ unsigned short P[64*64];
  const int lane = threadIdx.x;
  const int wb = blockIdx.x;
  const int w = wb >> 3, h = wb & 7;
  const int bidx = w >> 10, rem = w & 1023;
  const int wy = rem >> 5, wx = rem & 31;
  const long tok0 = (long)bidx * 65536 + (long)wy * 2048 + wx * 8;
  const int l15 = lane & 15, l4 = lane >> 4;

  short8 qf[4], kf[4];
  #pragma unroll
  for (int t = 0; t < 4; ++t){
    int n = t*16 + l15;
    long tok = tok0 + (n >> 3) * 256 + (n & 7);
    qf[t] = *(const short8*)(qkv + tok*768 +       h*32 + 8*l4);
    kf[t] = *(const short8*)(qkv + tok*768 + 256 + h*32 + 8*l4);
  }
  f32x4 s[4][4];
  #pragma unroll
  for (int i = 0; i < 4; ++i)
    #pragma unroll
    for (int j = 0; j < 4; ++j)
      s[i][j] = (f32x4){0.f, 0.f, 0.f, 0.f};
  #pragma unroll
  for (int mi = 0; mi < 4; ++mi)
    #pragma unroll
    for (int ni = 0; ni < 4; ++ni)
      s[mi][ni] = __builtin_amdgcn_mfma_f32_16x16x32_bf16(kf[ni], qf[mi], s[mi][ni], 0, 0, 0);

  const float scale = 0.17677669529663687f; // 1/sqrt(32)
  #pragma unroll
  for (int mi = 0; mi < 4; ++mi){
    int q = mi*16 + l15;
    int ny = q >> 3, nx = q & 7;
    #pragma unroll
    for (int ni = 0; ni < 4; ++ni){
      #pragma unroll
      for (int j = 0; j < 4; ++j){
        int k = ni*16 + 4*l4 + j;
        int db = (ny - (k >> 3) + 7) * 15 + (nx - (k & 7) + 7);
        s[mi][ni][j] = s[mi][ni][j] * scale + bt[db*8 + h];
      }
    }
    float mx = -1e30f;
    #pragma unroll
    for (int ni = 0; ni < 4; ++ni)
      #pragma unroll
      for (int j = 0; j < 4; ++j)
        mx = fmaxf(mx, s[mi][ni][j]);
    mx = fmaxf(mx, __shfl_xor(mx, 16));
    mx = fmaxf(mx, __shfl_xor(mx, 32));
    float sm = 0.f;
    #pragma unroll
    for (int ni = 0; ni < 4; ++ni)
      #pragma unroll
      for (int j = 0; j < 4; ++j){
        float p = __expf(s[mi][ni][j] - mx);
        s[mi][ni][j] = p;
        sm += p;
      }
    sm += __shfl_xor(sm, 16);
    sm += __shfl_xor(sm, 32);
    float inv = __builtin_amdgcn_rcpf(sm);
    #pragma unroll
    for (int ni = 0; ni < 4; ++ni){
      uint2 dv;
      dv.x = ((unsigned int)f2bf(s[mi][ni][1]*inv) << 16) | f2bf(s[mi][ni][0]*inv);
      dv.y = ((unsigned int)f2bf(s[mi][ni][3]*inv) << 16) | f2bf(s[mi][ni][2]*inv);
      int g = ni*2 + (l4 >> 1);
      *(uint2*)&P[q*64 + ((g ^ (q & 7)) << 3) + 4*(l4 & 1)] = dv;
    }
  }
  // single wave: no barrier needed (compiler orders via lgkmcnt)

  f32x4 o[4][2];
  #pragma unroll
  for (int i = 0; i < 4; ++i)
    #pragma unroll
    for (int j = 0; j < 2; ++j)
      o[i][j] = (f32x4){0.f, 0.f, 0.f, 0.f};
  #pragma unroll
  for (int kt = 0; kt < 2; ++kt){
    short8 vf[2];
    #pragma unroll
    for (int ni = 0; ni < 2; ++ni){
      union { unsigned short u[8]; short8 v; } tmp;
      #pragma unroll
      for (int i = 0; i < 8; ++i){
        int kk = kt*32 + 8*l4 + i;
        long tok = tok0 + (kk >> 3) * 256 + (kk & 7);
        tmp.u[i] = qkv[tok*768 + 512 + h*32 + ni*16 + l15];
      }
      vf[ni] = tmp.v;
    }
    #pragma unroll
    for (int mi = 0; mi < 4; ++mi){
      int r = mi*16 + l15;
      short8 pf = *(const short8*)&P[r*64 + (((kt*4 + l4) ^ (r & 7)) << 3)];
      #pragma unroll
      for (int ni = 0; ni < 2; ++ni)
        o[mi][ni] = __builtin_amdgcn_mfma_f32_16x16x32_bf16(vf[ni], pf, o[mi][ni], 0, 0, 0);
    }
  }
  #pragma unroll
  for (int mi = 0; mi < 4; ++mi){
    int t = mi*16 + l15;
    long tok = tok0 + (t >> 3) * 256 + (t & 7);
    #pragma unroll
    for (int ni = 0; ni < 2; ++ni){
      uint2 dv;
      dv.x = ((unsigned int)f2bf(o[mi][ni][1]) << 16) | f2bf(o[mi][ni][0]);
      dv.y = ((unsigned int)f2bf(o[mi][ni][3]) << 16) | f2bf(o[mi][ni][2]);
      *(uint2*)&ao[tok*256 + h*32 + ni*16 + 4*l4] = dv;
    }
  }
}

// ---------------- proj + residual + LN2 fused (R13 version) ------------------
__global__ __launch_bounds__(512, 4) void proj_ln2(
    const unsigned short* __restrict__ A,
    const unsigned short* __restrict__ Bt,
    const float* __restrict__ bias,
    const float* __restrict__ res,
    const float* __restrict__ g2,
    const float* __restrict__ b2,
    unsigned short* __restrict__ hout,
    unsigned short* __restrict__ hn){
  __shared__ unsigned short As[128*64];
  __shared__ unsigned short Bs[256*64];
  __shared__ float redsum[4][128];
  __shared__ float redsq[4][128];
  __shared__ float mu_s[128];
  __shared__ float rs_s[128];
  const int tid = threadIdx.x, lane = tid & 63, wave = tid >> 6;
  const int l15 = lane & 15, l4 = lane >> 4;
  const int wm = wave >> 2, wn = wave & 3;
  const long row0 = (long)blockIdx.x * 128;

  f32x4 acc[4][4];
  #pragma unroll
  for (int i = 0; i < 4; ++i)
    #pragma unroll
    for (int j = 0; j < 4; ++j)
      acc[i][j] = (f32x4){0.f, 0.f, 0.f, 0.f};

  for (int kt = 0; kt < 4; ++kt){
    #pragma unroll
    for (int it = 0; it < 2; ++it){
      int ch = it*512 + tid;
      int r = ch >> 3, cc = ch & 7;
      gload_lds16(A + (row0 + r)*256 + kt*64 + ((cc ^ (r & 7))*8), &As[ch*8]);
    }
    #pragma unroll
    for (int it = 0; it < 4; ++it){
      int ch = it*512 + tid;
      int r = ch >> 3, cc = ch & 7;
      gload_lds16(Bt + r*256 + kt*64 + ((cc ^ (r & 7))*8), &Bs[ch*8]);
    }
    __syncthreads();
    #pragma unroll
    for (int ks = 0; ks < 2; ++ks){
      short8 af[4], bf[4];
      #pragma unroll
      for (int mi = 0; mi < 4; ++mi){
        int ar = wm*64 + mi*16 + l15;
        af[mi] = *(const short8*)&As[ar*64 + (((ks*4 + l4) ^ (ar & 7))*8)];
      }
      #pragma unroll
      for (int ni = 0; ni < 4; ++ni){
        int br = wn*64 + ni*16 + l15;
        bf[ni] = *(const short8*)&Bs[br*64 + (((ks*4 + l4) ^ (br & 7))*8)];
      }
      #pragma unroll
      for (int mi = 0; mi < 4; ++mi)
        #pragma unroll
        for (int ni = 0; ni < 4; ++ni)
          acc[mi][ni] = __builtin_amdgcn_mfma_f32_16x16x32_bf16(af[mi], bf[ni], acc[mi][ni], 0, 0, 0);
    }
    __syncthreads();
  }

  float bcol[4];
  #pragma unroll
  for (int ni = 0; ni < 4; ++ni) bcol[ni] = bias[wn*64 + ni*16 + l15];
  f32x4 psum[4], psq[4];
  #pragma unroll
  for (int mi = 0; mi < 4; ++mi){
    psum[mi] = (f32x4){0.f,0.f,0.f,0.f};
    psq[mi]  = (f32x4){0.f,0.f,0.f,0.f};
    #pragma unroll
    for (int ni = 0; ni < 4; ++ni){
      int col = wn*64 + ni*16 + l15;
      #pragma unroll
      for (int j = 0; j < 4; ++j){
        long row = row0 + wm*64 + mi*16 + 4*l4 + j;
        long idx = row * 256 + col;
        float v = acc[mi][ni][j] + bcol[ni] + res[idx];
        hout[idx] = f2bf(v);
        acc[mi][ni][j] = v;
        psum[mi][j] += v;
        psq[mi][j]  += v * v;
      }
    }
  }
  #pragma unroll
  for (int mi = 0; mi < 4; ++mi){
    #pragma unroll
    for (int j = 0; j < 4; ++j){
      float s = psum[mi][j], q = psq[mi][j];
      #pragma unroll
      for (int m = 1; m < 16; m <<= 1){
        s += __shfl_xor(s, m);
        q += __shfl_xor(q, m);
      }
      if (l15 == 0){
        int rl = wm*64 + mi*16 + 4*l4 + j;
        redsum[wn][rl] = s;
        redsq[wn][rl]  = q;
      }
    }
  }
  __syncthreads();
  if (tid < 128){
    float s = redsum[0][tid] + redsum[1][tid] + redsum[2][tid] + redsum[3][tid];
    float q = redsq[0][tid]  + redsq[1][tid]  + redsq[2][tid]  + redsq[3][tid];
    float mu = s * (1.f/256.f);
    mu_s[tid] = mu;
    rs_s[tid] = rsqrtf(q * (1.f/256.f) - mu*mu + 1e-5f);
  }
  __syncthreads();
  float gcol[4], b2col[4];
  #pragma unroll
  for (int ni = 0; ni < 4; ++ni){
    gcol[ni]  = g2[wn*64 + ni*16 + l15];
    b2col[ni] = b2[wn*64 + ni*16 + l15];
  }
  #pragma unroll
  for (int mi = 0; mi < 4; ++mi){
    #pragma unroll
    for (int j = 0; j < 4; ++j){
      int rl = wm*64 + mi*16 + 4*l4 + j;
      float mu = mu_s[rl], rs = rs_s[rl];
      long row = row0 + rl;
      #pragma unroll
      for (int ni = 0; ni < 4; ++ni){
        int col = wn*64 + ni*16 + l15;
        hn[row*256 + col] = f2bf((acc[mi][ni][j] - mu)*rs*gcol[ni] + b2col[ni]);
      }
    }
  }
}

extern "C" void kernel_launch(void* const* d_in, const int* in_sizes, int n_in,
                              void* d_out, int out_size, void* d_ws, size_t ws_size,
                              hipStream_t stream){
  const float* x      = (const float*)d_in[0];
  const float* ln1_g  = (const float*)d_in[1];
  const float* ln1_b  = (const float*)d_in[2];
  const float* qkv_w  = (const float*)d_in[3];
  const float* qkv_b  = (const float*)d_in[4];
  const float* proj_w = (const float*)d_in[5];
  const float* proj_b = (const float*)d_in[6];
  const float* btab   = (const float*)d_in[7];
  const float* ln2_g  = (const float*)d_in[8];
  const float* ln2_b  = (const float*)d_in[9];
  const float* fc1_w  = (const float*)d_in[10];
  const float* fc1_b  = (const float*)d_in[11];
  const float* fc2_w  = (const float*)d_in[12];
  const float* fc2_b  = (const float*)d_in[13];

  const long M = (long)in_sizes[0] / 256;  // 262144 tokens

  char* ws = (char*)d_ws;
  // Layout (time-disjoint overlaps):
  //   [0, 268MB):       xn -> ao -> act8 (fp8, 268MB spans dead xn+qkv space)
  //   [134, 536.9MB):   qkv
  //   [536.9, 671MB):   hn
  //   [671, ~674MB):    weights (wq/wp/w1 bf16, w2 fp8)
  //   [712MiB, +134MB): hh (bf16 residual trunk)
  unsigned short* xn   = (unsigned short*)(ws);
  unsigned short* ao   = xn;
  unsigned char*  act8 = (unsigned char*)(ws);
  unsigned short* qkv  = (unsigned short*)(ws + 134217728);
  unsigned short* hn   = (unsigned short*)(ws + 536870912);
  unsigned short* wq   = (unsigned short*)(ws + 671088640);
  unsigned short* wp   = wq + 256*768;
  unsigned short* w1   = wp + 256*256;
  unsigned char*  w2f8 = (unsigned char*)(w1 + 256*1024);
  unsigned short* hh   = (unsigned short*)(ws + (712ull << 20));
  float* outf = (float*)d_out;

  // all 4 weight transposes in one launch (786432 elems)
  wconv4<<<3072, 256, 0, stream>>>(qkv_w, proj_w, fc1_w, fc2_w, wq, wp, w1, w2f8);

  // LN1
  ln_kernel<<<M/4, 256, 0, stream>>>(x, ln1_g, ln1_b, xn);
  // QKV (swizzled): nbx=6
  gemm_bt<0><<<6 * (M/128), 256, 0, stream>>>(xn, wq, qkv_b, qkv, 768, 256, 6);
  // window attention: one wave per (window, head)
  attn_kernel<<<(M/64) * 8, 64, 0, stream>>>(qkv, btab, ao);
  // proj + residual + LN2  (h bf16 -> hh, hn bf16)
  proj_ln2<<<M/128, 512, 0, stream>>>(ao, wp, proj_b, x, ln2_g, ln2_b, hh, hn);
  // FC1 + GELU -> act fp8 (swizzled): nbx=8
  gemm_bt<1><<<8 * (M/128), 256, 0, stream>>>(hn, w1, fc1_b, act8, 1024, 256, 8);
  // FC2 fp8 + residual(hh bf16) -> out f32 (swizzled): nbx=2
  gemm_fp8<<<2 * (M/128), 256, 0, stream>>>(act8, w2f8, fc2_b, hh, outf, 256, 1024, 2);
}

// Round 19
// 1111.524 us; speedup vs baseline: 1.3029x; 1.0502x over previous
//
#include <hip/hip_runtime.h>
#include <hip/hip_bf16.h>
#include <math.h>

typedef __attribute__((ext_vector_type(8))) short short8;
typedef __attribute__((ext_vector_type(4))) float f32x4;

__device__ __forceinline__ unsigned short f2bf(float f){
  union { __hip_bfloat16 h; unsigned short u; } cv;
  cv.h = __float2bfloat16(f);
  return cv.u;
}

__device__ __forceinline__ float bf2f(unsigned short u){
  union { unsigned int i; float f; } v;
  v.i = ((unsigned int)u) << 16;
  return v.f;
}

__device__ __forceinline__ unsigned char f2fp8(float v){
  return (unsigned char)(__builtin_amdgcn_cvt_pk_fp8_f32(v, v, 0, 0) & 0xff);
}

// gelu via sigmoid: 0.5v(1+tanh(u)) == v*sigmoid(2u), exp2-folded constants
__device__ __forceinline__ float gelu_f(float v){
  float v2 = v * v;
  float nw = v * fmaf(-0.10294364f, v2, -2.3022090f);  // -2u*log2(e)
  float e  = __builtin_amdgcn_exp2f(nw);
  return v * __builtin_amdgcn_rcpf(1.f + e);
}

__device__ __forceinline__ void gload_lds16(const void* g, void* l){
  __builtin_amdgcn_global_load_lds(
      (const __attribute__((address_space(1))) void*)g,
      (__attribute__((address_space(3))) void*)l, 16, 0, 0);
}

// ---------------- all four weight transposes in one launch -------------------
// wq/wp bf16; w1 fp8 e4m3 *64; w2 fp8 e4m3 *64
__global__ __launch_bounds__(256) void wconv4(
    const float* __restrict__ qkv_w, const float* __restrict__ proj_w,
    const float* __restrict__ fc1_w, const float* __restrict__ fc2_w,
    unsigned short* __restrict__ wq, unsigned short* __restrict__ wp,
    unsigned char* __restrict__ w1, unsigned char* __restrict__ w2){
  int idx = blockIdx.x * 256 + threadIdx.x;
  if (idx < 196608){                       // qkv: K=256 N=768
    int k = idx / 768, n = idx % 768;
    wq[n*256 + k] = f2bf(qkv_w[idx]);
  } else if (idx < 262144){                // proj: K=256 N=256
    int l = idx - 196608;
    int k = l >> 8, n = l & 255;
    wp[n*256 + k] = f2bf(proj_w[l]);
  } else if (idx < 524288){                // fc1: K=256 N=1024 -> fp8 * 64
    int l = idx - 262144;
    int k = l >> 10, n = l & 1023;
    w1[n*256 + k] = f2fp8(fc1_w[l] * 64.f);
  } else {                                 // fc2: K=1024 N=256 -> fp8 * 64
    int l = idx - 524288;
    int k = l >> 8, n = l & 255;
    w2[n*1024 + k] = f2fp8(fc2_w[l] * 64.f);
  }
}

// ---------------- LayerNorm: x f32 [M][256] -> out bf16 [M][256] -------------
__global__ __launch_bounds__(256) void ln_kernel(
    const float* __restrict__ x, const float* __restrict__ g,
    const float* __restrict__ b, unsigned short* __restrict__ out){
  const int lane = threadIdx.x & 63;
  const int wv = threadIdx.x >> 6;
  const long row = (long)blockIdx.x * 4 + wv;
  const float4 xv = ((const float4*)(x + row * 256))[lane];
  float s  = xv.x + xv.y + xv.z + xv.w;
  float s2 = xv.x*xv.x + xv.y*xv.y + xv.z*xv.z + xv.w*xv.w;
  #pragma unroll
  for (int m = 1; m < 64; m <<= 1){
    s  += __shfl_xor(s,  m);
    s2 += __shfl_xor(s2, m);
  }
  float mu = s * (1.f/256.f);
  float rs = rsqrtf(s2 * (1.f/256.f) - mu*mu + 1e-5f);
  float4 gv = ((const float4*)g)[lane];
  float4 bv = ((const float4*)b)[lane];
  ushort4 o;
  o.x = f2bf((xv.x - mu)*rs*gv.x + bv.x);
  o.y = f2bf((xv.y - mu)*rs*gv.y + bv.y);
  o.z = f2bf((xv.z - mu)*rs*gv.z + bv.z);
  o.w = f2bf((xv.w - mu)*rs*gv.w + bv.w);
  ((ushort4*)(out + row * 256))[lane] = o;
}

// ---------------- bf16 GEMM (qkv): A[M][K] @ Wt[N][K] -> out bf16 ------------
__global__ __launch_bounds__(256, 4) void gemm_bt(
    const unsigned short* __restrict__ A,
    const unsigned short* __restrict__ Bt,
    const float* __restrict__ bias,
    unsigned short* __restrict__ out,
    int N, int K, int nbx){
  __shared__ unsigned short S[2*128*64];
  unsigned short* As = S;
  unsigned short* Bs = S + 128*64;
  const int tid  = threadIdx.x;
  const int lane = tid & 63;
  const int wave = tid >> 6;
  const int wm = wave >> 1, wn = wave & 1;

  const int nby  = gridDim.x / nbx;
  const int bid  = blockIdx.x;
  const int xcd  = bid & 7;
  const int local = bid >> 3;
  const int lrow = local / nbx;
  const int rowb = xcd * (nby >> 3) + lrow;
  const int colb = local - lrow * nbx;
  const long row0 = (long)rowb * 128;
  const int  col0 = colb * 128;
  const int l15 = lane & 15, l4 = lane >> 4;

  f32x4 acc[4][4];
  #pragma unroll
  for (int i = 0; i < 4; ++i)
    #pragma unroll
    for (int j = 0; j < 4; ++j)
      acc[i][j] = (f32x4){0.f, 0.f, 0.f, 0.f};

  const int nk = K >> 6;
  for (int kt = 0; kt < nk; ++kt){
    #pragma unroll
    for (int it = 0; it < 4; ++it){
      int ch = it*256 + tid;
      int r = ch >> 3, cc = ch & 7;
      int srcc = ((cc ^ (r & 7)) << 3);
      gload_lds16(A  + (row0 + r) * K + kt*64 + srcc, &As[ch*8]);
      gload_lds16(Bt + (long)(col0 + r) * K + kt*64 + srcc, &Bs[ch*8]);
    }
    __syncthreads();
    #pragma unroll
    for (int ks = 0; ks < 2; ++ks){
      short8 af[4], bfr[4];
      #pragma unroll
      for (int mi = 0; mi < 4; ++mi){
        int ar = wm*64 + mi*16 + l15;
        af[mi] = *(const short8*)&As[ar*64 + (((ks*4 + l4) ^ (ar & 7)) << 3)];
      }
      #pragma unroll
      for (int ni = 0; ni < 4; ++ni){
        int br = wn*64 + ni*16 + l15;
        bfr[ni] = *(const short8*)&Bs[br*64 + (((ks*4 + l4) ^ (br & 7)) << 3)];
      }
      #pragma unroll
      for (int mi = 0; mi < 4; ++mi)
        #pragma unroll
        for (int ni = 0; ni < 4; ++ni)
          acc[mi][ni] = __builtin_amdgcn_mfma_f32_16x16x32_bf16(bfr[ni], af[mi], acc[mi][ni], 0, 0, 0);
    }
    __syncthreads();
  }

  #pragma unroll
  for (int mi = 0; mi < 4; ++mi){
    long row = row0 + wm*64 + mi*16 + l15;
    #pragma unroll
    for (int ni = 0; ni < 4; ++ni){
      int colg = col0 + wn*64 + ni*16 + 4*l4;
      float4 bv = *(const float4*)&bias[colg];
      uint2 dv;
      dv.x = ((unsigned int)f2bf(acc[mi][ni][1] + bv.y) << 16) | f2bf(acc[mi][ni][0] + bv.x);
      dv.y = ((unsigned int)f2bf(acc[mi][ni][3] + bv.w) << 16) | f2bf(acc[mi][ni][2] + bv.z);
      *(uint2*)&out[row * N + colg] = dv;
    }
  }
}

// ---------------- fp8 GEMM: A fp8 [M][K] @ Bt fp8 [N][K] ---------------------
// BK=128 fp8, XOR-granule swizzle, XCD banding, swapped MFMA.
// MODE 1: out fp8 = cvt(8 * gelu(acc*s + bias))
// MODE 2: out f32 = acc*s + bias + res(bf16)
template<int MODE>
__global__ __launch_bounds__(256, 4) void gemm_fp8(
    const unsigned char* __restrict__ A,
    const unsigned char* __restrict__ Bt,
    const float* __restrict__ bias,
    const unsigned short* __restrict__ res,
    void* __restrict__ out,
    int N, int K, int nbx, float sc){
  __shared__ unsigned char S[2*128*128];
  unsigned char* As = S;
  unsigned char* Bs = S + 128*128;
  const int tid  = threadIdx.x;
  const int lane = tid & 63;
  const int wave = tid >> 6;
  const int wm = wave >> 1, wn = wave & 1;

  const int nby  = gridDim.x / nbx;
  const int bid  = blockIdx.x;
  const int xcd  = bid & 7;
  const int local = bid >> 3;
  const int lrow = local / nbx;
  const int rowb = xcd * (nby >> 3) + lrow;
  const int colb = local - lrow * nbx;
  const long row0 = (long)rowb * 128;
  const int  col0 = colb * 128;
  const int l15 = lane & 15, l4 = lane >> 4;

  f32x4 acc[4][4];
  #pragma unroll
  for (int i = 0; i < 4; ++i)
    #pragma unroll
    for (int j = 0; j < 4; ++j)
      acc[i][j] = (f32x4){0.f, 0.f, 0.f, 0.f};

  const int nk = K >> 7;
  for (int kt = 0; kt < nk; ++kt){
    #pragma unroll
    for (int it = 0; it < 4; ++it){
      int ch = it*256 + tid;
      int r = ch >> 3, cc = ch & 7;
      int srcc = ((cc ^ (r & 7)) << 4);
      gload_lds16(A  + (row0 + r) * K + kt*128 + srcc, &As[ch*16]);
      gload_lds16(Bt + (long)(col0 + r) * K + kt*128 + srcc, &Bs[ch*16]);
    }
    __syncthreads();
    #pragma unroll
    for (int ks = 0; ks < 4; ++ks){
      long af[4], bfr[4];
      #pragma unroll
      for (int mi = 0; mi < 4; ++mi){
        int ar = wm*64 + mi*16 + l15;
        af[mi] = *(const long*)&As[ar*128 + (((2*ks + (l4 >> 1)) ^ (ar & 7)) << 4) + 8*(l4 & 1)];
      }
      #pragma unroll
      for (int ni = 0; ni < 4; ++ni){
        int br = wn*64 + ni*16 + l15;
        bfr[ni] = *(const long*)&Bs[br*128 + (((2*ks + (l4 >> 1)) ^ (br & 7)) << 4) + 8*(l4 & 1)];
      }
      #pragma unroll
      for (int mi = 0; mi < 4; ++mi)
        #pragma unroll
        for (int ni = 0; ni < 4; ++ni)
          acc[mi][ni] = __builtin_amdgcn_mfma_f32_16x16x32_fp8_fp8(bfr[ni], af[mi], acc[mi][ni], 0, 0, 0);
    }
    __syncthreads();
  }

  if (MODE == 2){
    float* outf = (float*)out;
    #pragma unroll
    for (int mi = 0; mi < 4; ++mi){
      long row = row0 + wm*64 + mi*16 + l15;
      #pragma unroll
      for (int ni = 0; ni < 4; ++ni){
        int colg = col0 + wn*64 + ni*16 + 4*l4;
        float4 bv = *(const float4*)&bias[colg];
        long idx = row * N + colg;
        ushort4 rv = *(const ushort4*)&res[idx];
        float4 o;
        o.x = acc[mi][ni][0]*sc + bv.x + bf2f(rv.x);
        o.y = acc[mi][ni][1]*sc + bv.y + bf2f(rv.y);
        o.z = acc[mi][ni][2]*sc + bv.z + bf2f(rv.z);
        o.w = acc[mi][ni][3]*sc + bv.w + bf2f(rv.w);
        *(float4*)&outf[idx] = o;
      }
    }
  } else {
    unsigned char* outp = (unsigned char*)out;
    #pragma unroll
    for (int mi = 0; mi < 4; ++mi){
      long row = row0 + wm*64 + mi*16 + l15;
      #pragma unroll
      for (int ni = 0; ni < 4; ++ni){
        int colg = col0 + wn*64 + ni*16 + 4*l4;
        float4 bv = *(const float4*)&bias[colg];
        float v0 = 8.f * gelu_f(acc[mi][ni][0]*sc + bv.x);
        float v1 = 8.f * gelu_f(acc[mi][ni][1]*sc + bv.y);
        float v2 = 8.f * gelu_f(acc[mi][ni][2]*sc + bv.z);
        float v3 = 8.f * gelu_f(acc[mi][ni][3]*sc + bv.w);
        int p = __builtin_amdgcn_cvt_pk_fp8_f32(v0, v1, 0, 0);
        p = __builtin_amdgcn_cvt_pk_fp8_f32(v2, v3, p, 1);
        *(unsigned int*)&outp[row * N + colg] = (unsigned int)p;
      }
    }
  }
}

// ---------------- Window attention: one WAVE = one (window, head) ------------
__global__ __launch_bounds__(64, 3) void attn_kernel(
    const unsigned short* __restrict__ qkv,
    const float* __restrict__ bt,
    unsigned short* __restrict__ ao){
  __shared__ unsigned short P[64*64];
  const int lane = threadIdx.x;
  const int wb = blockIdx.x;
  const int w = wb >> 3, h = wb & 7;
  const int bidx = w >> 10, rem = w & 1023;
  const int wy = rem >> 5, wx = rem & 31;
  const long tok0 = (long)bidx * 65536 + (long)wy * 2048 + wx * 8;
  const int l15 = lane & 15, l4 = lane >> 4;

  short8 qf[4], kf[4];
  #pragma unroll
  for (int t = 0; t < 4; ++t){
    int n = t*16 + l15;
    long tok = tok0 + (n >> 3) * 256 + (n & 7);
    qf[t] = *(const short8*)(qkv + tok*768 +       h*32 + 8*l4);
    kf[t] = *(const short8*)(qkv + tok*768 + 256 + h*32 + 8*l4);
  }
  f32x4 s[4][4];
  #pragma unroll
  for (int i = 0; i < 4; ++i)
    #pragma unroll
    for (int j = 0; j < 4; ++j)
      s[i][j] = (f32x4){0.f, 0.f, 0.f, 0.f};
  #pragma unroll
  for (int mi = 0; mi < 4; ++mi)
    #pragma unroll
    for (int ni = 0; ni < 4; ++ni)
      s[mi][ni] = __builtin_amdgcn_mfma_f32_16x16x32_bf16(kf[ni], qf[mi], s[mi][ni], 0, 0, 0);

  const float scale = 0.17677669529663687f; // 1/sqrt(32)
  #pragma unroll
  for (int mi = 0; mi < 4; ++mi){
    int q = mi*16 + l15;
    int ny = q >> 3, nx = q & 7;
    #pragma unroll
    for (int ni = 0; ni < 4; ++ni){
      #pragma unroll
      for (int j = 0; j < 4; ++j){
        int k = ni*16 + 4*l4 + j;
        int db = (ny - (k >> 3) + 7) * 15 + (nx - (k & 7) + 7);
        s[mi][ni][j] = s[mi][ni][j] * scale + bt[db*8 + h];
      }
    }
    float mx = -1e30f;
    #pragma unroll
    for (int ni = 0; ni < 4; ++ni)
      #pragma unroll
      for (int j = 0; j < 4; ++j)
        mx = fmaxf(mx, s[mi][ni][j]);
    mx = fmaxf(mx, __shfl_xor(mx, 16));
    mx = fmaxf(mx, __shfl_xor(mx, 32));
    float sm = 0.f;
    #pragma unroll
    for (int ni = 0; ni < 4; ++ni)
      #pragma unroll
      for (int j = 0; j < 4; ++j){
        float p = __expf(s[mi][ni][j] - mx);
        s[mi][ni][j] = p;
        sm += p;
      }
    sm += __shfl_xor(sm, 16);
    sm += __shfl_xor(sm, 32);
    float inv = __builtin_amdgcn_rcpf(sm);
    #pragma unroll
    for (int ni = 0; ni < 4; ++ni){
      uint2 dv;
      dv.x = ((unsigned int)f2bf(s[mi][ni][1]*inv) << 16) | f2bf(s[mi][ni][0]*inv);
      dv.y = ((unsigned int)f2bf(s[mi][ni][3]*inv) << 16) | f2bf(s[mi][ni][2]*inv);
      int g = ni*2 + (l4 >> 1);
      *(uint2*)&P[q*64 + ((g ^ (q & 7)) << 3) + 4*(l4 & 1)] = dv;
    }
  }
  // single wave: no barrier needed (compiler orders via lgkmcnt)

  f32x4 o[4][2];
  #pragma unroll
  for (int i = 0; i < 4; ++i)
    #pragma unroll
    for (int j = 0; j < 2; ++j)
      o[i][j] = (f32x4){0.f, 0.f, 0.f, 0.f};
  #pragma unroll
  for (int kt = 0; kt < 2; ++kt){
    short8 vf[2];
    #pragma unroll
    for (int ni = 0; ni < 2; ++ni){
      union { unsigned short u[8]; short8 v; } tmp;
      #pragma unroll
      for (int i = 0; i < 8; ++i){
        int kk = kt*32 + 8*l4 + i;
        long tok = tok0 + (kk >> 3) * 256 + (kk & 7);
        tmp.u[i] = qkv[tok*768 + 512 + h*32 + ni*16 + l15];
      }
      vf[ni] = tmp.v;
    }
    #pragma unroll
    for (int mi = 0; mi < 4; ++mi){
      int r = mi*16 + l15;
      short8 pf = *(const short8*)&P[r*64 + (((kt*4 + l4) ^ (r & 7)) << 3)];
      #pragma unroll
      for (int ni = 0; ni < 2; ++ni)
        o[mi][ni] = __builtin_amdgcn_mfma_f32_16x16x32_bf16(vf[ni], pf, o[mi][ni], 0, 0, 0);
    }
  }
  #pragma unroll
  for (int mi = 0; mi < 4; ++mi){
    int t = mi*16 + l15;
    long tok = tok0 + (t >> 3) * 256 + (t & 7);
    #pragma unroll
    for (int ni = 0; ni < 2; ++ni){
      uint2 dv;
      dv.x = ((unsigned int)f2bf(o[mi][ni][1]) << 16) | f2bf(o[mi][ni][0]);
      dv.y = ((unsigned int)f2bf(o[mi][ni][3]) << 16) | f2bf(o[mi][ni][2]);
      *(uint2*)&ao[tok*256 + h*32 + ni*16 + 4*l4] = dv;
    }
  }
}

// ---------------- proj + residual + LN2 fused --------------------------------
// writes h (bf16) and hn (fp8 e4m3 * 16); LN2 stats on exact f32 values
__global__ __launch_bounds__(512, 4) void proj_ln2(
    const unsigned short* __restrict__ A,
    const unsigned short* __restrict__ Bt,
    const float* __restrict__ bias,
    const float* __restrict__ res,
    const float* __restrict__ g2,
    const float* __restrict__ b2,
    unsigned short* __restrict__ hout,
    unsigned char* __restrict__ hn){
  __shared__ unsigned short As[128*64];
  __shared__ unsigned short Bs[256*64];
  __shared__ float redsum[4][128];
  __shared__ float redsq[4][128];
  __shared__ float mu_s[128];
  __shared__ float rs_s[128];
  const int tid = threadIdx.x, lane = tid & 63, wave = tid >> 6;
  const int l15 = lane & 15, l4 = lane >> 4;
  const int wm = wave >> 2, wn = wave & 3;
  const long row0 = (long)blockIdx.x * 128;

  f32x4 acc[4][4];
  #pragma unroll
  for (int i = 0; i < 4; ++i)
    #pragma unroll
    for (int j = 0; j < 4; ++j)
      acc[i][j] = (f32x4){0.f, 0.f, 0.f, 0.f};

  for (int kt = 0; kt < 4; ++kt){
    #pragma unroll
    for (int it = 0; it < 2; ++it){
      int ch = it*512 + tid;
      int r = ch >> 3, cc = ch & 7;
      gload_lds16(A + (row0 + r)*256 + kt*64 + ((cc ^ (r & 7))*8), &As[ch*8]);
    }
    #pragma unroll
    for (int it = 0; it < 4; ++it){
      int ch = it*512 + tid;
      int r = ch >> 3, cc = ch & 7;
      gload_lds16(Bt + r*256 + kt*64 + ((cc ^ (r & 7))*8), &Bs[ch*8]);
    }
    __syncthreads();
    #pragma unroll
    for (int ks = 0; ks < 2; ++ks){
      short8 af[4], bf[4];
      #pragma unroll
      for (int mi = 0; mi < 4; ++mi){
        int ar = wm*64 + mi*16 + l15;
        af[mi] = *(const short8*)&As[ar*64 + (((ks*4 + l4) ^ (ar & 7))*8)];
      }
      #pragma unroll
      for (int ni = 0; ni < 4; ++ni){
        int br = wn*64 + ni*16 + l15;
        bf[ni] = *(const short8*)&Bs[br*64 + (((ks*4 + l4) ^ (br & 7))*8)];
      }
      #pragma unroll
      for (int mi = 0; mi < 4; ++mi)
        #pragma unroll
        for (int ni = 0; ni < 4; ++ni)
          acc[mi][ni] = __builtin_amdgcn_mfma_f32_16x16x32_bf16(af[mi], bf[ni], acc[mi][ni], 0, 0, 0);
    }
    __syncthreads();
  }

  float bcol[4];
  #pragma unroll
  for (int ni = 0; ni < 4; ++ni) bcol[ni] = bias[wn*64 + ni*16 + l15];
  f32x4 psum[4], psq[4];
  #pragma unroll
  for (int mi = 0; mi < 4; ++mi){
    psum[mi] = (f32x4){0.f,0.f,0.f,0.f};
    psq[mi]  = (f32x4){0.f,0.f,0.f,0.f};
    #pragma unroll
    for (int ni = 0; ni < 4; ++ni){
      int col = wn*64 + ni*16 + l15;
      #pragma unroll
      for (int j = 0; j < 4; ++j){
        long row = row0 + wm*64 + mi*16 + 4*l4 + j;
        long idx = row * 256 + col;
        float v = acc[mi][ni][j] + bcol[ni] + res[idx];
        hout[idx] = f2bf(v);
        acc[mi][ni][j] = v;
        psum[mi][j] += v;
        psq[mi][j]  += v * v;
      }
    }
  }
  #pragma unroll
  for (int mi = 0; mi < 4; ++mi){
    #pragma unroll
    for (int j = 0; j < 4; ++j){
      float s = psum[mi][j], q = psq[mi][j];
      #pragma unroll
      for (int m = 1; m < 16; m <<= 1){
        s += __shfl_xor(s, m);
        q += __shfl_xor(q, m);
      }
      if (l15 == 0){
        int rl = wm*64 + mi*16 + 4*l4 + j;
        redsum[wn][rl] = s;
        redsq[wn][rl]  = q;
      }
    }
  }
  __syncthreads();
  if (tid < 128){
    float s = redsum[0][tid] + redsum[1][tid] + redsum[2][tid] + redsum[3][tid];
    float q = redsq[0][tid]  + redsq[1][tid]  + redsq[2][tid]  + redsq[3][tid];
    float mu = s * (1.f/256.f);
    mu_s[tid] = mu;
    rs_s[tid] = rsqrtf(q * (1.f/256.f) - mu*mu + 1e-5f);
  }
  __syncthreads();
  float gcol[4], b2col[4];
  #pragma unroll
  for (int ni = 0; ni < 4; ++ni){
    gcol[ni]  = g2[wn*64 + ni*16 + l15];
    b2col[ni] = b2[wn*64 + ni*16 + l15];
  }
  #pragma unroll
  for (int mi = 0; mi < 4; ++mi){
    #pragma unroll
    for (int j = 0; j < 4; ++j){
      int rl = wm*64 + mi*16 + 4*l4 + j;
      float mu = mu_s[rl], rs = rs_s[rl];
      long row = row0 + rl;
      #pragma unroll
      for (int ni = 0; ni < 4; ++ni){
        int col = wn*64 + ni*16 + l15;
        hn[row*256 + col] = f2fp8(16.f * ((acc[mi][ni][j] - mu)*rs*gcol[ni] + b2col[ni]));
      }
    }
  }
}

extern "C" void kernel_launch(void* const* d_in, const int* in_sizes, int n_in,
                              void* d_out, int out_size, void* d_ws, size_t ws_size,
                              hipStream_t stream){
  const float* x      = (const float*)d_in[0];
  const float* ln1_g  = (const float*)d_in[1];
  const float* ln1_b  = (const float*)d_in[2];
  const float* qkv_w  = (const float*)d_in[3];
  const float* qkv_b  = (const float*)d_in[4];
  const float* proj_w = (const float*)d_in[5];
  const float* proj_b = (const float*)d_in[6];
  const float* btab   = (const float*)d_in[7];
  const float* ln2_g  = (const float*)d_in[8];
  const float* ln2_b  = (const float*)d_in[9];
  const float* fc1_w  = (const float*)d_in[10];
  const float* fc1_b  = (const float*)d_in[11];
  const float* fc2_w  = (const float*)d_in[12];
  const float* fc2_b  = (const float*)d_in[13];

  const long M = (long)in_sizes[0] / 256;  // 262144 tokens

  char* ws = (char*)d_ws;
  // Layout (time-disjoint overlaps):
  //   [0, 268MB):       xn -> ao -> act8 (fp8)
  //   [134, 536.9MB):   qkv
  //   [536.9, 604MB):   hn8 (fp8, 67MB)
  //   [671, ~674MB):    weights (wq/wp bf16, w1/w2 fp8)
  //   [712MiB, +134MB): hh (bf16 residual trunk)
  unsigned short* xn   = (unsigned short*)(ws);
  unsigned short* ao   = xn;
  unsigned char*  act8 = (unsigned char*)(ws);
  unsigned short* qkv  = (unsigned short*)(ws + 134217728);
  unsigned char*  hn8  = (unsigned char*)(ws + 536870912);
  unsigned short* wq   = (unsigned short*)(ws + 671088640);
  unsigned short* wp   = wq + 256*768;
  unsigned char*  w1f8 = (unsigned char*)(wp + 256*256);
  unsigned char*  w2f8 = w1f8 + 256*1024;
  unsigned short* hh   = (unsigned short*)(ws + (712ull << 20));
  float* outf = (float*)d_out;

  // all 4 weight transposes in one launch (786432 elems)
  wconv4<<<3072, 256, 0, stream>>>(qkv_w, proj_w, fc1_w, fc2_w, wq, wp, w1f8, w2f8);

  // LN1
  ln_kernel<<<M/4, 256, 0, stream>>>(x, ln1_g, ln1_b, xn);
  // QKV (swizzled): nbx=6
  gemm_bt<<<6 * (M/128), 256, 0, stream>>>(xn, wq, qkv_b, qkv, 768, 256, 6);
  // window attention: one wave per (window, head)
  attn_kernel<<<(M/64) * 8, 64, 0, stream>>>(qkv, btab, ao);
  // proj + residual + LN2  (h bf16 -> hh, hn fp8*16)
  proj_ln2<<<M/128, 512, 0, stream>>>(ao, wp, proj_b, x, ln2_g, ln2_b, hh, hn8);
  // FC1 fp8 + GELU -> act fp8 (swizzled): nbx=8, scale 1/(16*64)
  gemm_fp8<1><<<8 * (M/128), 256, 0, stream>>>(hn8, w1f8, fc1_b, nullptr, act8, 1024, 256, 8, 1.f/1024.f);
  // FC2 fp8 + residual(hh bf16) -> out f32 (swizzled): nbx=2, scale 1/(8*64)
  gemm_fp8<2><<<2 * (M/128), 256, 0, stream>>>(act8, w2f8, fc2_b, hh, outf, 256, 1024, 2, 1.f/512.f);
}

// Round 20
// 1056.788 us; speedup vs baseline: 1.3704x; 1.0518x over previous
//
#include <hip/hip_runtime.h>
#include <hip/hip_bf16.h>
#include <math.h>

typedef __attribute__((ext_vector_type(8))) short short8;
typedef __attribute__((ext_vector_type(4))) float f32x4;

__device__ __forceinline__ unsigned short f2bf(float f){
  union { __hip_bfloat16 h; unsigned short u; } cv;
  cv.h = __float2bfloat16(f);
  return cv.u;
}

__device__ __forceinline__ float bf2f(unsigned short u){
  union { unsigned int i; float f; } v;
  v.i = ((unsigned int)u) << 16;
  return v.f;
}

__device__ __forceinline__ unsigned char f2fp8(float v){
  return (unsigned char)(__builtin_amdgcn_cvt_pk_fp8_f32(v, v, 0, 0) & 0xff);
}

// gelu via sigmoid: 0.5v(1+tanh(u)) == v*sigmoid(2u), exp2-folded constants
__device__ __forceinline__ float gelu_f(float v){
  float v2 = v * v;
  float nw = v * fmaf(-0.10294364f, v2, -2.3022090f);  // -2u*log2(e)
  float e  = __builtin_amdgcn_exp2f(nw);
  return v * __builtin_amdgcn_rcpf(1.f + e);
}

__device__ __forceinline__ void gload_lds16(const void* g, void* l){
  __builtin_amdgcn_global_load_lds(
      (const __attribute__((address_space(1))) void*)g,
      (__attribute__((address_space(3))) void*)l, 16, 0, 0);
}

// ---------------- all four weight transposes in one launch -------------------
// wq fp8*64; wp bf16; w1 fp8*64; w2 fp8*64
__global__ __launch_bounds__(256) void wconv4(
    const float* __restrict__ qkv_w, const float* __restrict__ proj_w,
    const float* __restrict__ fc1_w, const float* __restrict__ fc2_w,
    unsigned char* __restrict__ wq, unsigned short* __restrict__ wp,
    unsigned char* __restrict__ w1, unsigned char* __restrict__ w2){
  int idx = blockIdx.x * 256 + threadIdx.x;
  if (idx < 196608){                       // qkv: K=256 N=768 -> fp8 * 64
    int k = idx / 768, n = idx % 768;
    wq[n*256 + k] = f2fp8(qkv_w[idx] * 64.f);
  } else if (idx < 262144){                // proj: K=256 N=256 (bf16)
    int l = idx - 196608;
    int k = l >> 8, n = l & 255;
    wp[n*256 + k] = f2bf(proj_w[l]);
  } else if (idx < 524288){                // fc1: K=256 N=1024 -> fp8 * 64
    int l = idx - 262144;
    int k = l >> 10, n = l & 1023;
    w1[n*256 + k] = f2fp8(fc1_w[l] * 64.f);
  } else {                                 // fc2: K=1024 N=256 -> fp8 * 64
    int l = idx - 524288;
    int k = l >> 8, n = l & 255;
    w2[n*1024 + k] = f2fp8(fc2_w[l] * 64.f);
  }
}

// ---------------- LayerNorm: x f32 [M][256] -> out fp8*16 [M][256] -----------
__global__ __launch_bounds__(256) void ln_kernel(
    const float* __restrict__ x, const float* __restrict__ g,
    const float* __restrict__ b, unsigned char* __restrict__ out){
  const int lane = threadIdx.x & 63;
  const int wv = threadIdx.x >> 6;
  const long row = (long)blockIdx.x * 4 + wv;
  const float4 xv = ((const float4*)(x + row * 256))[lane];
  float s  = xv.x + xv.y + xv.z + xv.w;
  float s2 = xv.x*xv.x + xv.y*xv.y + xv.z*xv.z + xv.w*xv.w;
  #pragma unroll
  for (int m = 1; m < 64; m <<= 1){
    s  += __shfl_xor(s,  m);
    s2 += __shfl_xor(s2, m);
  }
  float mu = s * (1.f/256.f);
  float rs = rsqrtf(s2 * (1.f/256.f) - mu*mu + 1e-5f);
  float4 gv = ((const float4*)g)[lane];
  float4 bv = ((const float4*)b)[lane];
  float v0 = 16.f * ((xv.x - mu)*rs*gv.x + bv.x);
  float v1 = 16.f * ((xv.y - mu)*rs*gv.y + bv.y);
  float v2 = 16.f * ((xv.z - mu)*rs*gv.z + bv.z);
  float v3 = 16.f * ((xv.w - mu)*rs*gv.w + bv.w);
  int p = __builtin_amdgcn_cvt_pk_fp8_f32(v0, v1, 0, 0);
  p = __builtin_amdgcn_cvt_pk_fp8_f32(v2, v3, p, 1);
  ((unsigned int*)(out + row * 256))[lane] = (unsigned int)p;
}

// ---------------- fp8 GEMM: A fp8 [M][K] @ Bt fp8 [N][K] ---------------------
// BK=128 fp8, XOR-granule swizzle, XCD banding, swapped MFMA.
// MODE 0: out bf16 = acc*s + bias
// MODE 1: out fp8 = cvt(8 * gelu(acc*s + bias))
// MODE 2: out f32 = acc*s + bias + res(bf16)
template<int MODE>
__global__ __launch_bounds__(256, 4) void gemm_fp8(
    const unsigned char* __restrict__ A,
    const unsigned char* __restrict__ Bt,
    const float* __restrict__ bias,
    const unsigned short* __restrict__ res,
    void* __restrict__ out,
    int N, int K, int nbx, float sc){
  __shared__ unsigned char S[2*128*128];
  unsigned char* As = S;
  unsigned char* Bs = S + 128*128;
  const int tid  = threadIdx.x;
  const int lane = tid & 63;
  const int wave = tid >> 6;
  const int wm = wave >> 1, wn = wave & 1;

  const int nby  = gridDim.x / nbx;
  const int bid  = blockIdx.x;
  const int xcd  = bid & 7;
  const int local = bid >> 3;
  const int lrow = local / nbx;
  const int rowb = xcd * (nby >> 3) + lrow;
  const int colb = local - lrow * nbx;
  const long row0 = (long)rowb * 128;
  const int  col0 = colb * 128;
  const int l15 = lane & 15, l4 = lane >> 4;

  f32x4 acc[4][4];
  #pragma unroll
  for (int i = 0; i < 4; ++i)
    #pragma unroll
    for (int j = 0; j < 4; ++j)
      acc[i][j] = (f32x4){0.f, 0.f, 0.f, 0.f};

  const int nk = K >> 7;
  for (int kt = 0; kt < nk; ++kt){
    #pragma unroll
    for (int it = 0; it < 4; ++it){
      int ch = it*256 + tid;
      int r = ch >> 3, cc = ch & 7;
      int srcc = ((cc ^ (r & 7)) << 4);
      gload_lds16(A  + (row0 + r) * K + kt*128 + srcc, &As[ch*16]);
      gload_lds16(Bt + (long)(col0 + r) * K + kt*128 + srcc, &Bs[ch*16]);
    }
    __syncthreads();
    #pragma unroll
    for (int ks = 0; ks < 4; ++ks){
      long af[4], bfr[4];
      #pragma unroll
      for (int mi = 0; mi < 4; ++mi){
        int ar = wm*64 + mi*16 + l15;
        af[mi] = *(const long*)&As[ar*128 + (((2*ks + (l4 >> 1)) ^ (ar & 7)) << 4) + 8*(l4 & 1)];
      }
      #pragma unroll
      for (int ni = 0; ni < 4; ++ni){
        int br = wn*64 + ni*16 + l15;
        bfr[ni] = *(const long*)&Bs[br*128 + (((2*ks + (l4 >> 1)) ^ (br & 7)) << 4) + 8*(l4 & 1)];
      }
      #pragma unroll
      for (int mi = 0; mi < 4; ++mi)
        #pragma unroll
        for (int ni = 0; ni < 4; ++ni)
          acc[mi][ni] = __builtin_amdgcn_mfma_f32_16x16x32_fp8_fp8(bfr[ni], af[mi], acc[mi][ni], 0, 0, 0);
    }
    __syncthreads();
  }

  if (MODE == 2){
    float* outf = (float*)out;
    #pragma unroll
    for (int mi = 0; mi < 4; ++mi){
      long row = row0 + wm*64 + mi*16 + l15;
      #pragma unroll
      for (int ni = 0; ni < 4; ++ni){
        int colg = col0 + wn*64 + ni*16 + 4*l4;
        float4 bv = *(const float4*)&bias[colg];
        long idx = row * N + colg;
        ushort4 rv = *(const ushort4*)&res[idx];
        float4 o;
        o.x = acc[mi][ni][0]*sc + bv.x + bf2f(rv.x);
        o.y = acc[mi][ni][1]*sc + bv.y + bf2f(rv.y);
        o.z = acc[mi][ni][2]*sc + bv.z + bf2f(rv.z);
        o.w = acc[mi][ni][3]*sc + bv.w + bf2f(rv.w);
        *(float4*)&outf[idx] = o;
      }
    }
  } else if (MODE == 1){
    unsigned char* outp = (unsigned char*)out;
    #pragma unroll
    for (int mi = 0; mi < 4; ++mi){
      long row = row0 + wm*64 + mi*16 + l15;
      #pragma unroll
      for (int ni = 0; ni < 4; ++ni){
        int colg = col0 + wn*64 + ni*16 + 4*l4;
        float4 bv = *(const float4*)&bias[colg];
        float v0 = 8.f * gelu_f(acc[mi][ni][0]*sc + bv.x);
        float v1 = 8.f * gelu_f(acc[mi][ni][1]*sc + bv.y);
        float v2 = 8.f * gelu_f(acc[mi][ni][2]*sc + bv.z);
        float v3 = 8.f * gelu_f(acc[mi][ni][3]*sc + bv.w);
        int p = __builtin_amdgcn_cvt_pk_fp8_f32(v0, v1, 0, 0);
        p = __builtin_amdgcn_cvt_pk_fp8_f32(v2, v3, p, 1);
        *(unsigned int*)&outp[row * N + colg] = (unsigned int)p;
      }
    }
  } else {
    unsigned short* outp = (unsigned short*)out;
    #pragma unroll
    for (int mi = 0; mi < 4; ++mi){
      long row = row0 + wm*64 + mi*16 + l15;
      #pragma unroll
      for (int ni = 0; ni < 4; ++ni){
        int colg = col0 + wn*64 + ni*16 + 4*l4;
        float4 bv = *(const float4*)&bias[colg];
        uint2 dv;
        dv.x = ((unsigned int)f2bf(acc[mi][ni][1]*sc + bv.y) << 16) | f2bf(acc[mi][ni][0]*sc + bv.x);
        dv.y = ((unsigned int)f2bf(acc[mi][ni][3]*sc + bv.w) << 16) | f2bf(acc[mi][ni][2]*sc + bv.z);
        *(uint2*)&outp[row * N + colg] = dv;
      }
    }
  }
}

// ---------------- Window attention: one WAVE = one (window, head) ------------
__global__ __launch_bounds__(64, 3) void attn_kernel(
    const unsigned short* __restrict__ qkv,
    const float* __restrict__ bt,
    unsigned short* __restrict__ ao){
  __shared__ unsigned short P[64*64];
  const int lane = threadIdx.x;
  const int wb = blockIdx.x;
  const int w = wb >> 3, h = wb & 7;
  const int bidx = w >> 10, rem = w & 1023;
  const int wy = rem >> 5, wx = rem & 31;
  const long tok0 = (long)bidx * 65536 + (long)wy * 2048 + wx * 8;
  const int l15 = lane & 15, l4 = lane >> 4;

  short8 qf[4], kf[4];
  #pragma unroll
  for (int t = 0; t < 4; ++t){
    int n = t*16 + l15;
    long tok = tok0 + (n >> 3) * 256 + (n & 7);
    qf[t] = *(const short8*)(qkv + tok*768 +       h*32 + 8*l4);
    kf[t] = *(const short8*)(qkv + tok*768 + 256 + h*32 + 8*l4);
  }
  f32x4 s[4][4];
  #pragma unroll
  for (int i = 0; i < 4; ++i)
    #pragma unroll
    for (int j = 0; j < 4; ++j)
      s[i][j] = (f32x4){0.f, 0.f, 0.f, 0.f};
  #pragma unroll
  for (int mi = 0; mi < 4; ++mi)
    #pragma unroll
    for (int ni = 0; ni < 4; ++ni)
      s[mi][ni] = __builtin_amdgcn_mfma_f32_16x16x32_bf16(kf[ni], qf[mi], s[mi][ni], 0, 0, 0);

  const float scale = 0.17677669529663687f; // 1/sqrt(32)
  #pragma unroll
  for (int mi = 0; mi < 4; ++mi){
    int q = mi*16 + l15;
    int ny = q >> 3, nx = q & 7;
    #pragma unroll
    for (int ni = 0; ni < 4; ++ni){
      #pragma unroll
      for (int j = 0; j < 4; ++j){
        int k = ni*16 + 4*l4 + j;
        int db = (ny - (k >> 3) + 7) * 15 + (nx - (k & 7) + 7);
        s[mi][ni][j] = s[mi][ni][j] * scale + bt[db*8 + h];
      }
    }
    float mx = -1e30f;
    #pragma unroll
    for (int ni = 0; ni < 4; ++ni)
      #pragma unroll
      for (int j = 0; j < 4; ++j)
        mx = fmaxf(mx, s[mi][ni][j]);
    mx = fmaxf(mx, __shfl_xor(mx, 16));
    mx = fmaxf(mx, __shfl_xor(mx, 32));
    float sm = 0.f;
    #pragma unroll
    for (int ni = 0; ni < 4; ++ni)
      #pragma unroll
      for (int j = 0; j < 4; ++j){
        float p = __expf(s[mi][ni][j] - mx);
        s[mi][ni][j] = p;
        sm += p;
      }
    sm += __shfl_xor(sm, 16);
    sm += __shfl_xor(sm, 32);
    float inv = __builtin_amdgcn_rcpf(sm);
    #pragma unroll
    for (int ni = 0; ni < 4; ++ni){
      uint2 dv;
      dv.x = ((unsigned int)f2bf(s[mi][ni][1]*inv) << 16) | f2bf(s[mi][ni][0]*inv);
      dv.y = ((unsigned int)f2bf(s[mi][ni][3]*inv) << 16) | f2bf(s[mi][ni][2]*inv);
      int g = ni*2 + (l4 >> 1);
      *(uint2*)&P[q*64 + ((g ^ (q & 7)) << 3) + 4*(l4 & 1)] = dv;
    }
  }
  // single wave: no barrier needed (compiler orders via lgkmcnt)

  f32x4 o[4][2];
  #pragma unroll
  for (int i = 0; i < 4; ++i)
    #pragma unroll
    for (int j = 0; j < 2; ++j)
      o[i][j] = (f32x4){0.f, 0.f, 0.f, 0.f};
  #pragma unroll
  for (int kt = 0; kt < 2; ++kt){
    short8 vf[2];
    #pragma unroll
    for (int ni = 0; ni < 2; ++ni){
      union { unsigned short u[8]; short8 v; } tmp;
      #pragma unroll
      for (int i = 0; i < 8; ++i){
        int kk = kt*32 + 8*l4 + i;
        long tok = tok0 + (kk >> 3) * 256 + (kk & 7);
        tmp.u[i] = qkv[tok*768 + 512 + h*32 + ni*16 + l15];
      }
      vf[ni] = tmp.v;
    }
    #pragma unroll
    for (int mi = 0; mi < 4; ++mi){
      int r = mi*16 + l15;
      short8 pf = *(const short8*)&P[r*64 + (((kt*4 + l4) ^ (r & 7)) << 3)];
      #pragma unroll
      for (int ni = 0; ni < 2; ++ni)
        o[mi][ni] = __builtin_amdgcn_mfma_f32_16x16x32_bf16(vf[ni], pf, o[mi][ni], 0, 0, 0);
    }
  }
  #pragma unroll
  for (int mi = 0; mi < 4; ++mi){
    int t = mi*16 + l15;
    long tok = tok0 + (t >> 3) * 256 + (t & 7);
    #pragma unroll
    for (int ni = 0; ni < 2; ++ni){
      uint2 dv;
      dv.x = ((unsigned int)f2bf(o[mi][ni][1]) << 16) | f2bf(o[mi][ni][0]);
      dv.y = ((unsigned int)f2bf(o[mi][ni][3]) << 16) | f2bf(o[mi][ni][2]);
      *(uint2*)&ao[tok*256 + h*32 + ni*16 + 4*l4] = dv;
    }
  }
}

// ---------------- proj + residual + LN2 fused --------------------------------
// writes h (bf16) and hn (fp8 e4m3 * 16); LN2 stats on exact f32 values
__global__ __launch_bounds__(512, 4) void proj_ln2(
    const unsigned short* __restrict__ A,
    const unsigned short* __restrict__ Bt,
    const float* __restrict__ bias,
    const float* __restrict__ res,
    const float* __restrict__ g2,
    const float* __restrict__ b2,
    unsigned short* __restrict__ hout,
    unsigned char* __restrict__ hn){
  __shared__ unsigned short As[128*64];
  __shared__ unsigned short Bs[256*64];
  __shared__ float redsum[4][128];
  __shared__ float redsq[4][128];
  __shared__ float mu_s[128];
  __shared__ float rs_s[128];
  const int tid = threadIdx.x, lane = tid & 63, wave = tid >> 6;
  const int l15 = lane & 15, l4 = lane >> 4;
  const int wm = wave >> 2, wn = wave & 3;
  const long row0 = (long)blockIdx.x * 128;

  f32x4 acc[4][4];
  #pragma unroll
  for (int i = 0; i < 4; ++i)
    #pragma unroll
    for (int j = 0; j < 4; ++j)
      acc[i][j] = (f32x4){0.f, 0.f, 0.f, 0.f};

  for (int kt = 0; kt < 4; ++kt){
    #pragma unroll
    for (int it = 0; it < 2; ++it){
      int ch = it*512 + tid;
      int r = ch >> 3, cc = ch & 7;
      gload_lds16(A + (row0 + r)*256 + kt*64 + ((cc ^ (r & 7))*8), &As[ch*8]);
    }
    #pragma unroll
    for (int it = 0; it < 4; ++it){
      int ch = it*512 + tid;
      int r = ch >> 3, cc = ch & 7;
      gload_lds16(Bt + r*256 + kt*64 + ((cc ^ (r & 7))*8), &Bs[ch*8]);
    }
    __syncthreads();
    #pragma unroll
    for (int ks = 0; ks < 2; ++ks){
      short8 af[4], bf[4];
      #pragma unroll
      for (int mi = 0; mi < 4; ++mi){
        int ar = wm*64 + mi*16 + l15;
        af[mi] = *(const short8*)&As[ar*64 + (((ks*4 + l4) ^ (ar & 7))*8)];
      }
      #pragma unroll
      for (int ni = 0; ni < 4; ++ni){
        int br = wn*64 + ni*16 + l15;
        bf[ni] = *(const short8*)&Bs[br*64 + (((ks*4 + l4) ^ (br & 7))*8)];
      }
      #pragma unroll
      for (int mi = 0; mi < 4; ++mi)
        #pragma unroll
        for (int ni = 0; ni < 4; ++ni)
          acc[mi][ni] = __builtin_amdgcn_mfma_f32_16x16x32_bf16(af[mi], bf[ni], acc[mi][ni], 0, 0, 0);
    }
    __syncthreads();
  }

  float bcol[4];
  #pragma unroll
  for (int ni = 0; ni < 4; ++ni) bcol[ni] = bias[wn*64 + ni*16 + l15];
  f32x4 psum[4], psq[4];
  #pragma unroll
  for (int mi = 0; mi < 4; ++mi){
    psum[mi] = (f32x4){0.f,0.f,0.f,0.f};
    psq[mi]  = (f32x4){0.f,0.f,0.f,0.f};
    #pragma unroll
    for (int ni = 0; ni < 4; ++ni){
      int col = wn*64 + ni*16 + l15;
      #pragma unroll
      for (int j = 0; j < 4; ++j){
        long row = row0 + wm*64 + mi*16 + 4*l4 + j;
        long idx = row * 256 + col;
        float v = acc[mi][ni][j] + bcol[ni] + res[idx];
        hout[idx] = f2bf(v);
        acc[mi][ni][j] = v;
        psum[mi][j] += v;
        psq[mi][j]  += v * v;
      }
    }
  }
  #pragma unroll
  for (int mi = 0; mi < 4; ++mi){
    #pragma unroll
    for (int j = 0; j < 4; ++j){
      float s = psum[mi][j], q = psq[mi][j];
      #pragma unroll
      for (int m = 1; m < 16; m <<= 1){
        s += __shfl_xor(s, m);
        q += __shfl_xor(q, m);
      }
      if (l15 == 0){
        int rl = wm*64 + mi*16 + 4*l4 + j;
        redsum[wn][rl] = s;
        redsq[wn][rl]  = q;
      }
    }
  }
  __syncthreads();
  if (tid < 128){
    float s = redsum[0][tid] + redsum[1][tid] + redsum[2][tid] + redsum[3][tid];
    float q = redsq[0][tid]  + redsq[1][tid]  + redsq[2][tid]  + redsq[3][tid];
    float mu = s * (1.f/256.f);
    mu_s[tid] = mu;
    rs_s[tid] = rsqrtf(q * (1.f/256.f) - mu*mu + 1e-5f);
  }
  __syncthreads();
  float gcol[4], b2col[4];
  #pragma unroll
  for (int ni = 0; ni < 4; ++ni){
    gcol[ni]  = g2[wn*64 + ni*16 + l15];
    b2col[ni] = b2[wn*64 + ni*16 + l15];
  }
  #pragma unroll
  for (int mi = 0; mi < 4; ++mi){
    #pragma unroll
    for (int j = 0; j < 4; ++j){
      int rl = wm*64 + mi*16 + 4*l4 + j;
      float mu = mu_s[rl], rs = rs_s[rl];
      long row = row0 + rl;
      #pragma unroll
      for (int ni = 0; ni < 4; ++ni){
        int col = wn*64 + ni*16 + l15;
        hn[row*256 + col] = f2fp8(16.f * ((acc[mi][ni][j] - mu)*rs*gcol[ni] + b2col[ni]));
      }
    }
  }
}

extern "C" void kernel_launch(void* const* d_in, const int* in_sizes, int n_in,
                              void* d_out, int out_size, void* d_ws, size_t ws_size,
                              hipStream_t stream){
  const float* x      = (const float*)d_in[0];
  const float* ln1_g  = (const float*)d_in[1];
  const float* ln1_b  = (const float*)d_in[2];
  const float* qkv_w  = (const float*)d_in[3];
  const float* qkv_b  = (const float*)d_in[4];
  const float* proj_w = (const float*)d_in[5];
  const float* proj_b = (const float*)d_in[6];
  const float* btab   = (const float*)d_in[7];
  const float* ln2_g  = (const float*)d_in[8];
  const float* ln2_b  = (const float*)d_in[9];
  const float* fc1_w  = (const float*)d_in[10];
  const float* fc1_b  = (const float*)d_in[11];
  const float* fc2_w  = (const float*)d_in[12];
  const float* fc2_b  = (const float*)d_in[13];

  const long M = (long)in_sizes[0] / 256;  // 262144 tokens

  char* ws = (char*)d_ws;
  // Layout (time-disjoint overlaps):
  //   [0, 67MB):        xn8 (fp8) -> then dead; ao bf16 [0,134MB) after qkv;
  //                     act8 fp8 [0,268MB) after proj (all time-disjoint)
  //   [134, 536.9MB):   qkv (bf16)
  //   [536.9, 604MB):   hn8 (fp8)
  //   [671MB, ...):     weights (wq/w1/w2 fp8, wp bf16)
  //   [712MiB, +134MB): hh (bf16 residual trunk)
  unsigned char*  xn8  = (unsigned char*)(ws);
  unsigned short* ao   = (unsigned short*)(ws);
  unsigned char*  act8 = (unsigned char*)(ws);
  unsigned short* qkv  = (unsigned short*)(ws + 134217728);
  unsigned char*  hn8  = (unsigned char*)(ws + 536870912);
  unsigned char*  wqf8 = (unsigned char*)(ws + 671088640);
  unsigned short* wp   = (unsigned short*)(wqf8 + 196608);
  unsigned char*  w1f8 = (unsigned char*)(wp + 256*256);
  unsigned char*  w2f8 = w1f8 + 256*1024;
  unsigned short* hh   = (unsigned short*)(ws + (712ull << 20));
  float* outf = (float*)d_out;

  // all 4 weight transposes in one launch (786432 elems)
  wconv4<<<3072, 256, 0, stream>>>(qkv_w, proj_w, fc1_w, fc2_w, wqf8, wp, w1f8, w2f8);

  // LN1 -> fp8*16
  ln_kernel<<<M/4, 256, 0, stream>>>(x, ln1_g, ln1_b, xn8);
  // QKV fp8 (swizzled): nbx=6, scale 1/(16*64)
  gemm_fp8<0><<<6 * (M/128), 256, 0, stream>>>(xn8, wqf8, qkv_b, nullptr, qkv, 768, 256, 6, 1.f/1024.f);
  // window attention: one wave per (window, head)
  attn_kernel<<<(M/64) * 8, 64, 0, stream>>>(qkv, btab, ao);
  // proj + residual + LN2  (h bf16 -> hh, hn fp8*16)
  proj_ln2<<<M/128, 512, 0, stream>>>(ao, wp, proj_b, x, ln2_g, ln2_b, hh, hn8);
  // FC1 fp8 + GELU -> act fp8 (swizzled): nbx=8, scale 1/(16*64)
  gemm_fp8<1><<<8 * (M/128), 256, 0, stream>>>(hn8, w1f8, fc1_b, nullptr, act8, 1024, 256, 8, 1.f/1024.f);
  // FC2 fp8 + residual(hh bf16) -> out f32 (swizzled): nbx=2, scale 1/(8*64)
  gemm_fp8<2><<<2 * (M/128), 256, 0, stream>>>(act8, w2f8, fc2_b, hh, outf, 256, 1024, 2, 1.f/512.f);
}

// Round 22
// 998.585 us; speedup vs baseline: 1.4502x; 1.0583x over previous
//
#include <hip/hip_runtime.h>
#include <hip/hip_bf16.h>
#include <math.h>

typedef __attribute__((ext_vector_type(8))) short short8;
typedef __attribute__((ext_vector_type(4))) float f32x4;

__device__ __forceinline__ unsigned short f2bf(float f){
  union { __hip_bfloat16 h; unsigned short u; } cv;
  cv.h = __float2bfloat16(f);
  return cv.u;
}

__device__ __forceinline__ float bf2f(unsigned short u){
  union { unsigned int i; float f; } v;
  v.i = ((unsigned int)u) << 16;
  return v.f;
}

__device__ __forceinline__ unsigned char f2fp8(float v){
  return (unsigned char)(__builtin_amdgcn_cvt_pk_fp8_f32(v, v, 0, 0) & 0xff);
}

// gelu via sigmoid: 0.5v(1+tanh(u)) == v*sigmoid(2u), exp2-folded constants
__device__ __forceinline__ float gelu_f(float v){
  float v2 = v * v;
  float nw = v * fmaf(-0.10294364f, v2, -2.3022090f);  // -2u*log2(e)
  float e  = __builtin_amdgcn_exp2f(nw);
  return v * __builtin_amdgcn_rcpf(1.f + e);
}

__device__ __forceinline__ void gload_lds16(const void* g, void* l){
  __builtin_amdgcn_global_load_lds(
      (const __attribute__((address_space(1))) void*)g,
      (__attribute__((address_space(3))) void*)l, 16, 0, 0);
}

// ---------------- all four weight transposes in one launch -------------------
// wq fp8*64; wp bf16; w1 fp8*64; w2 fp8*64
__global__ __launch_bounds__(256) void wconv4(
    const float* __restrict__ qkv_w, const float* __restrict__ proj_w,
    const float* __restrict__ fc1_w, const float* __restrict__ fc2_w,
    unsigned char* __restrict__ wq, unsigned short* __restrict__ wp,
    unsigned char* __restrict__ w1, unsigned char* __restrict__ w2){
  int idx = blockIdx.x * 256 + threadIdx.x;
  if (idx < 196608){                       // qkv: K=256 N=768 -> fp8 * 64
    int k = idx / 768, n = idx % 768;
    wq[n*256 + k] = f2fp8(qkv_w[idx] * 64.f);
  } else if (idx < 262144){                // proj: K=256 N=256 (bf16)
    int l = idx - 196608;
    int k = l >> 8, n = l & 255;
    wp[n*256 + k] = f2bf(proj_w[l]);
  } else if (idx < 524288){                // fc1: K=256 N=1024 -> fp8 * 64
    int l = idx - 262144;
    int k = l >> 10, n = l & 1023;
    w1[n*256 + k] = f2fp8(fc1_w[l] * 64.f);
  } else {                                 // fc2: K=1024 N=256 -> fp8 * 64
    int l = idx - 524288;
    int k = l >> 8, n = l & 255;
    w2[n*1024 + k] = f2fp8(fc2_w[l] * 64.f);
  }
}

// ---------------- LayerNorm: x f32 [M][256] -> out fp8*16 [M][256] -----------
__global__ __launch_bounds__(256) void ln_kernel(
    const float* __restrict__ x, const float* __restrict__ g,
    const float* __restrict__ b, unsigned char* __restrict__ out){
  const int lane = threadIdx.x & 63;
  const int wv = threadIdx.x >> 6;
  const long row = (long)blockIdx.x * 4 + wv;
  const float4 xv = ((const float4*)(x + row * 256))[lane];
  float s  = xv.x + xv.y + xv.z + xv.w;
  float s2 = xv.x*xv.x + xv.y*xv.y + xv.z*xv.z + xv.w*xv.w;
  #pragma unroll
  for (int m = 1; m < 64; m <<= 1){
    s  += __shfl_xor(s,  m);
    s2 += __shfl_xor(s2, m);
  }
  float mu = s * (1.f/256.f);
  float rs = rsqrtf(s2 * (1.f/256.f) - mu*mu + 1e-5f);
  float4 gv = ((const float4*)g)[lane];
  float4 bv = ((const float4*)b)[lane];
  float v0 = 16.f * ((xv.x - mu)*rs*gv.x + bv.x);
  float v1 = 16.f * ((xv.y - mu)*rs*gv.y + bv.y);
  float v2 = 16.f * ((xv.z - mu)*rs*gv.z + bv.z);
  float v3 = 16.f * ((xv.w - mu)*rs*gv.w + bv.w);
  int p = __builtin_amdgcn_cvt_pk_fp8_f32(v0, v1, 0, 0);
  p = __builtin_amdgcn_cvt_pk_fp8_f32(v2, v3, p, 1);
  ((unsigned int*)(out + row * 256))[lane] = (unsigned int)p;
}

// ---------------- fp8 GEMM: A fp8 [M][K] @ Bt fp8 [N][K] ---------------------
// BK=128 fp8, XOR-granule swizzle, XCD banding, swapped MFMA.
// MODE 0: out bf16 = acc*s + bias
// MODE 1: out fp8 = cvt(8 * gelu(acc*s + bias))
// MODE 2: out f32 = acc*s + bias + res(bf16)
// MODE 3: out fp8 = cvt(16 * (acc*s + bias))
template<int MODE>
__global__ __launch_bounds__(256, 4) void gemm_fp8(
    const unsigned char* __restrict__ A,
    const unsigned char* __restrict__ Bt,
    const float* __restrict__ bias,
    const unsigned short* __restrict__ res,
    void* __restrict__ out,
    int N, int K, int nbx, float sc){
  __shared__ unsigned char S[2*128*128];
  unsigned char* As = S;
  unsigned char* Bs = S + 128*128;
  const int tid  = threadIdx.x;
  const int lane = tid & 63;
  const int wave = tid >> 6;
  const int wm = wave >> 1, wn = wave & 1;

  const int nby  = gridDim.x / nbx;
  const int bid  = blockIdx.x;
  const int xcd  = bid & 7;
  const int local = bid >> 3;
  const int lrow = local / nbx;
  const int rowb = xcd * (nby >> 3) + lrow;
  const int colb = local - lrow * nbx;
  const long row0 = (long)rowb * 128;
  const int  col0 = colb * 128;
  const int l15 = lane & 15, l4 = lane >> 4;

  f32x4 acc[4][4];
  #pragma unroll
  for (int i = 0; i < 4; ++i)
    #pragma unroll
    for (int j = 0; j < 4; ++j)
      acc[i][j] = (f32x4){0.f, 0.f, 0.f, 0.f};

  const int nk = K >> 7;
  for (int kt = 0; kt < nk; ++kt){
    #pragma unroll
    for (int it = 0; it < 4; ++it){
      int ch = it*256 + tid;
      int r = ch >> 3, cc = ch & 7;
      int srcc = ((cc ^ (r & 7)) << 4);
      gload_lds16(A  + (row0 + r) * K + kt*128 + srcc, &As[ch*16]);
      gload_lds16(Bt + (long)(col0 + r) * K + kt*128 + srcc, &Bs[ch*16]);
    }
    __syncthreads();
    #pragma unroll
    for (int ks = 0; ks < 4; ++ks){
      long af[4], bfr[4];
      #pragma unroll
      for (int mi = 0; mi < 4; ++mi){
        int ar = wm*64 + mi*16 + l15;
        af[mi] = *(const long*)&As[ar*128 + (((2*ks + (l4 >> 1)) ^ (ar & 7)) << 4) + 8*(l4 & 1)];
      }
      #pragma unroll
      for (int ni = 0; ni < 4; ++ni){
        int br = wn*64 + ni*16 + l15;
        bfr[ni] = *(const long*)&Bs[br*128 + (((2*ks + (l4 >> 1)) ^ (br & 7)) << 4) + 8*(l4 & 1)];
      }
      #pragma unroll
      for (int mi = 0; mi < 4; ++mi)
        #pragma unroll
        for (int ni = 0; ni < 4; ++ni)
          acc[mi][ni] = __builtin_amdgcn_mfma_f32_16x16x32_fp8_fp8(bfr[ni], af[mi], acc[mi][ni], 0, 0, 0);
    }
    __syncthreads();
  }

  if (MODE == 2){
    float* outf = (float*)out;
    #pragma unroll
    for (int mi = 0; mi < 4; ++mi){
      long row = row0 + wm*64 + mi*16 + l15;
      #pragma unroll
      for (int ni = 0; ni < 4; ++ni){
        int colg = col0 + wn*64 + ni*16 + 4*l4;
        float4 bv = *(const float4*)&bias[colg];
        long idx = row * N + colg;
        ushort4 rv = *(const ushort4*)&res[idx];
        float4 o;
        o.x = acc[mi][ni][0]*sc + bv.x + bf2f(rv.x);
        o.y = acc[mi][ni][1]*sc + bv.y + bf2f(rv.y);
        o.z = acc[mi][ni][2]*sc + bv.z + bf2f(rv.z);
        o.w = acc[mi][ni][3]*sc + bv.w + bf2f(rv.w);
        *(float4*)&outf[idx] = o;
      }
    }
  } else if (MODE == 1 || MODE == 3){
    unsigned char* outp = (unsigned char*)out;
    #pragma unroll
    for (int mi = 0; mi < 4; ++mi){
      long row = row0 + wm*64 + mi*16 + l15;
      #pragma unroll
      for (int ni = 0; ni < 4; ++ni){
        int colg = col0 + wn*64 + ni*16 + 4*l4;
        float4 bv = *(const float4*)&bias[colg];
        float v0, v1, v2, v3;
        if (MODE == 1){
          v0 = 8.f * gelu_f(acc[mi][ni][0]*sc + bv.x);
          v1 = 8.f * gelu_f(acc[mi][ni][1]*sc + bv.y);
          v2 = 8.f * gelu_f(acc[mi][ni][2]*sc + bv.z);
          v3 = 8.f * gelu_f(acc[mi][ni][3]*sc + bv.w);
        } else {
          v0 = 16.f * (acc[mi][ni][0]*sc + bv.x);
          v1 = 16.f * (acc[mi][ni][1]*sc + bv.y);
          v2 = 16.f * (acc[mi][ni][2]*sc + bv.z);
          v3 = 16.f * (acc[mi][ni][3]*sc + bv.w);
        }
        int p = __builtin_amdgcn_cvt_pk_fp8_f32(v0, v1, 0, 0);
        p = __builtin_amdgcn_cvt_pk_fp8_f32(v2, v3, p, 1);
        *(unsigned int*)&outp[row * N + colg] = (unsigned int)p;
      }
    }
  } else {
    unsigned short* outp = (unsigned short*)out;
    #pragma unroll
    for (int mi = 0; mi < 4; ++mi){
      long row = row0 + wm*64 + mi*16 + l15;
      #pragma unroll
      for (int ni = 0; ni < 4; ++ni){
        int colg = col0 + wn*64 + ni*16 + 4*l4;
        float4 bv = *(const float4*)&bias[colg];
        uint2 dv;
        dv.x = ((unsigned int)f2bf(acc[mi][ni][1]*sc + bv.y) << 16) | f2bf(acc[mi][ni][0]*sc + bv.x);
        dv.y = ((unsigned int)f2bf(acc[mi][ni][3]*sc + bv.w) << 16) | f2bf(acc[mi][ni][2]*sc + bv.z);
        *(uint2*)&outp[row * N + colg] = dv;
      }
    }
  }
}

// ---------------- Window attention: one WAVE = one (window, head), full fp8 --
// qkv fp8*16. QK^T fp8 (scale absorbs 1/256). P fp8*16 in padded LDS.
// PV fp8, result /256. ao bf16.
// P LDS round-trip: uint-typed both ways + __syncthreads() (ordering-safe).
__global__ __launch_bounds__(64, 3) void attn_kernel(
    const unsigned char* __restrict__ qkv,
    const float* __restrict__ bt,
    unsigned short* __restrict__ ao){
  __shared__ unsigned int P8[64*18];      // 72B row stride (18 uints): bank-spread
  const int lane = threadIdx.x;
  const int wb = blockIdx.x;
  const int w = wb >> 3, h = wb & 7;
  const int bidx = w >> 10, rem = w & 1023;
  const int wy = rem >> 5, wx = rem & 31;
  const long tok0 = (long)bidx * 65536 + (long)wy * 2048 + wx * 8;
  const int l15 = lane & 15, l4 = lane >> 4;

  long qf[4], kf[4];
  #pragma unroll
  for (int t = 0; t < 4; ++t){
    int n = t*16 + l15;
    long tok = tok0 + (n >> 3) * 256 + (n & 7);
    qf[t] = *(const long*)(qkv + tok*768 +       h*32 + 8*l4);
    kf[t] = *(const long*)(qkv + tok*768 + 256 + h*32 + 8*l4);
  }
  // swapped: s[mi][ni]: lane holds q = mi*16+l15, k = ni*16+4*l4+{0..3}
  f32x4 s[4][4];
  #pragma unroll
  for (int i = 0; i < 4; ++i)
    #pragma unroll
    for (int j = 0; j < 4; ++j)
      s[i][j] = (f32x4){0.f, 0.f, 0.f, 0.f};
  #pragma unroll
  for (int mi = 0; mi < 4; ++mi)
    #pragma unroll
    for (int ni = 0; ni < 4; ++ni)
      s[mi][ni] = __builtin_amdgcn_mfma_f32_16x16x32_fp8_fp8(kf[ni], qf[mi], s[mi][ni], 0, 0, 0);

  const float scale = 0.17677669529663687f / 256.f;  // undo q*16, k*16
  #pragma unroll
  for (int mi = 0; mi < 4; ++mi){
    int q = mi*16 + l15;
    int ny = q >> 3, nx = q & 7;
    #pragma unroll
    for (int ni = 0; ni < 4; ++ni){
      #pragma unroll
      for (int j = 0; j < 4; ++j){
        int k = ni*16 + 4*l4 + j;
        int db = (ny - (k >> 3) + 7) * 15 + (nx - (k & 7) + 7);
        s[mi][ni][j] = s[mi][ni][j] * scale + bt[db*8 + h];
      }
    }
    float mx = -1e30f;
    #pragma unroll
    for (int ni = 0; ni < 4; ++ni)
      #pragma unroll
      for (int j = 0; j < 4; ++j)
        mx = fmaxf(mx, s[mi][ni][j]);
    mx = fmaxf(mx, __shfl_xor(mx, 16));
    mx = fmaxf(mx, __shfl_xor(mx, 32));
    float sm = 0.f;
    #pragma unroll
    for (int ni = 0; ni < 4; ++ni)
      #pragma unroll
      for (int j = 0; j < 4; ++j){
        float p = __expf(s[mi][ni][j] - mx);
        s[mi][ni][j] = p;
        sm += p;
      }
    sm += __shfl_xor(sm, 16);
    sm += __shfl_xor(sm, 32);
    float inv16 = 16.f * __builtin_amdgcn_rcpf(sm);
    // packed P write: 4 consecutive k per lane, fp8*16 (uint-typed)
    #pragma unroll
    for (int ni = 0; ni < 4; ++ni){
      int p = __builtin_amdgcn_cvt_pk_fp8_f32(s[mi][ni][0]*inv16, s[mi][ni][1]*inv16, 0, 0);
      p = __builtin_amdgcn_cvt_pk_fp8_f32(s[mi][ni][2]*inv16, s[mi][ni][3]*inv16, p, 1);
      P8[q*18 + ni*4 + l4] = (unsigned int)p;
    }
  }
  __syncthreads();   // make P visible/ordered before PV reads

  // PV swapped: o[mi][ni]: lane holds token = mi*16+l15, d = ni*16+4*l4+{0..3}
  f32x4 o[4][2];
  #pragma unroll
  for (int i = 0; i < 4; ++i)
    #pragma unroll
    for (int j = 0; j < 2; ++j)
      o[i][j] = (f32x4){0.f, 0.f, 0.f, 0.f};
  #pragma unroll
  for (int kt = 0; kt < 2; ++kt){
    long vf[2];
    #pragma unroll
    for (int ni = 0; ni < 2; ++ni){
      union { unsigned char b[8]; long v; } tmp;
      #pragma unroll
      for (int i = 0; i < 8; ++i){
        int kk = kt*32 + 8*l4 + i;
        long tok = tok0 + (kk >> 3) * 256 + (kk & 7);
        tmp.b[i] = qkv[tok*768 + 512 + h*32 + ni*16 + l15];
      }
      vf[ni] = tmp.v;
    }
    #pragma unroll
    for (int mi = 0; mi < 4; ++mi){
      int rr = mi*16 + l15;
      union { unsigned int u[2]; long v; } pfu;
      pfu.u[0] = P8[rr*18 + kt*8 + 2*l4];
      pfu.u[1] = P8[rr*18 + kt*8 + 2*l4 + 1];
      long pf = pfu.v;
      #pragma unroll
      for (int ni = 0; ni < 2; ++ni)
        o[mi][ni] = __builtin_amdgcn_mfma_f32_16x16x32_fp8_fp8(vf[ni], pf, o[mi][ni], 0, 0, 0);
    }
  }
  // packed ao write: 4 consecutive d per lane; undo P*16 and V*16
  const float osc = 1.f / 256.f;
  #pragma unroll
  for (int mi = 0; mi < 4; ++mi){
    int t = mi*16 + l15;
    long tok = tok0 + (t >> 3) * 256 + (t & 7);
    #pragma unroll
    for (int ni = 0; ni < 2; ++ni){
      uint2 dv;
      dv.x = ((unsigned int)f2bf(o[mi][ni][1]*osc) << 16) | f2bf(o[mi][ni][0]*osc);
      dv.y = ((unsigned int)f2bf(o[mi][ni][3]*osc) << 16) | f2bf(o[mi][ni][2]*osc);
      *(uint2*)&ao[tok*256 + h*32 + ni*16 + 4*l4] = dv;
    }
  }
}

// ---------------- proj + residual + LN2 fused --------------------------------
// writes h (bf16) and hn (fp8 e4m3 * 16); LN2 stats on exact f32 values
__global__ __launch_bounds__(512, 4) void proj_ln2(
    const unsigned short* __restrict__ A,
    const unsigned short* __restrict__ Bt,
    const float* __restrict__ bias,
    const float* __restrict__ res,
    const float* __restrict__ g2,
    const float* __restrict__ b2,
    unsigned short* __restrict__ hout,
    unsigned char* __restrict__ hn){
  __shared__ unsigned short As[128*64];
  __shared__ unsigned short Bs[256*64];
  __shared__ float redsum[4][128];
  __shared__ float redsq[4][128];
  __shared__ float mu_s[128];
  __shared__ float rs_s[128];
  const int tid = threadIdx.x, lane = tid & 63, wave = tid >> 6;
  const int l15 = lane & 15, l4 = lane >> 4;
  const int wm = wave >> 2, wn = wave & 3;
  const long row0 = (long)blockIdx.x * 128;

  f32x4 acc[4][4];
  #pragma unroll
  for (int i = 0; i < 4; ++i)
    #pragma unroll
    for (int j = 0; j < 4; ++j)
      acc[i][j] = (f32x4){0.f, 0.f, 0.f, 0.f};

  for (int kt = 0; kt < 4; ++kt){
    #pragma unroll
    for (int it = 0; it < 2; ++it){
      int ch = it*512 + tid;
      int r = ch >> 3, cc = ch & 7;
      gload_lds16(A + (row0 + r)*256 + kt*64 + ((cc ^ (r & 7))*8), &As[ch*8]);
    }
    #pragma unroll
    for (int it = 0; it < 4; ++it){
      int ch = it*512 + tid;
      int r = ch >> 3, cc = ch & 7;
      gload_lds16(Bt + r*256 + kt*64 + ((cc ^ (r & 7))*8), &Bs[ch*8]);
    }
    __syncthreads();
    #pragma unroll
    for (int ks = 0; ks < 2; ++ks){
      short8 af[4], bf[4];
      #pragma unroll
      for (int mi = 0; mi < 4; ++mi){
        int ar = wm*64 + mi*16 + l15;
        af[mi] = *(const short8*)&As[ar*64 + (((ks*4 + l4) ^ (ar & 7))*8)];
      }
      #pragma unroll
      for (int ni = 0; ni < 4; ++ni){
        int br = wn*64 + ni*16 + l15;
        bf[ni] = *(const short8*)&Bs[br*64 + (((ks*4 + l4) ^ (br & 7))*8)];
      }
      #pragma unroll
      for (int mi = 0; mi < 4; ++mi)
        #pragma unroll
        for (int ni = 0; ni < 4; ++ni)
          acc[mi][ni] = __builtin_amdgcn_mfma_f32_16x16x32_bf16(af[mi], bf[ni], acc[mi][ni], 0, 0, 0);
    }
    __syncthreads();
  }

  float bcol[4];
  #pragma unroll
  for (int ni = 0; ni < 4; ++ni) bcol[ni] = bias[wn*64 + ni*16 + l15];
  f32x4 psum[4], psq[4];
  #pragma unroll
  for (int mi = 0; mi < 4; ++mi){
    psum[mi] = (f32x4){0.f,0.f,0.f,0.f};
    psq[mi]  = (f32x4){0.f,0.f,0.f,0.f};
    #pragma unroll
    for (int ni = 0; ni < 4; ++ni){
      int col = wn*64 + ni*16 + l15;
      #pragma unroll
      for (int j = 0; j < 4; ++j){
        long row = row0 + wm*64 + mi*16 + 4*l4 + j;
        long idx = row * 256 + col;
        float v = acc[mi][ni][j] + bcol[ni] + res[idx];
        hout[idx] = f2bf(v);
        acc[mi][ni][j] = v;
        psum[mi][j] += v;
        psq[mi][j]  += v * v;
      }
    }
  }
  #pragma unroll
  for (int mi = 0; mi < 4; ++mi){
    #pragma unroll
    for (int j = 0; j < 4; ++j){
      float s = psum[mi][j], q = psq[mi][j];
      #pragma unroll
      for (int m = 1; m < 16; m <<= 1){
        s += __shfl_xor(s, m);
        q += __shfl_xor(q, m);
      }
      if (l15 == 0){
        int rl = wm*64 + mi*16 + 4*l4 + j;
        redsum[wn][rl] = s;
        redsq[wn][rl]  = q;
      }
    }
  }
  __syncthreads();
  if (tid < 128){
    float s = redsum[0][tid] + redsum[1][tid] + redsum[2][tid] + redsum[3][tid];
    float q = redsq[0][tid]  + redsq[1][tid]  + redsq[2][tid]  + redsq[3][tid];
    float mu = s * (1.f/256.f);
    mu_s[tid] = mu;
    rs_s[tid] = rsqrtf(q * (1.f/256.f) - mu*mu + 1e-5f);
  }
  __syncthreads();
  float gcol[4], b2col[4];
  #pragma unroll
  for (int ni = 0; ni < 4; ++ni){
    gcol[ni]  = g2[wn*64 + ni*16 + l15];
    b2col[ni] = b2[wn*64 + ni*16 + l15];
  }
  #pragma unroll
  for (int mi = 0; mi < 4; ++mi){
    #pragma unroll
    for (int j = 0; j < 4; ++j){
      int rl = wm*64 + mi*16 + 4*l4 + j;
      float mu = mu_s[rl], rs = rs_s[rl];
      long row = row0 + rl;
      #pragma unroll
      for (int ni = 0; ni < 4; ++ni){
        int col = wn*64 + ni*16 + l15;
        hn[row*256 + col] = f2fp8(16.f * ((acc[mi][ni][j] - mu)*rs*gcol[ni] + b2col[ni]));
      }
    }
  }
}

extern "C" void kernel_launch(void* const* d_in, const int* in_sizes, int n_in,
                              void* d_out, int out_size, void* d_ws, size_t ws_size,
                              hipStream_t stream){
  const float* x      = (const float*)d_in[0];
  const float* ln1_g  = (const float*)d_in[1];
  const float* ln1_b  = (const float*)d_in[2];
  const float* qkv_w  = (const float*)d_in[3];
  const float* qkv_b  = (const float*)d_in[4];
  const float* proj_w = (const float*)d_in[5];
  const float* proj_b = (const float*)d_in[6];
  const float* btab   = (const float*)d_in[7];
  const float* ln2_g  = (const float*)d_in[8];
  const float* ln2_b  = (const float*)d_in[9];
  const float* fc1_w  = (const float*)d_in[10];
  const float* fc1_b  = (const float*)d_in[11];
  const float* fc2_w  = (const float*)d_in[12];
  const float* fc2_b  = (const float*)d_in[13];

  const long M = (long)in_sizes[0] / 256;  // 262144 tokens

  char* ws = (char*)d_ws;
  // Layout (time-disjoint overlaps):
  //   [0, 67MB):        xn8 fp8 -> dead after qkv; ao bf16 [0,134) after attn;
  //                     act8 fp8 [0,268) after proj (all time-disjoint)
  //   [320MiB, 512MiB): qkv8 (fp8, 192MiB)
  //   [536.9, 604MB):   hn8 (fp8)
  //   [671MB, ...):     weights (wq/w1/w2 fp8, wp bf16)
  //   [712MiB, +134MB): hh (bf16 residual trunk)
  unsigned char*  xn8  = (unsigned char*)(ws);
  unsigned short* ao   = (unsigned short*)(ws);
  unsigned char*  act8 = (unsigned char*)(ws);
  unsigned char*  qkv8 = (unsigned char*)(ws + 335544320);
  unsigned char*  hn8  = (unsigned char*)(ws + 536870912);
  unsigned char*  wqf8 = (unsigned char*)(ws + 671088640);
  unsigned short* wp   = (unsigned short*)(wqf8 + 196608);
  unsigned char*  w1f8 = (unsigned char*)(wp + 256*256);
  unsigned char*  w2f8 = w1f8 + 256*1024;
  unsigned short* hh   = (unsigned short*)(ws + (712ull << 20));
  float* outf = (float*)d_out;

  // all 4 weight transposes in one launch (786432 elems)
  wconv4<<<3072, 256, 0, stream>>>(qkv_w, proj_w, fc1_w, fc2_w, wqf8, wp, w1f8, w2f8);

  // LN1 -> fp8*16
  ln_kernel<<<M/4, 256, 0, stream>>>(x, ln1_g, ln1_b, xn8);
  // QKV fp8 -> fp8*16 out (swizzled): nbx=6, scale 1/(16*64)
  gemm_fp8<3><<<6 * (M/128), 256, 0, stream>>>(xn8, wqf8, qkv_b, nullptr, qkv8, 768, 256, 6, 1.f/1024.f);
  // window attention (full fp8): one wave per (window, head)
  attn_kernel<<<(M/64) * 8, 64, 0, stream>>>(qkv8, btab, ao);
  // proj + residual + LN2  (h bf16 -> hh, hn fp8*16)
  proj_ln2<<<M/128, 512, 0, stream>>>(ao, wp, proj_b, x, ln2_g, ln2_b, hh, hn8);
  // FC1 fp8 + GELU -> act fp8 (swizzled): nbx=8, scale 1/(16*64)
  gemm_fp8<1><<<8 * (M/128), 256, 0, stream>>>(hn8, w1f8, fc1_b, nullptr, act8, 1024, 256, 8, 1.f/1024.f);
  // FC2 fp8 + residual(hh bf16) -> out f32 (swizzled): nbx=2, scale 1/(8*64)
  gemm_fp8<2><<<2 * (M/128), 256, 0, stream>>>(act8, w2f8, fc2_b, hh, outf, 256, 1024, 2, 1.f/512.f);
}

// Round 23
// 991.077 us; speedup vs baseline: 1.4612x; 1.0076x over previous
//
#include <hip/hip_runtime.h>
#include <hip/hip_bf16.h>
#include <math.h>

typedef __attribute__((ext_vector_type(8))) short short8;
typedef __attribute__((ext_vector_type(4))) float f32x4;

__device__ __forceinline__ unsigned short f2bf(float f){
  union { __hip_bfloat16 h; unsigned short u; } cv;
  cv.h = __float2bfloat16(f);
  return cv.u;
}

__device__ __forceinline__ float bf2f(unsigned short u){
  union { unsigned int i; float f; } v;
  v.i = ((unsigned int)u) << 16;
  return v.f;
}

__device__ __forceinline__ unsigned char f2fp8(float v){
  return (unsigned char)(__builtin_amdgcn_cvt_pk_fp8_f32(v, v, 0, 0) & 0xff);
}

// gelu via sigmoid: 0.5v(1+tanh(u)) == v*sigmoid(2u), exp2-folded constants
__device__ __forceinline__ float gelu_f(float v){
  float v2 = v * v;
  float nw = v * fmaf(-0.10294364f, v2, -2.3022090f);  // -2u*log2(e)
  float e  = __builtin_amdgcn_exp2f(nw);
  return v * __builtin_amdgcn_rcpf(1.f + e);
}

__device__ __forceinline__ void gload_lds16(const void* g, void* l){
  __builtin_amdgcn_global_load_lds(
      (const __attribute__((address_space(1))) void*)g,
      (__attribute__((address_space(3))) void*)l, 16, 0, 0);
}

// ---------------- all four weight transposes in one launch -------------------
// wq fp8*64; wp bf16; w1 fp8*64; w2 fp8*64
__global__ __launch_bounds__(256) void wconv4(
    const float* __restrict__ qkv_w, const float* __restrict__ proj_w,
    const float* __restrict__ fc1_w, const float* __restrict__ fc2_w,
    unsigned char* __restrict__ wq, unsigned short* __restrict__ wp,
    unsigned char* __restrict__ w1, unsigned char* __restrict__ w2){
  int idx = blockIdx.x * 256 + threadIdx.x;
  if (idx < 196608){                       // qkv: K=256 N=768 -> fp8 * 64
    int k = idx / 768, n = idx % 768;
    wq[n*256 + k] = f2fp8(qkv_w[idx] * 64.f);
  } else if (idx < 262144){                // proj: K=256 N=256 (bf16)
    int l = idx - 196608;
    int k = l >> 8, n = l & 255;
    wp[n*256 + k] = f2bf(proj_w[l]);
  } else if (idx < 524288){                // fc1: K=256 N=1024 -> fp8 * 64
    int l = idx - 262144;
    int k = l >> 10, n = l & 1023;
    w1[n*256 + k] = f2fp8(fc1_w[l] * 64.f);
  } else {                                 // fc2: K=1024 N=256 -> fp8 * 64
    int l = idx - 524288;
    int k = l >> 8, n = l & 255;
    w2[n*1024 + k] = f2fp8(fc2_w[l] * 64.f);
  }
}

// ---------------- LayerNorm: x f32 [M][256] -> out fp8*16 [M][256] -----------
__global__ __launch_bounds__(256) void ln_kernel(
    const float* __restrict__ x, const float* __restrict__ g,
    const float* __restrict__ b, unsigned char* __restrict__ out){
  const int lane = threadIdx.x & 63;
  const int wv = threadIdx.x >> 6;
  const long row = (long)blockIdx.x * 4 + wv;
  const float4 xv = ((const float4*)(x + row * 256))[lane];
  float s  = xv.x + xv.y + xv.z + xv.w;
  float s2 = xv.x*xv.x + xv.y*xv.y + xv.z*xv.z + xv.w*xv.w;
  #pragma unroll
  for (int m = 1; m < 64; m <<= 1){
    s  += __shfl_xor(s,  m);
    s2 += __shfl_xor(s2, m);
  }
  float mu = s * (1.f/256.f);
  float rs = rsqrtf(s2 * (1.f/256.f) - mu*mu + 1e-5f);
  float4 gv = ((const float4*)g)[lane];
  float4 bv = ((const float4*)b)[lane];
  float v0 = 16.f * ((xv.x - mu)*rs*gv.x + bv.x);
  float v1 = 16.f * ((xv.y - mu)*rs*gv.y + bv.y);
  float v2 = 16.f * ((xv.z - mu)*rs*gv.z + bv.z);
  float v3 = 16.f * ((xv.w - mu)*rs*gv.w + bv.w);
  int p = __builtin_amdgcn_cvt_pk_fp8_f32(v0, v1, 0, 0);
  p = __builtin_amdgcn_cvt_pk_fp8_f32(v2, v3, p, 1);
  ((unsigned int*)(out + row * 256))[lane] = (unsigned int)p;
}

// ---------------- fp8 GEMM: A fp8 [M][K] @ Bt fp8 [N][K] ---------------------
// BK=128 fp8, XOR-granule swizzle, XCD banding, swapped MFMA.
// MODE 0: out bf16 = acc*s + bias
// MODE 1: out fp8 = cvt(8 * gelu(acc*s + bias))
// MODE 2: out f32 = acc*s + bias + res(bf16)
// MODE 3: out fp8 = cvt(16 * (acc*s + bias))
template<int MODE>
__global__ __launch_bounds__(256, 4) void gemm_fp8(
    const unsigned char* __restrict__ A,
    const unsigned char* __restrict__ Bt,
    const float* __restrict__ bias,
    const unsigned short* __restrict__ res,
    void* __restrict__ out,
    int N, int K, int nbx, float sc){
  __shared__ unsigned char S[2*128*128];
  unsigned char* As = S;
  unsigned char* Bs = S + 128*128;
  const int tid  = threadIdx.x;
  const int lane = tid & 63;
  const int wave = tid >> 6;
  const int wm = wave >> 1, wn = wave & 1;

  const int nby  = gridDim.x / nbx;
  const int bid  = blockIdx.x;
  const int xcd  = bid & 7;
  const int local = bid >> 3;
  const int lrow = local / nbx;
  const int rowb = xcd * (nby >> 3) + lrow;
  const int colb = local - lrow * nbx;
  const long row0 = (long)rowb * 128;
  const int  col0 = colb * 128;
  const int l15 = lane & 15, l4 = lane >> 4;

  f32x4 acc[4][4];
  #pragma unroll
  for (int i = 0; i < 4; ++i)
    #pragma unroll
    for (int j = 0; j < 4; ++j)
      acc[i][j] = (f32x4){0.f, 0.f, 0.f, 0.f};

  const int nk = K >> 7;
  for (int kt = 0; kt < nk; ++kt){
    #pragma unroll
    for (int it = 0; it < 4; ++it){
      int ch = it*256 + tid;
      int r = ch >> 3, cc = ch & 7;
      int srcc = ((cc ^ (r & 7)) << 4);
      gload_lds16(A  + (row0 + r) * K + kt*128 + srcc, &As[ch*16]);
      gload_lds16(Bt + (long)(col0 + r) * K + kt*128 + srcc, &Bs[ch*16]);
    }
    __syncthreads();
    #pragma unroll
    for (int ks = 0; ks < 4; ++ks){
      long af[4], bfr[4];
      #pragma unroll
      for (int mi = 0; mi < 4; ++mi){
        int ar = wm*64 + mi*16 + l15;
        af[mi] = *(const long*)&As[ar*128 + (((2*ks + (l4 >> 1)) ^ (ar & 7)) << 4) + 8*(l4 & 1)];
      }
      #pragma unroll
      for (int ni = 0; ni < 4; ++ni){
        int br = wn*64 + ni*16 + l15;
        bfr[ni] = *(const long*)&Bs[br*128 + (((2*ks + (l4 >> 1)) ^ (br & 7)) << 4) + 8*(l4 & 1)];
      }
      #pragma unroll
      for (int mi = 0; mi < 4; ++mi)
        #pragma unroll
        for (int ni = 0; ni < 4; ++ni)
          acc[mi][ni] = __builtin_amdgcn_mfma_f32_16x16x32_fp8_fp8(bfr[ni], af[mi], acc[mi][ni], 0, 0, 0);
    }
    __syncthreads();
  }

  if (MODE == 2){
    float* outf = (float*)out;
    #pragma unroll
    for (int mi = 0; mi < 4; ++mi){
      long row = row0 + wm*64 + mi*16 + l15;
      #pragma unroll
      for (int ni = 0; ni < 4; ++ni){
        int colg = col0 + wn*64 + ni*16 + 4*l4;
        float4 bv = *(const float4*)&bias[colg];
        long idx = row * N + colg;
        ushort4 rv = *(const ushort4*)&res[idx];
        float4 o;
        o.x = acc[mi][ni][0]*sc + bv.x + bf2f(rv.x);
        o.y = acc[mi][ni][1]*sc + bv.y + bf2f(rv.y);
        o.z = acc[mi][ni][2]*sc + bv.z + bf2f(rv.z);
        o.w = acc[mi][ni][3]*sc + bv.w + bf2f(rv.w);
        *(float4*)&outf[idx] = o;
      }
    }
  } else if (MODE == 1 || MODE == 3){
    unsigned char* outp = (unsigned char*)out;
    #pragma unroll
    for (int mi = 0; mi < 4; ++mi){
      long row = row0 + wm*64 + mi*16 + l15;
      #pragma unroll
      for (int ni = 0; ni < 4; ++ni){
        int colg = col0 + wn*64 + ni*16 + 4*l4;
        float4 bv = *(const float4*)&bias[colg];
        float v0, v1, v2, v3;
        if (MODE == 1){
          v0 = 8.f * gelu_f(acc[mi][ni][0]*sc + bv.x);
          v1 = 8.f * gelu_f(acc[mi][ni][1]*sc + bv.y);
          v2 = 8.f * gelu_f(acc[mi][ni][2]*sc + bv.z);
          v3 = 8.f * gelu_f(acc[mi][ni][3]*sc + bv.w);
        } else {
          v0 = 16.f * (acc[mi][ni][0]*sc + bv.x);
          v1 = 16.f * (acc[mi][ni][1]*sc + bv.y);
          v2 = 16.f * (acc[mi][ni][2]*sc + bv.z);
          v3 = 16.f * (acc[mi][ni][3]*sc + bv.w);
        }
        int p = __builtin_amdgcn_cvt_pk_fp8_f32(v0, v1, 0, 0);
        p = __builtin_amdgcn_cvt_pk_fp8_f32(v2, v3, p, 1);
        *(unsigned int*)&outp[row * N + colg] = (unsigned int)p;
      }
    }
  } else {
    unsigned short* outp = (unsigned short*)out;
    #pragma unroll
    for (int mi = 0; mi < 4; ++mi){
      long row = row0 + wm*64 + mi*16 + l15;
      #pragma unroll
      for (int ni = 0; ni < 4; ++ni){
        int colg = col0 + wn*64 + ni*16 + 4*l4;
        float4 bv = *(const float4*)&bias[colg];
        uint2 dv;
        dv.x = ((unsigned int)f2bf(acc[mi][ni][1]*sc + bv.y) << 16) | f2bf(acc[mi][ni][0]*sc + bv.x);
        dv.y = ((unsigned int)f2bf(acc[mi][ni][3]*sc + bv.w) << 16) | f2bf(acc[mi][ni][2]*sc + bv.z);
        *(uint2*)&outp[row * N + colg] = dv;
      }
    }
  }
}

// ---------------- Window attention: one WAVE = one (window, head), full fp8 --
// qkv fp8*16. QK^T fp8 (scale absorbs 1/256). P fp8*16 in padded LDS.
// V staged early into LDS (4x 8B loads/lane, hidden under QK^T+softmax).
// PV fp8, result /256. ao bf16.
__global__ __launch_bounds__(64, 3) void attn_kernel(
    const unsigned char* __restrict__ qkv,
    const float* __restrict__ bt,
    unsigned short* __restrict__ ao){
  __shared__ unsigned int P8[64*18];      // 72B row stride (18 uints): bank-spread
  __shared__ unsigned char V8[64*32];     // V tile, row-major [tok][d]
  const int lane = threadIdx.x;
  const int wb = blockIdx.x;
  const int w = wb >> 3, h = wb & 7;
  const int bidx = w >> 10, rem = w & 1023;
  const int wy = rem >> 5, wx = rem & 31;
  const long tok0 = (long)bidx * 65536 + (long)wy * 2048 + wx * 8;
  const int l15 = lane & 15, l4 = lane >> 4;

  // ---- stage V early: 64 tok x 32B; 4 lanes cover one token row (32B)
  #pragma unroll
  for (int p = 0; p < 4; ++p){
    int t = p*16 + (lane >> 2);
    int ch = lane & 3;
    long tok = tok0 + (t >> 3) * 256 + (t & 7);
    *(unsigned long long*)&V8[t*32 + ch*8] =
        *(const unsigned long long*)(qkv + tok*768 + 512 + h*32 + ch*8);
  }

  long qf[4], kf[4];
  #pragma unroll
  for (int t = 0; t < 4; ++t){
    int n = t*16 + l15;
    long tok = tok0 + (n >> 3) * 256 + (n & 7);
    qf[t] = *(const long*)(qkv + tok*768 +       h*32 + 8*l4);
    kf[t] = *(const long*)(qkv + tok*768 + 256 + h*32 + 8*l4);
  }
  // swapped: s[mi][ni]: lane holds q = mi*16+l15, k = ni*16+4*l4+{0..3}
  f32x4 s[4][4];
  #pragma unroll
  for (int i = 0; i < 4; ++i)
    #pragma unroll
    for (int j = 0; j < 4; ++j)
      s[i][j] = (f32x4){0.f, 0.f, 0.f, 0.f};
  #pragma unroll
  for (int mi = 0; mi < 4; ++mi)
    #pragma unroll
    for (int ni = 0; ni < 4; ++ni)
      s[mi][ni] = __builtin_amdgcn_mfma_f32_16x16x32_fp8_fp8(kf[ni], qf[mi], s[mi][ni], 0, 0, 0);

  const float scale = 0.17677669529663687f / 256.f;  // undo q*16, k*16
  #pragma unroll
  for (int mi = 0; mi < 4; ++mi){
    int q = mi*16 + l15;
    int ny = q >> 3, nx = q & 7;
    #pragma unroll
    for (int ni = 0; ni < 4; ++ni){
      #pragma unroll
      for (int j = 0; j < 4; ++j){
        int k = ni*16 + 4*l4 + j;
        int db = (ny - (k >> 3) + 7) * 15 + (nx - (k & 7) + 7);
        s[mi][ni][j] = s[mi][ni][j] * scale + bt[db*8 + h];
      }
    }
    float mx = -1e30f;
    #pragma unroll
    for (int ni = 0; ni < 4; ++ni)
      #pragma unroll
      for (int j = 0; j < 4; ++j)
        mx = fmaxf(mx, s[mi][ni][j]);
    mx = fmaxf(mx, __shfl_xor(mx, 16));
    mx = fmaxf(mx, __shfl_xor(mx, 32));
    float sm = 0.f;
    #pragma unroll
    for (int ni = 0; ni < 4; ++ni)
      #pragma unroll
      for (int j = 0; j < 4; ++j){
        float p = __expf(s[mi][ni][j] - mx);
        s[mi][ni][j] = p;
        sm += p;
      }
    sm += __shfl_xor(sm, 16);
    sm += __shfl_xor(sm, 32);
    float inv16 = 16.f * __builtin_amdgcn_rcpf(sm);
    // packed P write: 4 consecutive k per lane, fp8*16 (uint-typed)
    #pragma unroll
    for (int ni = 0; ni < 4; ++ni){
      int p = __builtin_amdgcn_cvt_pk_fp8_f32(s[mi][ni][0]*inv16, s[mi][ni][1]*inv16, 0, 0);
      p = __builtin_amdgcn_cvt_pk_fp8_f32(s[mi][ni][2]*inv16, s[mi][ni][3]*inv16, p, 1);
      P8[q*18 + ni*4 + l4] = (unsigned int)p;
    }
  }
  __syncthreads();   // make P and V visible/ordered before PV reads

  // PV swapped: o[mi][ni]: lane holds token = mi*16+l15, d = ni*16+4*l4+{0..3}
  f32x4 o[4][2];
  #pragma unroll
  for (int i = 0; i < 4; ++i)
    #pragma unroll
    for (int j = 0; j < 2; ++j)
      o[i][j] = (f32x4){0.f, 0.f, 0.f, 0.f};
  #pragma unroll
  for (int kt = 0; kt < 2; ++kt){
    long vf[2];
    #pragma unroll
    for (int ni = 0; ni < 2; ++ni){
      union { unsigned char b[8]; long v; } tmp;
      #pragma unroll
      for (int i = 0; i < 8; ++i){
        int kk = kt*32 + 8*l4 + i;
        tmp.b[i] = V8[kk*32 + ni*16 + l15];
      }
      vf[ni] = tmp.v;
    }
    #pragma unroll
    for (int mi = 0; mi < 4; ++mi){
      int rr = mi*16 + l15;
      union { unsigned int u[2]; long v; } pfu;
      pfu.u[0] = P8[rr*18 + kt*8 + 2*l4];
      pfu.u[1] = P8[rr*18 + kt*8 + 2*l4 + 1];
      long pf = pfu.v;
      #pragma unroll
      for (int ni = 0; ni < 2; ++ni)
        o[mi][ni] = __builtin_amdgcn_mfma_f32_16x16x32_fp8_fp8(vf[ni], pf, o[mi][ni], 0, 0, 0);
    }
  }
  // packed ao write: 4 consecutive d per lane; undo P*16 and V*16
  const float osc = 1.f / 256.f;
  #pragma unroll
  for (int mi = 0; mi < 4; ++mi){
    int t = mi*16 + l15;
    long tok = tok0 + (t >> 3) * 256 + (t & 7);
    #pragma unroll
    for (int ni = 0; ni < 2; ++ni){
      uint2 dv;
      dv.x = ((unsigned int)f2bf(o[mi][ni][1]*osc) << 16) | f2bf(o[mi][ni][0]*osc);
      dv.y = ((unsigned int)f2bf(o[mi][ni][3]*osc) << 16) | f2bf(o[mi][ni][2]*osc);
      *(uint2*)&ao[tok*256 + h*32 + ni*16 + 4*l4] = dv;
    }
  }
}

// ---------------- proj + residual + LN2 fused --------------------------------
// writes h (bf16) and hn (fp8 e4m3 * 16); LN2 stats on exact f32 values
__global__ __launch_bounds__(512, 4) void proj_ln2(
    const unsigned short* __restrict__ A,
    const unsigned short* __restrict__ Bt,
    const float* __restrict__ bias,
    const float* __restrict__ res,
    const float* __restrict__ g2,
    const float* __restrict__ b2,
    unsigned short* __restrict__ hout,
    unsigned char* __restrict__ hn){
  __shared__ unsigned short As[128*64];
  __shared__ unsigned short Bs[256*64];
  __shared__ float redsum[4][128];
  __shared__ float redsq[4][128];
  __shared__ float mu_s[128];
  __shared__ float rs_s[128];
  const int tid = threadIdx.x, lane = tid & 63, wave = tid >> 6;
  const int l15 = lane & 15, l4 = lane >> 4;
  const int wm = wave >> 2, wn = wave & 3;
  const long row0 = (long)blockIdx.x * 128;

  f32x4 acc[4][4];
  #pragma unroll
  for (int i = 0; i < 4; ++i)
    #pragma unroll
    for (int j = 0; j < 4; ++j)
      acc[i][j] = (f32x4){0.f, 0.f, 0.f, 0.f};

  for (int kt = 0; kt < 4; ++kt){
    #pragma unroll
    for (int it = 0; it < 2; ++it){
      int ch = it*512 + tid;
      int r = ch >> 3, cc = ch & 7;
      gload_lds16(A + (row0 + r)*256 + kt*64 + ((cc ^ (r & 7))*8), &As[ch*8]);
    }
    #pragma unroll
    for (int it = 0; it < 4; ++it){
      int ch = it*512 + tid;
      int r = ch >> 3, cc = ch & 7;
      gload_lds16(Bt + r*256 + kt*64 + ((cc ^ (r & 7))*8), &Bs[ch*8]);
    }
    __syncthreads();
    #pragma unroll
    for (int ks = 0; ks < 2; ++ks){
      short8 af[4], bf[4];
      #pragma unroll
      for (int mi = 0; mi < 4; ++mi){
        int ar = wm*64 + mi*16 + l15;
        af[mi] = *(const short8*)&As[ar*64 + (((ks*4 + l4) ^ (ar & 7))*8)];
      }
      #pragma unroll
      for (int ni = 0; ni < 4; ++ni){
        int br = wn*64 + ni*16 + l15;
        bf[ni] = *(const short8*)&Bs[br*64 + (((ks*4 + l4) ^ (br & 7))*8)];
      }
      #pragma unroll
      for (int mi = 0; mi < 4; ++mi)
        #pragma unroll
        for (int ni = 0; ni < 4; ++ni)
          acc[mi][ni] = __builtin_amdgcn_mfma_f32_16x16x32_bf16(af[mi], bf[ni], acc[mi][ni], 0, 0, 0);
    }
    __syncthreads();
  }

  float bcol[4];
  #pragma unroll
  for (int ni = 0; ni < 4; ++ni) bcol[ni] = bias[wn*64 + ni*16 + l15];
  f32x4 psum[4], psq[4];
  #pragma unroll
  for (int mi = 0; mi < 4; ++mi){
    psum[mi] = (f32x4){0.f,0.f,0.f,0.f};
    psq[mi]  = (f32x4){0.f,0.f,0.f,0.f};
    #pragma unroll
    for (int ni = 0; ni < 4; ++ni){
      int col = wn*64 + ni*16 + l15;
      #pragma unroll
      for (int j = 0; j < 4; ++j){
        long row = row0 + wm*64 + mi*16 + 4*l4 + j;
        long idx = row * 256 + col;
        float v = acc[mi][ni][j] + bcol[ni] + res[idx];
        hout[idx] = f2bf(v);
        acc[mi][ni][j] = v;
        psum[mi][j] += v;
        psq[mi][j]  += v * v;
      }
    }
  }
  #pragma unroll
  for (int mi = 0; mi < 4; ++mi){
    #pragma unroll
    for (int j = 0; j < 4; ++j){
      float s = psum[mi][j], q = psq[mi][j];
      #pragma unroll
      for (int m = 1; m < 16; m <<= 1){
        s += __shfl_xor(s, m);
        q += __shfl_xor(q, m);
      }
      if (l15 == 0){
        int rl = wm*64 + mi*16 + 4*l4 + j;
        redsum[wn][rl] = s;
        redsq[wn][rl]  = q;
      }
    }
  }
  __syncthreads();
  if (tid < 128){
    float s = redsum[0][tid] + redsum[1][tid] + redsum[2][tid] + redsum[3][tid];
    float q = redsq[0][tid]  + redsq[1][tid]  + redsq[2][tid]  + redsq[3][tid];
    float mu = s * (1.f/256.f);
    mu_s[tid] = mu;
    rs_s[tid] = rsqrtf(q * (1.f/256.f) - mu*mu + 1e-5f);
  }
  __syncthreads();
  float gcol[4], b2col[4];
  #pragma unroll
  for (int ni = 0; ni < 4; ++ni){
    gcol[ni]  = g2[wn*64 + ni*16 + l15];
    b2col[ni] = b2[wn*64 + ni*16 + l15];
  }
  #pragma unroll
  for (int mi = 0; mi < 4; ++mi){
    #pragma unroll
    for (int j = 0; j < 4; ++j){
      int rl = wm*64 + mi*16 + 4*l4 + j;
      float mu = mu_s[rl], rs = rs_s[rl];
      long row = row0 + rl;
      #pragma unroll
      for (int ni = 0; ni < 4; ++ni){
        int col = wn*64 + ni*16 + l15;
        hn[row*256 + col] = f2fp8(16.f * ((acc[mi][ni][j] - mu)*rs*gcol[ni] + b2col[ni]));
      }
    }
  }
}

extern "C" void kernel_launch(void* const* d_in, const int* in_sizes, int n_in,
                              void* d_out, int out_size, void* d_ws, size_t ws_size,
                              hipStream_t stream){
  const float* x      = (const float*)d_in[0];
  const float* ln1_g  = (const float*)d_in[1];
  const float* ln1_b  = (const float*)d_in[2];
  const float* qkv_w  = (const float*)d_in[3];
  const float* qkv_b  = (const float*)d_in[4];
  const float* proj_w = (const float*)d_in[5];
  const float* proj_b = (const float*)d_in[6];
  const float* btab   = (const float*)d_in[7];
  const float* ln2_g  = (const float*)d_in[8];
  const float* ln2_b  = (const float*)d_in[9];
  const float* fc1_w  = (const float*)d_in[10];
  const float* fc1_b  = (const float*)d_in[11];
  const float* fc2_w  = (const float*)d_in[12];
  const float* fc2_b  = (const float*)d_in[13];

  const long M = (long)in_sizes[0] / 256;  // 262144 tokens

  char* ws = (char*)d_ws;
  // Layout (time-disjoint overlaps):
  //   [0, 67MB):        xn8 fp8 -> dead after qkv; ao bf16 [0,134) after attn;
  //                     act8 fp8 [0,268) after proj (all time-disjoint)
  //   [320MiB, 512MiB): qkv8 (fp8, 192MiB)
  //   [536.9, 604MB):   hn8 (fp8)
  //   [671MB, ...):     weights (wq/w1/w2 fp8, wp bf16)
  //   [712MiB, +134MB): hh (bf16 residual trunk)
  unsigned char*  xn8  = (unsigned char*)(ws);
  unsigned short* ao   = (unsigned short*)(ws);
  unsigned char*  act8 = (unsigned char*)(ws);
  unsigned char*  qkv8 = (unsigned char*)(ws + 335544320);
  unsigned char*  hn8  = (unsigned char*)(ws + 536870912);
  unsigned char*  wqf8 = (unsigned char*)(ws + 671088640);
  unsigned short* wp   = (unsigned short*)(wqf8 + 196608);
  unsigned char*  w1f8 = (unsigned char*)(wp + 256*256);
  unsigned char*  w2f8 = w1f8 + 256*1024;
  unsigned short* hh   = (unsigned short*)(ws + (712ull << 20));
  float* outf = (float*)d_out;

  // all 4 weight transposes in one launch (786432 elems)
  wconv4<<<3072, 256, 0, stream>>>(qkv_w, proj_w, fc1_w, fc2_w, wqf8, wp, w1f8, w2f8);

  // LN1 -> fp8*16
  ln_kernel<<<M/4, 256, 0, stream>>>(x, ln1_g, ln1_b, xn8);
  // QKV fp8 -> fp8*16 out (swizzled): nbx=6, scale 1/(16*64)
  gemm_fp8<3><<<6 * (M/128), 256, 0, stream>>>(xn8, wqf8, qkv_b, nullptr, qkv8, 768, 256, 6, 1.f/1024.f);
  // window attention (full fp8): one wave per (window, head)
  attn_kernel<<<(M/64) * 8, 64, 0, stream>>>(qkv8, btab, ao);
  // proj + residual + LN2  (h bf16 -> hh, hn fp8*16)
  proj_ln2<<<M/128, 512, 0, stream>>>(ao, wp, proj_b, x, ln2_g, ln2_b, hh, hn8);
  // FC1 fp8 + GELU -> act fp8 (swizzled): nbx=8, scale 1/(16*64)
  gemm_fp8<1><<<8 * (M/128), 256, 0, stream>>>(hn8, w1f8, fc1_b, nullptr, act8, 1024, 256, 8, 1.f/1024.f);
  // FC2 fp8 + residual(hh bf16) -> out f32 (swizzled): nbx=2, scale 1/(8*64)
  gemm_fp8<2><<<2 * (M/128), 256, 0, stream>>>(act8, w2f8, fc2_b, hh, outf, 256, 1024, 2, 1.f/512.f);
}

// Round 24
// 962.561 us; speedup vs baseline: 1.5045x; 1.0296x over previous
//
#include <hip/hip_runtime.h>
#include <hip/hip_bf16.h>
#include <math.h>

typedef __attribute__((ext_vector_type(8))) short short8;
typedef __attribute__((ext_vector_type(4))) float f32x4;

__device__ __forceinline__ unsigned short f2bf(float f){
  union { __hip_bfloat16 h; unsigned short u; } cv;
  cv.h = __float2bfloat16(f);
  return cv.u;
}

__device__ __forceinline__ float bf2f(unsigned short u){
  union { unsigned int i; float f; } v;
  v.i = ((unsigned int)u) << 16;
  return v.f;
}

__device__ __forceinline__ unsigned char f2fp8(float v){
  return (unsigned char)(__builtin_amdgcn_cvt_pk_fp8_f32(v, v, 0, 0) & 0xff);
}

// gelu via sigmoid: 0.5v(1+tanh(u)) == v*sigmoid(2u), exp2-folded constants
__device__ __forceinline__ float gelu_f(float v){
  float v2 = v * v;
  float nw = v * fmaf(-0.10294364f, v2, -2.3022090f);  // -2u*log2(e)
  float e  = __builtin_amdgcn_exp2f(nw);
  return v * __builtin_amdgcn_rcpf(1.f + e);
}

__device__ __forceinline__ void gload_lds16(const void* g, void* l){
  __builtin_amdgcn_global_load_lds(
      (const __attribute__((address_space(1))) void*)g,
      (__attribute__((address_space(3))) void*)l, 16, 0, 0);
}

// ---------------- all four weight transposes in one launch -------------------
// wq fp8*64; wp fp8*64; w1 fp8*64; w2 fp8*64
__global__ __launch_bounds__(256) void wconv4(
    const float* __restrict__ qkv_w, const float* __restrict__ proj_w,
    const float* __restrict__ fc1_w, const float* __restrict__ fc2_w,
    unsigned char* __restrict__ wq, unsigned char* __restrict__ wp,
    unsigned char* __restrict__ w1, unsigned char* __restrict__ w2){
  int idx = blockIdx.x * 256 + threadIdx.x;
  if (idx < 196608){                       // qkv: K=256 N=768 -> fp8 * 64
    int k = idx / 768, n = idx % 768;
    wq[n*256 + k] = f2fp8(qkv_w[idx] * 64.f);
  } else if (idx < 262144){                // proj: K=256 N=256 -> fp8 * 64
    int l = idx - 196608;
    int k = l >> 8, n = l & 255;
    wp[n*256 + k] = f2fp8(proj_w[l] * 64.f);
  } else if (idx < 524288){                // fc1: K=256 N=1024 -> fp8 * 64
    int l = idx - 262144;
    int k = l >> 10, n = l & 1023;
    w1[n*256 + k] = f2fp8(fc1_w[l] * 64.f);
  } else {                                 // fc2: K=1024 N=256 -> fp8 * 64
    int l = idx - 524288;
    int k = l >> 8, n = l & 255;
    w2[n*1024 + k] = f2fp8(fc2_w[l] * 64.f);
  }
}

// ---------------- LayerNorm: x f32 [M][256] -> out fp8*16 [M][256] -----------
__global__ __launch_bounds__(256) void ln_kernel(
    const float* __restrict__ x, const float* __restrict__ g,
    const float* __restrict__ b, unsigned char* __restrict__ out){
  const int lane = threadIdx.x & 63;
  const int wv = threadIdx.x >> 6;
  const long row = (long)blockIdx.x * 4 + wv;
  const float4 xv = ((const float4*)(x + row * 256))[lane];
  float s  = xv.x + xv.y + xv.z + xv.w;
  float s2 = xv.x*xv.x + xv.y*xv.y + xv.z*xv.z + xv.w*xv.w;
  #pragma unroll
  for (int m = 1; m < 64; m <<= 1){
    s  += __shfl_xor(s,  m);
    s2 += __shfl_xor(s2, m);
  }
  float mu = s * (1.f/256.f);
  float rs = rsqrtf(s2 * (1.f/256.f) - mu*mu + 1e-5f);
  float4 gv = ((const float4*)g)[lane];
  float4 bv = ((const float4*)b)[lane];
  float v0 = 16.f * ((xv.x - mu)*rs*gv.x + bv.x);
  float v1 = 16.f * ((xv.y - mu)*rs*gv.y + bv.y);
  float v2 = 16.f * ((xv.z - mu)*rs*gv.z + bv.z);
  float v3 = 16.f * ((xv.w - mu)*rs*gv.w + bv.w);
  int p = __builtin_amdgcn_cvt_pk_fp8_f32(v0, v1, 0, 0);
  p = __builtin_amdgcn_cvt_pk_fp8_f32(v2, v3, p, 1);
  ((unsigned int*)(out + row * 256))[lane] = (unsigned int)p;
}

// ---------------- fp8 GEMM: A fp8 [M][K] @ Bt fp8 [N][K] ---------------------
// BK=128 fp8, XOR-granule swizzle, XCD banding, swapped MFMA.
// MODE 1: out fp8 = cvt(8 * gelu(acc*s + bias))
// MODE 2: out f32 = acc*s + bias + res(bf16)
// MODE 3: out fp8 = cvt(16 * (acc*s + bias))
template<int MODE>
__global__ __launch_bounds__(256, 4) void gemm_fp8(
    const unsigned char* __restrict__ A,
    const unsigned char* __restrict__ Bt,
    const float* __restrict__ bias,
    const unsigned short* __restrict__ res,
    void* __restrict__ out,
    int N, int K, int nbx, float sc){
  __shared__ unsigned char S[2*128*128];
  unsigned char* As = S;
  unsigned char* Bs = S + 128*128;
  const int tid  = threadIdx.x;
  const int lane = tid & 63;
  const int wave = tid >> 6;
  const int wm = wave >> 1, wn = wave & 1;

  const int nby  = gridDim.x / nbx;
  const int bid  = blockIdx.x;
  const int xcd  = bid & 7;
  const int local = bid >> 3;
  const int lrow = local / nbx;
  const int rowb = xcd * (nby >> 3) + lrow;
  const int colb = local - lrow * nbx;
  const long row0 = (long)rowb * 128;
  const int  col0 = colb * 128;
  const int l15 = lane & 15, l4 = lane >> 4;

  f32x4 acc[4][4];
  #pragma unroll
  for (int i = 0; i < 4; ++i)
    #pragma unroll
    for (int j = 0; j < 4; ++j)
      acc[i][j] = (f32x4){0.f, 0.f, 0.f, 0.f};

  const int nk = K >> 7;
  for (int kt = 0; kt < nk; ++kt){
    #pragma unroll
    for (int it = 0; it < 4; ++it){
      int ch = it*256 + tid;
      int r = ch >> 3, cc = ch & 7;
      int srcc = ((cc ^ (r & 7)) << 4);
      gload_lds16(A  + (row0 + r) * K + kt*128 + srcc, &As[ch*16]);
      gload_lds16(Bt + (long)(col0 + r) * K + kt*128 + srcc, &Bs[ch*16]);
    }
    __syncthreads();
    #pragma unroll
    for (int ks = 0; ks < 4; ++ks){
      long af[4], bfr[4];
      #pragma unroll
      for (int mi = 0; mi < 4; ++mi){
        int ar = wm*64 + mi*16 + l15;
        af[mi] = *(const long*)&As[ar*128 + (((2*ks + (l4 >> 1)) ^ (ar & 7)) << 4) + 8*(l4 & 1)];
      }
      #pragma unroll
      for (int ni = 0; ni < 4; ++ni){
        int br = wn*64 + ni*16 + l15;
        bfr[ni] = *(const long*)&Bs[br*128 + (((2*ks + (l4 >> 1)) ^ (br & 7)) << 4) + 8*(l4 & 1)];
      }
      #pragma unroll
      for (int mi = 0; mi < 4; ++mi)
        #pragma unroll
        for (int ni = 0; ni < 4; ++ni)
          acc[mi][ni] = __builtin_amdgcn_mfma_f32_16x16x32_fp8_fp8(bfr[ni], af[mi], acc[mi][ni], 0, 0, 0);
    }
    __syncthreads();
  }

  if (MODE == 2){
    float* outf = (float*)out;
    #pragma unroll
    for (int mi = 0; mi < 4; ++mi){
      long row = row0 + wm*64 + mi*16 + l15;
      #pragma unroll
      for (int ni = 0; ni < 4; ++ni){
        int colg = col0 + wn*64 + ni*16 + 4*l4;
        float4 bv = *(const float4*)&bias[colg];
        long idx = row * N + colg;
        ushort4 rv = *(const ushort4*)&res[idx];
        float4 o;
        o.x = acc[mi][ni][0]*sc + bv.x + bf2f(rv.x);
        o.y = acc[mi][ni][1]*sc + bv.y + bf2f(rv.y);
        o.z = acc[mi][ni][2]*sc + bv.z + bf2f(rv.z);
        o.w = acc[mi][ni][3]*sc + bv.w + bf2f(rv.w);
        *(float4*)&outf[idx] = o;
      }
    }
  } else {
    unsigned char* outp = (unsigned char*)out;
    #pragma unroll
    for (int mi = 0; mi < 4; ++mi){
      long row = row0 + wm*64 + mi*16 + l15;
      #pragma unroll
      for (int ni = 0; ni < 4; ++ni){
        int colg = col0 + wn*64 + ni*16 + 4*l4;
        float4 bv = *(const float4*)&bias[colg];
        float v0, v1, v2, v3;
        if (MODE == 1){
          v0 = 8.f * gelu_f(acc[mi][ni][0]*sc + bv.x);
          v1 = 8.f * gelu_f(acc[mi][ni][1]*sc + bv.y);
          v2 = 8.f * gelu_f(acc[mi][ni][2]*sc + bv.z);
          v3 = 8.f * gelu_f(acc[mi][ni][3]*sc + bv.w);
        } else {
          v0 = 16.f * (acc[mi][ni][0]*sc + bv.x);
          v1 = 16.f * (acc[mi][ni][1]*sc + bv.y);
          v2 = 16.f * (acc[mi][ni][2]*sc + bv.z);
          v3 = 16.f * (acc[mi][ni][3]*sc + bv.w);
        }
        int p = __builtin_amdgcn_cvt_pk_fp8_f32(v0, v1, 0, 0);
        p = __builtin_amdgcn_cvt_pk_fp8_f32(v2, v3, p, 1);
        *(unsigned int*)&outp[row * N + colg] = (unsigned int)p;
      }
    }
  }
}

// ---------------- Window attention: one WAVE = one (window, head), full fp8 --
// qkv fp8*16. QK^T fp8 (scale absorbs 1/256). P fp8*16 in padded LDS.
// V staged early into LDS. PV fp8. ao fp8*16 (packed uint stores).
__global__ __launch_bounds__(64, 3) void attn_kernel(
    const unsigned char* __restrict__ qkv,
    const float* __restrict__ bt,
    unsigned char* __restrict__ ao){
  __shared__ unsigned int P8[64*18];      // 72B row stride (18 uints): bank-spread
  __shared__ unsigned char V8[64*32];     // V tile, row-major [tok][d]
  const int lane = threadIdx.x;
  const int wb = blockIdx.x;
  const int w = wb >> 3, h = wb & 7;
  const int bidx = w >> 10, rem = w & 1023;
  const int wy = rem >> 5, wx = rem & 31;
  const long tok0 = (long)bidx * 65536 + (long)wy * 2048 + wx * 8;
  const int l15 = lane & 15, l4 = lane >> 4;

  // ---- stage V early: 64 tok x 32B; 4 lanes cover one token row (32B)
  #pragma unroll
  for (int p = 0; p < 4; ++p){
    int t = p*16 + (lane >> 2);
    int ch = lane & 3;
    long tok = tok0 + (t >> 3) * 256 + (t & 7);
    *(unsigned long long*)&V8[t*32 + ch*8] =
        *(const unsigned long long*)(qkv + tok*768 + 512 + h*32 + ch*8);
  }

  long qf[4], kf[4];
  #pragma unroll
  for (int t = 0; t < 4; ++t){
    int n = t*16 + l15;
    long tok = tok0 + (n >> 3) * 256 + (n & 7);
    qf[t] = *(const long*)(qkv + tok*768 +       h*32 + 8*l4);
    kf[t] = *(const long*)(qkv + tok*768 + 256 + h*32 + 8*l4);
  }
  // swapped: s[mi][ni]: lane holds q = mi*16+l15, k = ni*16+4*l4+{0..3}
  f32x4 s[4][4];
  #pragma unroll
  for (int i = 0; i < 4; ++i)
    #pragma unroll
    for (int j = 0; j < 4; ++j)
      s[i][j] = (f32x4){0.f, 0.f, 0.f, 0.f};
  #pragma unroll
  for (int mi = 0; mi < 4; ++mi)
    #pragma unroll
    for (int ni = 0; ni < 4; ++ni)
      s[mi][ni] = __builtin_amdgcn_mfma_f32_16x16x32_fp8_fp8(kf[ni], qf[mi], s[mi][ni], 0, 0, 0);

  const float scale = 0.17677669529663687f / 256.f;  // undo q*16, k*16
  #pragma unroll
  for (int mi = 0; mi < 4; ++mi){
    int q = mi*16 + l15;
    int ny = q >> 3, nx = q & 7;
    #pragma unroll
    for (int ni = 0; ni < 4; ++ni){
      #pragma unroll
      for (int j = 0; j < 4; ++j){
        int k = ni*16 + 4*l4 + j;
        int db = (ny - (k >> 3) + 7) * 15 + (nx - (k & 7) + 7);
        s[mi][ni][j] = s[mi][ni][j] * scale + bt[db*8 + h];
      }
    }
    float mx = -1e30f;
    #pragma unroll
    for (int ni = 0; ni < 4; ++ni)
      #pragma unroll
      for (int j = 0; j < 4; ++j)
        mx = fmaxf(mx, s[mi][ni][j]);
    mx = fmaxf(mx, __shfl_xor(mx, 16));
    mx = fmaxf(mx, __shfl_xor(mx, 32));
    float sm = 0.f;
    #pragma unroll
    for (int ni = 0; ni < 4; ++ni)
      #pragma unroll
      for (int j = 0; j < 4; ++j){
        float p = __expf(s[mi][ni][j] - mx);
        s[mi][ni][j] = p;
        sm += p;
      }
    sm += __shfl_xor(sm, 16);
    sm += __shfl_xor(sm, 32);
    float inv16 = 16.f * __builtin_amdgcn_rcpf(sm);
    // packed P write: 4 consecutive k per lane, fp8*16 (uint-typed)
    #pragma unroll
    for (int ni = 0; ni < 4; ++ni){
      int p = __builtin_amdgcn_cvt_pk_fp8_f32(s[mi][ni][0]*inv16, s[mi][ni][1]*inv16, 0, 0);
      p = __builtin_amdgcn_cvt_pk_fp8_f32(s[mi][ni][2]*inv16, s[mi][ni][3]*inv16, p, 1);
      P8[q*18 + ni*4 + l4] = (unsigned int)p;
    }
  }
  __syncthreads();   // make P and V visible/ordered before PV reads

  // PV swapped: o[mi][ni]: lane holds token = mi*16+l15, d = ni*16+4*l4+{0..3}
  f32x4 o[4][2];
  #pragma unroll
  for (int i = 0; i < 4; ++i)
    #pragma unroll
    for (int j = 0; j < 2; ++j)
      o[i][j] = (f32x4){0.f, 0.f, 0.f, 0.f};
  #pragma unroll
  for (int kt = 0; kt < 2; ++kt){
    long vf[2];
    #pragma unroll
    for (int ni = 0; ni < 2; ++ni){
      union { unsigned char b[8]; long v; } tmp;
      #pragma unroll
      for (int i = 0; i < 8; ++i){
        int kk = kt*32 + 8*l4 + i;
        tmp.b[i] = V8[kk*32 + ni*16 + l15];
      }
      vf[ni] = tmp.v;
    }
    #pragma unroll
    for (int mi = 0; mi < 4; ++mi){
      int rr = mi*16 + l15;
      union { unsigned int u[2]; long v; } pfu;
      pfu.u[0] = P8[rr*18 + kt*8 + 2*l4];
      pfu.u[1] = P8[rr*18 + kt*8 + 2*l4 + 1];
      long pf = pfu.v;
      #pragma unroll
      for (int ni = 0; ni < 2; ++ni)
        o[mi][ni] = __builtin_amdgcn_mfma_f32_16x16x32_fp8_fp8(vf[ni], pf, o[mi][ni], 0, 0, 0);
    }
  }
  // packed ao write: fp8*16 per element; acc*(1/256) then *16 => 1/16
  const float osc = 1.f / 16.f;
  #pragma unroll
  for (int mi = 0; mi < 4; ++mi){
    int t = mi*16 + l15;
    long tok = tok0 + (t >> 3) * 256 + (t & 7);
    #pragma unroll
    for (int ni = 0; ni < 2; ++ni){
      int p = __builtin_amdgcn_cvt_pk_fp8_f32(o[mi][ni][0]*osc, o[mi][ni][1]*osc, 0, 0);
      p = __builtin_amdgcn_cvt_pk_fp8_f32(o[mi][ni][2]*osc, o[mi][ni][3]*osc, p, 1);
      *(unsigned int*)&ao[tok*256 + h*32 + ni*16 + 4*l4] = (unsigned int)p;
    }
  }
}

// ---------------- proj + residual + LN2 fused (fp8 GEMM path) ----------------
// A=ao fp8*16 [M][256] @ wp fp8*64 [256][256], acc/1024 + bias + res(x f32)
// writes h (bf16) and hn (fp8 e4m3 * 16); LN2 stats on exact f32 values
__global__ __launch_bounds__(512, 4) void proj_ln2(
    const unsigned char* __restrict__ A,
    const unsigned char* __restrict__ Bt,
    const float* __restrict__ bias,
    const float* __restrict__ res,
    const float* __restrict__ g2,
    const float* __restrict__ b2,
    unsigned short* __restrict__ hout,
    unsigned char* __restrict__ hn){
  __shared__ unsigned char As[128*128];   // 16 KB
  __shared__ unsigned char Bs[256*128];   // 32 KB
  __shared__ float redsum[4][128];
  __shared__ float redsq[4][128];
  __shared__ float mu_s[128];
  __shared__ float rs_s[128];
  const int tid = threadIdx.x, lane = tid & 63, wave = tid >> 6;
  const int l15 = lane & 15, l4 = lane >> 4;
  const int wm = wave >> 2, wn = wave & 3;
  const long row0 = (long)blockIdx.x * 128;

  f32x4 acc[4][4];
  #pragma unroll
  for (int i = 0; i < 4; ++i)
    #pragma unroll
    for (int j = 0; j < 4; ++j)
      acc[i][j] = (f32x4){0.f, 0.f, 0.f, 0.f};

  for (int kt = 0; kt < 2; ++kt){
    // stage A: 128 rows x 8 granules (16B); B: 256 rows x 8 granules
    #pragma unroll
    for (int it = 0; it < 2; ++it){
      int ch = it*512 + tid;
      int r = ch >> 3, cc = ch & 7;
      gload_lds16(A + (row0 + r)*256 + kt*128 + ((cc ^ (r & 7)) << 4), &As[ch*16]);
    }
    #pragma unroll
    for (int it = 0; it < 4; ++it){
      int ch = it*512 + tid;
      int r = ch >> 3, cc = ch & 7;
      gload_lds16(Bt + r*256 + kt*128 + ((cc ^ (r & 7)) << 4), &Bs[ch*16]);
    }
    __syncthreads();
    #pragma unroll
    for (int ks = 0; ks < 4; ++ks){
      long af[4], bf[4];
      #pragma unroll
      for (int mi = 0; mi < 4; ++mi){
        int ar = wm*64 + mi*16 + l15;
        af[mi] = *(const long*)&As[ar*128 + (((2*ks + (l4 >> 1)) ^ (ar & 7)) << 4) + 8*(l4 & 1)];
      }
      #pragma unroll
      for (int ni = 0; ni < 4; ++ni){
        int br = wn*64 + ni*16 + l15;
        bf[ni] = *(const long*)&Bs[br*128 + (((2*ks + (l4 >> 1)) ^ (br & 7)) << 4) + 8*(l4 & 1)];
      }
      #pragma unroll
      for (int mi = 0; mi < 4; ++mi)
        #pragma unroll
        for (int ni = 0; ni < 4; ++ni)
          acc[mi][ni] = __builtin_amdgcn_mfma_f32_16x16x32_fp8_fp8(af[mi], bf[ni], acc[mi][ni], 0, 0, 0);
    }
    __syncthreads();
  }

  const float sc = 1.f / 1024.f;   // undo ao*16, wp*64
  float bcol[4];
  #pragma unroll
  for (int ni = 0; ni < 4; ++ni) bcol[ni] = bias[wn*64 + ni*16 + l15];
  f32x4 psum[4], psq[4];
  #pragma unroll
  for (int mi = 0; mi < 4; ++mi){
    psum[mi] = (f32x4){0.f,0.f,0.f,0.f};
    psq[mi]  = (f32x4){0.f,0.f,0.f,0.f};
    #pragma unroll
    for (int ni = 0; ni < 4; ++ni){
      int col = wn*64 + ni*16 + l15;
      #pragma unroll
      for (int j = 0; j < 4; ++j){
        long row = row0 + wm*64 + mi*16 + 4*l4 + j;
        long idx = row * 256 + col;
        float v = acc[mi][ni][j]*sc + bcol[ni] + res[idx];
        hout[idx] = f2bf(v);
        acc[mi][ni][j] = v;
        psum[mi][j] += v;
        psq[mi][j]  += v * v;
      }
    }
  }
  #pragma unroll
  for (int mi = 0; mi < 4; ++mi){
    #pragma unroll
    for (int j = 0; j < 4; ++j){
      float s = psum[mi][j], q = psq[mi][j];
      #pragma unroll
      for (int m = 1; m < 16; m <<= 1){
        s += __shfl_xor(s, m);
        q += __shfl_xor(q, m);
      }
      if (l15 == 0){
        int rl = wm*64 + mi*16 + 4*l4 + j;
        redsum[wn][rl] = s;
        redsq[wn][rl]  = q;
      }
    }
  }
  __syncthreads();
  if (tid < 128){
    float s = redsum[0][tid] + redsum[1][tid] + redsum[2][tid] + redsum[3][tid];
    float q = redsq[0][tid]  + redsq[1][tid]  + redsq[2][tid]  + redsq[3][tid];
    float mu = s * (1.f/256.f);
    mu_s[tid] = mu;
    rs_s[tid] = rsqrtf(q * (1.f/256.f) - mu*mu + 1e-5f);
  }
  __syncthreads();
  float gcol[4], b2col[4];
  #pragma unroll
  for (int ni = 0; ni < 4; ++ni){
    gcol[ni]  = g2[wn*64 + ni*16 + l15];
    b2col[ni] = b2[wn*64 + ni*16 + l15];
  }
  #pragma unroll
  for (int mi = 0; mi < 4; ++mi){
    #pragma unroll
    for (int j = 0; j < 4; ++j){
      int rl = wm*64 + mi*16 + 4*l4 + j;
      float mu = mu_s[rl], rs = rs_s[rl];
      long row = row0 + rl;
      #pragma unroll
      for (int ni = 0; ni < 4; ++ni){
        int col = wn*64 + ni*16 + l15;
        hn[row*256 + col] = f2fp8(16.f * ((acc[mi][ni][j] - mu)*rs*gcol[ni] + b2col[ni]));
      }
    }
  }
}

extern "C" void kernel_launch(void* const* d_in, const int* in_sizes, int n_in,
                              void* d_out, int out_size, void* d_ws, size_t ws_size,
                              hipStream_t stream){
  const float* x      = (const float*)d_in[0];
  const float* ln1_g  = (const float*)d_in[1];
  const float* ln1_b  = (const float*)d_in[2];
  const float* qkv_w  = (const float*)d_in[3];
  const float* qkv_b  = (const float*)d_in[4];
  const float* proj_w = (const float*)d_in[5];
  const float* proj_b = (const float*)d_in[6];
  const float* btab   = (const float*)d_in[7];
  const float* ln2_g  = (const float*)d_in[8];
  const float* ln2_b  = (const float*)d_in[9];
  const float* fc1_w  = (const float*)d_in[10];
  const float* fc1_b  = (const float*)d_in[11];
  const float* fc2_w  = (const float*)d_in[12];
  const float* fc2_b  = (const float*)d_in[13];

  const long M = (long)in_sizes[0] / 256;  // 262144 tokens

  char* ws = (char*)d_ws;
  // Layout (time-disjoint overlaps):
  //   [0, 67MB):        xn8 fp8 -> dead after qkv; ao8 fp8 [0,67) after attn;
  //                     act8 fp8 [0,268) after proj (all time-disjoint... ao8
  //                     read by proj完成 before fc1 writes act8: stream-serial)
  //   [320MiB, 512MiB): qkv8 (fp8, 192MiB)
  //   [536.9, 604MB):   hn8 (fp8)
  //   [671MB, ...):     weights (all fp8)
  //   [712MiB, +134MB): hh (bf16 residual trunk)
  unsigned char*  xn8  = (unsigned char*)(ws);
  unsigned char*  ao8  = (unsigned char*)(ws);
  unsigned char*  act8 = (unsigned char*)(ws);
  unsigned char*  qkv8 = (unsigned char*)(ws + 335544320);
  unsigned char*  hn8  = (unsigned char*)(ws + 536870912);
  unsigned char*  wqf8 = (unsigned char*)(ws + 671088640);
  unsigned char*  wpf8 = wqf8 + 196608;
  unsigned char*  w1f8 = wpf8 + 65536;
  unsigned char*  w2f8 = w1f8 + 262144;
  unsigned short* hh   = (unsigned short*)(ws + (712ull << 20));
  float* outf = (float*)d_out;

  // all 4 weight transposes in one launch (786432 elems)
  wconv4<<<3072, 256, 0, stream>>>(qkv_w, proj_w, fc1_w, fc2_w, wqf8, wpf8, w1f8, w2f8);

  // LN1 -> fp8*16
  ln_kernel<<<M/4, 256, 0, stream>>>(x, ln1_g, ln1_b, xn8);
  // QKV fp8 -> fp8*16 out (swizzled): nbx=6, scale 1/(16*64)
  gemm_fp8<3><<<6 * (M/128), 256, 0, stream>>>(xn8, wqf8, qkv_b, nullptr, qkv8, 768, 256, 6, 1.f/1024.f);
  // window attention (full fp8): one wave per (window, head); ao fp8*16
  attn_kernel<<<(M/64) * 8, 64, 0, stream>>>(qkv8, btab, ao8);
  // proj fp8 + residual + LN2  (h bf16 -> hh, hn fp8*16)
  proj_ln2<<<M/128, 512, 0, stream>>>(ao8, wpf8, proj_b, x, ln2_g, ln2_b, hh, hn8);
  // FC1 fp8 + GELU -> act fp8 (swizzled): nbx=8, scale 1/(16*64)
  gemm_fp8<1><<<8 * (M/128), 256, 0, stream>>>(hn8, w1f8, fc1_b, nullptr, act8, 1024, 256, 8, 1.f/1024.f);
  // FC2 fp8 + residual(hh bf16) -> out f32 (swizzled): nbx=2, scale 1/(8*64)
  gemm_fp8<2><<<2 * (M/128), 256, 0, stream>>>(act8, w2f8, fc2_b, hh, outf, 256, 1024, 2, 1.f/512.f);
}